// Round 2
// baseline (9632.115 us; speedup 1.0000x reference)
//
#include <hip/hip_runtime.h>
#include <math.h>

#define NN 100000
#define EE 1600000
#define ETOT (EE + NN)
#define BN_EPS 1e-5f
#define NEG_SLOPE 0.2f

// ---------- helpers ----------
__device__ __forceinline__ unsigned fenc(float f) {
    unsigned u = __float_as_uint(f);
    return (u & 0x80000000u) ? ~u : (u | 0x80000000u);
}
__device__ __forceinline__ float fdec(unsigned u) {
    return __uint_as_float((u & 0x80000000u) ? (u & 0x7fffffffu) : ~u);
}
__device__ __forceinline__ float lrelu(float x) { return x > 0.f ? x : NEG_SLOPE * x; }
__device__ __forceinline__ float wsum(float v) {
#pragma unroll
    for (int m = 32; m; m >>= 1) v += __shfl_xor(v, m, 64);
    return v;
}
__device__ __forceinline__ void atomAddF(float* p, float v) {
    __hip_atomic_fetch_add(p, v, __ATOMIC_RELAXED, __HIP_MEMORY_SCOPE_AGENT);
}
__device__ __forceinline__ void atomMaxU(unsigned* p, unsigned v) {
    __hip_atomic_fetch_max(p, v, __ATOMIC_RELAXED, __HIP_MEMORY_SCOPE_AGENT);
}

// ---------- GEMM1: h1 = x @ w1 [128->256], + att coefficients ----------
// block = 256 threads, 32 nodes per block; thread j owns output column j.
__global__ __launch_bounds__(256) void k_gemm1(
    const float* __restrict__ x, const float* __restrict__ w,
    const float* __restrict__ asrc, const float* __restrict__ adst,
    float* __restrict__ h, float* __restrict__ as_, float* __restrict__ ad_)
{
    __shared__ float xs[32][128];
    const int n0 = blockIdx.x * 32;
    const int tid = threadIdx.x;
    for (int idx = tid; idx < 32 * 128; idx += 256)
        xs[idx >> 7][idx & 127] = x[(size_t)(n0 + (idx >> 7)) * 128 + (idx & 127)];
    __syncthreads();
    const int j = tid;
    float acc[32];
#pragma unroll
    for (int i = 0; i < 32; ++i) acc[i] = 0.f;
    for (int k = 0; k < 128; k += 4) {
        const float w0 = w[(k + 0) * 256 + j];
        const float w1v = w[(k + 1) * 256 + j];
        const float w2v = w[(k + 2) * 256 + j];
        const float w3v = w[(k + 3) * 256 + j];
#pragma unroll
        for (int i = 0; i < 32; ++i) {
            const float4 xv = *(const float4*)&xs[i][k];
            acc[i] = fmaf(xv.x, w0, acc[i]);
            acc[i] = fmaf(xv.y, w1v, acc[i]);
            acc[i] = fmaf(xv.z, w2v, acc[i]);
            acc[i] = fmaf(xv.w, w3v, acc[i]);
        }
    }
    const int head = j >> 6, lane = j & 63;   // wave == head group
    const float aw = asrc[j], dw = adst[j];
#pragma unroll 4
    for (int i = 0; i < 32; ++i) {
        h[(size_t)(n0 + i) * 256 + j] = acc[i];
        const float s = wsum(acc[i] * aw);
        const float d = wsum(acc[i] * dw);
        if (lane == 0) {
            as_[(n0 + i) * 4 + head] = s;
            ad_[(n0 + i) * 4 + head] = d;
        }
    }
}

// ---------- GEMM2: finalize layer1 (agg/den + b1, BN1, ELU) fused into staging,
// then h2 = hbn @ w2 [256->128], + att coefficients ----------
__global__ __launch_bounds__(128) void k_gemm2(
    const float* __restrict__ agg, const float* __restrict__ den,
    const float* __restrict__ b1, const float* __restrict__ g1,
    const float* __restrict__ be1, const float* __restrict__ m1,
    const float* __restrict__ v1, const float* __restrict__ w,
    const float* __restrict__ asrc, const float* __restrict__ adst,
    float* __restrict__ h, float* __restrict__ as_, float* __restrict__ ad_)
{
    __shared__ float xs[32][256];
    const int n0 = blockIdx.x * 32;
    const int tid = threadIdx.x;
    for (int idx = tid; idx < 32 * 256; idx += 128) {
        const int n = idx >> 8, j = idx & 255;
        const float dn = den[(n0 + n) * 4 + (j >> 6)] + 1e-16f;
        float val = agg[(size_t)(n0 + n) * 256 + j] / dn + b1[j];
        val = (val - m1[j]) * (g1[j] * rsqrtf(v1[j] + BN_EPS)) + be1[j];
        xs[n][j] = val > 0.f ? val : expm1f(val);   // ELU(alpha=1)
    }
    __syncthreads();
    const int j = tid;
    float acc[32];
#pragma unroll
    for (int i = 0; i < 32; ++i) acc[i] = 0.f;
    for (int k = 0; k < 256; k += 4) {
        const float w0 = w[(k + 0) * 128 + j];
        const float w1v = w[(k + 1) * 128 + j];
        const float w2v = w[(k + 2) * 128 + j];
        const float w3v = w[(k + 3) * 128 + j];
#pragma unroll
        for (int i = 0; i < 32; ++i) {
            const float4 xv = *(const float4*)&xs[i][k];
            acc[i] = fmaf(xv.x, w0, acc[i]);
            acc[i] = fmaf(xv.y, w1v, acc[i]);
            acc[i] = fmaf(xv.z, w2v, acc[i]);
            acc[i] = fmaf(xv.w, w3v, acc[i]);
        }
    }
    const int head = j >> 6, lane = j & 63;
    const float aw = asrc[j], dw = adst[j];
#pragma unroll 4
    for (int i = 0; i < 32; ++i) {
        h[(size_t)(n0 + i) * 128 + j] = acc[i];
        const float s = wsum(acc[i] * aw);
        const float d = wsum(acc[i] * dw);
        if (lane == 0) {
            as_[(n0 + i) * 2 + head] = s;
            ad_[(n0 + i) * 2 + head] = d;
        }
    }
}

// ---------- edge pass A: segment max (encoded-uint atomicMax) ----------
template <int H>
__global__ __launch_bounds__(256) void k_edge_max(
    const int* __restrict__ ei, const float* __restrict__ as_,
    const float* __restrict__ ad_, unsigned* __restrict__ mx)
{
    const int e = blockIdx.x * 256 + threadIdx.x;
    if (e >= ETOT) return;
    int s, d;
    if (e < EE) { s = ei[e]; d = ei[EE + e]; }
    else { s = d = e - EE; }
#pragma unroll
    for (int hh = 0; hh < H; ++hh) {
        const float el = lrelu(as_[s * H + hh] + ad_[d * H + hh]);
        atomMaxU(&mx[d * H + hh], fenc(el));
    }
}

// ---------- edge pass B: p=exp(e-mx); agg[dst]+=p*h[src]; den[dst]+=p ----------
// HC/4 lanes cooperate on one edge; lane covers 4 consecutive feature cols.
template <int HC, int H>
__global__ __launch_bounds__(256) void k_edge_acc(
    const int* __restrict__ ei, const float* __restrict__ hf,
    const float* __restrict__ as_, const float* __restrict__ ad_,
    const unsigned* __restrict__ mx, float* __restrict__ agg,
    float* __restrict__ den)
{
    constexpr int LPE = HC / 4;
    constexpr int SH = (LPE == 64) ? 6 : 5;
    const int gid = blockIdx.x * 256 + threadIdx.x;
    const int e = gid >> SH;
    if (e >= ETOT) return;
    const int g = threadIdx.x & (LPE - 1);
    int s, d;
    if (e < EE) { s = ei[e]; d = ei[EE + e]; }
    else { s = d = e - EE; }
    const int j0 = g * 4;
    const int hh = j0 >> 6;
    const float el = lrelu(as_[s * H + hh] + ad_[d * H + hh]);
    const float p = expf(el - fdec(mx[d * H + hh]));
    const float4 hv = *(const float4*)&hf[(size_t)s * HC + j0];
    float* ag = &agg[(size_t)d * HC + j0];
    atomAddF(ag + 0, p * hv.x);
    atomAddF(ag + 1, p * hv.y);
    atomAddF(ag + 2, p * hv.z);
    atomAddF(ag + 3, p * hv.w);
    if ((g & 15) == 0) atomAddF(&den[d * H + hh], p);
}

// ---------- final: mean heads, +b2, BN2, @wc + bc ----------
__global__ __launch_bounds__(256) void k_final(
    const float* __restrict__ agg2, const float* __restrict__ den2,
    const float* __restrict__ b2, const float* __restrict__ g2,
    const float* __restrict__ be2, const float* __restrict__ m2,
    const float* __restrict__ v2, const float* __restrict__ wc,
    const float* __restrict__ bc, float* __restrict__ out)
{
    const int n = blockIdx.x * 4 + (threadIdx.x >> 6);
    const int c = threadIdx.x & 63;
    if (n >= NN) return;
    const float d0 = den2[n * 2 + 0] + 1e-16f;
    const float d1 = den2[n * 2 + 1] + 1e-16f;
    const float v0 = agg2[(size_t)n * 128 + c] / d0;
    const float v1_ = agg2[(size_t)n * 128 + 64 + c] / d1;
    float o = 0.5f * (v0 + v1_) + b2[c];
    o = (o - m2[c]) * (g2[c] * rsqrtf(v2[c] + BN_EPS)) + be2[c];
    const float r0 = wsum(o * wc[c * 2 + 0]);
    const float r1 = wsum(o * wc[c * 2 + 1]);
    if (c == 0) {
        out[n * 2 + 0] = r0 + bc[0];
        out[n * 2 + 1] = r1 + bc[1];
    }
}

extern "C" void kernel_launch(void* const* d_in, const int* in_sizes, int n_in,
                              void* d_out, int out_size, void* d_ws, size_t ws_size,
                              hipStream_t stream) {
    const float* x      = (const float*)d_in[0];
    const int*   ei     = (const int*)d_in[1];   // int64 in ref -> int32 on device
    const float* w1     = (const float*)d_in[2];
    const float* a_src1 = (const float*)d_in[3];
    const float* a_dst1 = (const float*)d_in[4];
    const float* b1     = (const float*)d_in[5];
    const float* g1     = (const float*)d_in[6];
    const float* be1    = (const float*)d_in[7];
    const float* m1     = (const float*)d_in[8];
    const float* v1     = (const float*)d_in[9];
    const float* w2     = (const float*)d_in[10];
    const float* a_src2 = (const float*)d_in[11];
    const float* a_dst2 = (const float*)d_in[12];
    const float* b2     = (const float*)d_in[13];
    const float* g2     = (const float*)d_in[14];
    const float* be2    = (const float*)d_in[15];
    const float* m2     = (const float*)d_in[16];
    const float* v2     = (const float*)d_in[17];
    const float* wc     = (const float*)d_in[18];
    const float* bc     = (const float*)d_in[19];
    float* out = (float*)d_out;

    float* ws = (float*)d_ws;
    const size_t NA = (size_t)NN * 256;            // 25.6M floats
    float* A = ws;                                  // h1; later h2 | agg2
    float* B = ws + NA;                             // agg1
    float* C = ws + 2 * NA;                         // small arrays
    float* as1 = C;
    float* ad1 = C + (size_t)NN * 4;
    float* as2 = C + (size_t)NN * 8;
    float* ad2 = C + (size_t)NN * 10;
    unsigned* mx1 = (unsigned*)(C + (size_t)NN * 12);
    float*    den1 = C + (size_t)NN * 16;
    unsigned* mx2 = (unsigned*)(C + (size_t)NN * 20);
    float*    den2 = C + (size_t)NN * 22;

    float* h1   = A;
    float* agg1 = B;
    float* h2   = A;                                // reuses h1 (dead after L1 acc)
    float* agg2 = A + (size_t)NN * 128;

    // zero accumulators (ws is poisoned 0xAA once; must re-init every launch)
    hipMemsetAsync(agg1, 0, NA * sizeof(float), stream);
    hipMemsetAsync(C + (size_t)NN * 12, 0, (size_t)NN * 12 * sizeof(float), stream);

    // layer 1
    k_gemm1<<<NN / 32, 256, 0, stream>>>(x, w1, a_src1, a_dst1, h1, as1, ad1);
    k_edge_max<4><<<(ETOT + 255) / 256, 256, 0, stream>>>(ei, as1, ad1, mx1);
    k_edge_acc<256, 4><<<(int)(((size_t)ETOT * 64 + 255) / 256), 256, 0, stream>>>(
        ei, h1, as1, ad1, mx1, agg1, den1);

    // agg2 overlaps upper half of h1 -> zero only after L1 acc consumed h1
    hipMemsetAsync(agg2, 0, (size_t)NN * 128 * sizeof(float), stream);

    // layer 2 (finalize L1 fused into GEMM2 staging)
    k_gemm2<<<NN / 32, 128, 0, stream>>>(agg1, den1, b1, g1, be1, m1, v1,
                                         w2, a_src2, a_dst2, h2, as2, ad2);
    k_edge_max<2><<<(ETOT + 255) / 256, 256, 0, stream>>>(ei, as2, ad2, mx2);
    k_edge_acc<128, 2><<<(int)(((size_t)ETOT * 32 + 255) / 256), 256, 0, stream>>>(
        ei, h2, as2, ad2, mx2, agg2, den2);

    // epilogue
    k_final<<<NN / 4, 256, 0, stream>>>(agg2, den2, b2, g2, be2, m2, v2, wc, bc, out);
}

// Round 3
// 1252.183 us; speedup vs baseline: 7.6923x; 7.6923x over previous
//
#include <hip/hip_runtime.h>
#include <math.h>

#define NN 100000
#define EE 1600000
#define ETOT (EE + NN)
#define BN_EPS 1e-5f
#define NEG_SLOPE 0.2f
#define NBLK ((NN + 255) / 256)   // 391

// ---------- helpers ----------
__device__ __forceinline__ float lrelu(float x) { return x > 0.f ? x : NEG_SLOPE * x; }
__device__ __forceinline__ float wsum(float v) {
#pragma unroll
    for (int m = 32; m; m >>= 1) v += __shfl_xor(v, m, 64);
    return v;
}

// ================= CSR build =================
__global__ __launch_bounds__(256) void k_count_init(int* __restrict__ counts) {
    const int n = blockIdx.x * 256 + threadIdx.x;
    if (n < NN) counts[n] = 1;                       // self-loop
}
__global__ __launch_bounds__(256) void k_hist(const int* __restrict__ ei,
                                              int* __restrict__ counts) {
    const int e = blockIdx.x * 256 + threadIdx.x;
    if (e < EE) atomicAdd(&counts[ei[EE + e]], 1);
}
__global__ __launch_bounds__(256) void k_scan_bsum(const int* __restrict__ counts,
                                                   int* __restrict__ bsum) {
    __shared__ int sd[256];
    const int i = blockIdx.x * 256 + threadIdx.x;
    sd[threadIdx.x] = (i < NN) ? counts[i] : 0;
    __syncthreads();
    for (int s2 = 128; s2; s2 >>= 1) {
        if (threadIdx.x < s2) sd[threadIdx.x] += sd[threadIdx.x + s2];
        __syncthreads();
    }
    if (threadIdx.x == 0) bsum[blockIdx.x] = sd[0];
}
__global__ __launch_bounds__(512) void k_scan_top(int* __restrict__ bsum, int nb) {
    __shared__ int sd[512];
    const int t = threadIdx.x;
    const int orig = (t < nb) ? bsum[t] : 0;
    sd[t] = orig;
    __syncthreads();
    for (int off = 1; off < 512; off <<= 1) {
        const int v = (t >= off) ? sd[t - off] : 0;
        __syncthreads();
        sd[t] += v;
        __syncthreads();
    }
    if (t < nb) bsum[t] = sd[t] - orig;              // exclusive
}
__global__ __launch_bounds__(256) void k_scan_final(const int* __restrict__ counts,
                                                    const int* __restrict__ bsum_ex,
                                                    int* __restrict__ rowptr) {
    __shared__ int sd[256];
    const int i = blockIdx.x * 256 + threadIdx.x;
    const int orig = (i < NN) ? counts[i] : 0;
    sd[threadIdx.x] = orig;
    __syncthreads();
    for (int off = 1; off < 256; off <<= 1) {
        const int v = (threadIdx.x >= off) ? sd[threadIdx.x - off] : 0;
        __syncthreads();
        sd[threadIdx.x] += v;
        __syncthreads();
    }
    if (i < NN) rowptr[i] = bsum_ex[blockIdx.x] + sd[threadIdx.x] - orig;
    if (i == NN - 1) rowptr[NN] = ETOT;
}
__global__ __launch_bounds__(256) void k_self(const int* __restrict__ rowptr,
                                              int* __restrict__ srcs,
                                              int* __restrict__ cursor) {
    const int n = blockIdx.x * 256 + threadIdx.x;
    if (n < NN) { const int p = rowptr[n]; srcs[p] = n; cursor[n] = p + 1; }
}
__global__ __launch_bounds__(256) void k_scatter(const int* __restrict__ ei,
                                                 int* __restrict__ srcs,
                                                 int* __restrict__ cursor) {
    const int e = blockIdx.x * 256 + threadIdx.x;
    if (e < EE) {
        const int d = ei[EE + e];
        const int p = atomicAdd(&cursor[d], 1);
        srcs[p] = ei[e];
    }
}

// ================= GEMM1: h1 = x @ w1 [128->256] + att coefficients =================
__global__ __launch_bounds__(256) void k_gemm1(
    const float* __restrict__ x, const float* __restrict__ w,
    const float* __restrict__ asrc, const float* __restrict__ adst,
    float* __restrict__ h, float* __restrict__ as_, float* __restrict__ ad_)
{
    __shared__ float xs[32][128];
    const int n0 = blockIdx.x * 32;
    const int tid = threadIdx.x;
    for (int idx = tid; idx < 32 * 128; idx += 256)
        xs[idx >> 7][idx & 127] = x[(size_t)(n0 + (idx >> 7)) * 128 + (idx & 127)];
    __syncthreads();
    const int j = tid;
    float acc[32];
#pragma unroll
    for (int i = 0; i < 32; ++i) acc[i] = 0.f;
    for (int k = 0; k < 128; k += 4) {
        const float w0 = w[(k + 0) * 256 + j];
        const float w1v = w[(k + 1) * 256 + j];
        const float w2v = w[(k + 2) * 256 + j];
        const float w3v = w[(k + 3) * 256 + j];
#pragma unroll
        for (int i = 0; i < 32; ++i) {
            const float4 xv = *(const float4*)&xs[i][k];
            acc[i] = fmaf(xv.x, w0, acc[i]);
            acc[i] = fmaf(xv.y, w1v, acc[i]);
            acc[i] = fmaf(xv.z, w2v, acc[i]);
            acc[i] = fmaf(xv.w, w3v, acc[i]);
        }
    }
    const int head = j >> 6, lane = j & 63;
    const float aw = asrc[j], dw = adst[j];
#pragma unroll 4
    for (int i = 0; i < 32; ++i) {
        h[(size_t)(n0 + i) * 256 + j] = acc[i];
        const float s = wsum(acc[i] * aw);
        const float d = wsum(acc[i] * dw);
        if (lane == 0) {
            as_[(n0 + i) * 4 + head] = s;
            ad_[(n0 + i) * 4 + head] = d;
        }
    }
}

// ================= GEMM2: (agg1 + b1, BN1, ELU) @ w2 [256->128] + coefficients =====
__global__ __launch_bounds__(128) void k_gemm2(
    const float* __restrict__ agg,
    const float* __restrict__ b1, const float* __restrict__ g1,
    const float* __restrict__ be1, const float* __restrict__ m1,
    const float* __restrict__ v1, const float* __restrict__ w,
    const float* __restrict__ asrc, const float* __restrict__ adst,
    float* __restrict__ h, float* __restrict__ as_, float* __restrict__ ad_)
{
    __shared__ float xs[32][256];
    const int n0 = blockIdx.x * 32;
    const int tid = threadIdx.x;
    for (int idx = tid; idx < 32 * 256; idx += 128) {
        const int n = idx >> 8, j = idx & 255;
        float val = agg[(size_t)(n0 + n) * 256 + j] + b1[j];   // agg pre-normalized
        val = (val - m1[j]) * (g1[j] * rsqrtf(v1[j] + BN_EPS)) + be1[j];
        xs[n][j] = val > 0.f ? val : expm1f(val);              // ELU
    }
    __syncthreads();
    const int j = tid;
    float acc[32];
#pragma unroll
    for (int i = 0; i < 32; ++i) acc[i] = 0.f;
    for (int k = 0; k < 256; k += 4) {
        const float w0 = w[(k + 0) * 128 + j];
        const float w1v = w[(k + 1) * 128 + j];
        const float w2v = w[(k + 2) * 128 + j];
        const float w3v = w[(k + 3) * 128 + j];
#pragma unroll
        for (int i = 0; i < 32; ++i) {
            const float4 xv = *(const float4*)&xs[i][k];
            acc[i] = fmaf(xv.x, w0, acc[i]);
            acc[i] = fmaf(xv.y, w1v, acc[i]);
            acc[i] = fmaf(xv.z, w2v, acc[i]);
            acc[i] = fmaf(xv.w, w3v, acc[i]);
        }
    }
    const int head = j >> 6, lane = j & 63;
    const float aw = asrc[j], dw = adst[j];
#pragma unroll 4
    for (int i = 0; i < 32; ++i) {
        h[(size_t)(n0 + i) * 128 + j] = acc[i];
        const float s = wsum(acc[i] * aw);
        const float d = wsum(acc[i] * dw);
        if (lane == 0) {
            as_[(n0 + i) * 2 + head] = s;
            ad_[(n0 + i) * 2 + head] = d;
        }
    }
}

// ================= per-node softmax + aggregation (CSR, no atomics) =================
// one wave per destination node; HC columns, H heads; writes normalized output.
template <int HC, int H>
__global__ __launch_bounds__(256) void k_agg(
    const int* __restrict__ rowptr, const int* __restrict__ srcs,
    const float* __restrict__ hf, const float* __restrict__ as_,
    const float* __restrict__ ad_, float* __restrict__ outp)
{
    constexpr int VPL = HC / 64;                 // floats per lane (4 or 2)
    const int d = blockIdx.x * 4 + (threadIdx.x >> 6);
    if (d >= NN) return;
    const int lane = threadIdx.x & 63;
    const int r0 = rowptr[d], r1 = rowptr[d + 1];

    float adv[H];
#pragma unroll
    for (int hh = 0; hh < H; ++hh) adv[hh] = ad_[d * H + hh];

    // pass 1: per-head max over this node's edges
    float mx[H];
#pragma unroll
    for (int hh = 0; hh < H; ++hh) mx[hh] = -1e30f;
    for (int k = r0 + lane; k < r1; k += 64) {
        const int s = srcs[k];
#pragma unroll
        for (int hh = 0; hh < H; ++hh)
            mx[hh] = fmaxf(mx[hh], lrelu(as_[s * H + hh] + adv[hh]));
    }
#pragma unroll
    for (int hh = 0; hh < H; ++hh)
#pragma unroll
        for (int m = 32; m; m >>= 1) mx[hh] = fmaxf(mx[hh], __shfl_xor(mx[hh], m, 64));

    // pass 2: denominator
    float den[H];
#pragma unroll
    for (int hh = 0; hh < H; ++hh) den[hh] = 0.f;
    for (int k = r0 + lane; k < r1; k += 64) {
        const int s = srcs[k];
#pragma unroll
        for (int hh = 0; hh < H; ++hh)
            den[hh] += expf(lrelu(as_[s * H + hh] + adv[hh]) - mx[hh]);
    }
#pragma unroll
    for (int hh = 0; hh < H; ++hh) den[hh] = wsum(den[hh]);

    // pass 3: feature accumulation — whole wave walks the edge list together
    const int myh = (lane * VPL) >> 6;
    const float myad = adv[myh];
    const float mymx = mx[myh];
    float acc[VPL];
#pragma unroll
    for (int i = 0; i < VPL; ++i) acc[i] = 0.f;
    for (int k = r0; k < r1; ++k) {
        const int s = __builtin_amdgcn_readfirstlane(srcs[k]);
        const float p = expf(lrelu(as_[s * H + myh] + myad) - mymx);
        if constexpr (VPL == 4) {
            const float4 hv = *(const float4*)&hf[(size_t)s * HC + lane * 4];
            acc[0] = fmaf(p, hv.x, acc[0]);
            acc[1] = fmaf(p, hv.y, acc[1]);
            acc[2] = fmaf(p, hv.z, acc[2]);
            acc[3] = fmaf(p, hv.w, acc[3]);
        } else {
            const float2 hv = *(const float2*)&hf[(size_t)s * HC + lane * 2];
            acc[0] = fmaf(p, hv.x, acc[0]);
            acc[1] = fmaf(p, hv.y, acc[1]);
        }
    }
    const float inv = 1.f / (den[myh] + 1e-16f);
#pragma unroll
    for (int i = 0; i < VPL; ++i)
        outp[(size_t)d * HC + lane * VPL + i] = acc[i] * inv;
}

// ================= final: mean heads, +b2, BN2, @wc + bc =================
__global__ __launch_bounds__(256) void k_final(
    const float* __restrict__ agg2,
    const float* __restrict__ b2, const float* __restrict__ g2,
    const float* __restrict__ be2, const float* __restrict__ m2,
    const float* __restrict__ v2, const float* __restrict__ wc,
    const float* __restrict__ bc, float* __restrict__ out)
{
    const int n = blockIdx.x * 4 + (threadIdx.x >> 6);
    const int c = threadIdx.x & 63;
    if (n >= NN) return;
    const float v0 = agg2[(size_t)n * 128 + c];
    const float v1_ = agg2[(size_t)n * 128 + 64 + c];
    float o = 0.5f * (v0 + v1_) + b2[c];
    o = (o - m2[c]) * (g2[c] * rsqrtf(v2[c] + BN_EPS)) + be2[c];
    const float r0 = wsum(o * wc[c * 2 + 0]);
    const float r1 = wsum(o * wc[c * 2 + 1]);
    if (c == 0) {
        out[n * 2 + 0] = r0 + bc[0];
        out[n * 2 + 1] = r1 + bc[1];
    }
}

extern "C" void kernel_launch(void* const* d_in, const int* in_sizes, int n_in,
                              void* d_out, int out_size, void* d_ws, size_t ws_size,
                              hipStream_t stream) {
    const float* x      = (const float*)d_in[0];
    const int*   ei     = (const int*)d_in[1];
    const float* w1     = (const float*)d_in[2];
    const float* a_src1 = (const float*)d_in[3];
    const float* a_dst1 = (const float*)d_in[4];
    const float* b1     = (const float*)d_in[5];
    const float* g1     = (const float*)d_in[6];
    const float* be1    = (const float*)d_in[7];
    const float* m1     = (const float*)d_in[8];
    const float* v1     = (const float*)d_in[9];
    const float* w2     = (const float*)d_in[10];
    const float* a_src2 = (const float*)d_in[11];
    const float* a_dst2 = (const float*)d_in[12];
    const float* b2     = (const float*)d_in[13];
    const float* g2     = (const float*)d_in[14];
    const float* be2    = (const float*)d_in[15];
    const float* m2     = (const float*)d_in[16];
    const float* v2     = (const float*)d_in[17];
    const float* wc     = (const float*)d_in[18];
    const float* bc     = (const float*)d_in[19];
    float* out = (float*)d_out;

    float* ws = (float*)d_ws;
    const size_t NA = (size_t)NN * 256;
    float* A = ws;            // h1 (NN*256); later h2 (NN*128) | agg2 (NN*128)
    float* B = ws + NA;       // agg1 (NN*256)
    float* C = ws + 2 * NA;   // aux

    float* as1 = C;                       // NN*4
    float* ad1 = C + (size_t)NN * 4;      // NN*4
    float* as2 = C + (size_t)NN * 8;      // NN*2
    float* ad2 = C + (size_t)NN * 10;     // NN*2
    int* counts = (int*)(C + (size_t)NN * 12);       // NN (reused as cursor)
    int* rowptr = counts + NN;                       // NN+1
    int* bsum   = rowptr + NN + 64;                  // 512
    int* srcs   = bsum + 512;                        // ETOT

    float* h1   = A;
    float* agg1 = B;
    float* h2   = A;                       // NN*128, reuses h1
    float* agg2 = A + (size_t)NN * 128;    // NN*128, upper half of A

    // ---- CSR build (per launch; ws is not preserved) ----
    k_count_init<<<NBLK, 256, 0, stream>>>(counts);
    k_hist<<<(EE + 255) / 256, 256, 0, stream>>>(ei, counts);
    k_scan_bsum<<<NBLK, 256, 0, stream>>>(counts, bsum);
    k_scan_top<<<1, 512, 0, stream>>>(bsum, NBLK);
    k_scan_final<<<NBLK, 256, 0, stream>>>(counts, bsum, rowptr);
    k_self<<<NBLK, 256, 0, stream>>>(rowptr, srcs, counts);   // counts -> cursor
    k_scatter<<<(EE + 255) / 256, 256, 0, stream>>>(ei, srcs, counts);

    // ---- layer 1 ----
    k_gemm1<<<NN / 32, 256, 0, stream>>>(x, w1, a_src1, a_dst1, h1, as1, ad1);
    k_agg<256, 4><<<(NN + 3) / 4, 256, 0, stream>>>(rowptr, srcs, h1, as1, ad1, agg1);

    // ---- layer 2 ----
    k_gemm2<<<NN / 32, 128, 0, stream>>>(agg1, b1, g1, be1, m1, v1,
                                         w2, a_src2, a_dst2, h2, as2, ad2);
    k_agg<128, 2><<<(NN + 3) / 4, 256, 0, stream>>>(rowptr, srcs, h2, as2, ad2, agg2);

    // ---- epilogue ----
    k_final<<<(NN + 3) / 4, 256, 0, stream>>>(agg2, b2, g2, be2, m2, v2, wc, bc, out);
}

// Round 4
// 970.349 us; speedup vs baseline: 9.9264x; 1.2904x over previous
//
#include <hip/hip_runtime.h>
#include <math.h>

#define NN 100000
#define EE 1600000
#define ETOT (EE + NN)
#define BN_EPS 1e-5f
#define NEG_SLOPE 0.2f
#define NBLK ((NN + 255) / 256)   // 391

// ---------- helpers ----------
__device__ __forceinline__ float lrelu(float x) { return x > 0.f ? x : NEG_SLOPE * x; }
__device__ __forceinline__ float wsum(float v) {
#pragma unroll
    for (int m = 32; m; m >>= 1) v += __shfl_xor(v, m, 64);
    return v;
}
__device__ __forceinline__ float wmax(float v) {
#pragma unroll
    for (int m = 32; m; m >>= 1) v = fmaxf(v, __shfl_xor(v, m, 64));
    return v;
}
__device__ __forceinline__ float gsum16(float v) {   // reduce within 16-lane group
#pragma unroll
    for (int m = 1; m < 16; m <<= 1) v += __shfl_xor(v, m, 64);
    return v;
}

// ================= CSR build =================
__global__ __launch_bounds__(256) void k_count_init(int* __restrict__ counts) {
    const int n = blockIdx.x * 256 + threadIdx.x;
    if (n < NN) counts[n] = 1;                       // self-loop
}
__global__ __launch_bounds__(256) void k_hist(const int* __restrict__ ei,
                                              int* __restrict__ counts) {
    const int e = blockIdx.x * 256 + threadIdx.x;
    if (e < EE) atomicAdd(&counts[ei[EE + e]], 1);
}
__global__ __launch_bounds__(256) void k_scan_bsum(const int* __restrict__ counts,
                                                   int* __restrict__ bsum) {
    __shared__ int sd[256];
    const int i = blockIdx.x * 256 + threadIdx.x;
    sd[threadIdx.x] = (i < NN) ? counts[i] : 0;
    __syncthreads();
    for (int s2 = 128; s2; s2 >>= 1) {
        if (threadIdx.x < s2) sd[threadIdx.x] += sd[threadIdx.x + s2];
        __syncthreads();
    }
    if (threadIdx.x == 0) bsum[blockIdx.x] = sd[0];
}
__global__ __launch_bounds__(512) void k_scan_top(int* __restrict__ bsum, int nb) {
    __shared__ int sd[512];
    const int t = threadIdx.x;
    const int orig = (t < nb) ? bsum[t] : 0;
    sd[t] = orig;
    __syncthreads();
    for (int off = 1; off < 512; off <<= 1) {
        const int v = (t >= off) ? sd[t - off] : 0;
        __syncthreads();
        sd[t] += v;
        __syncthreads();
    }
    if (t < nb) bsum[t] = sd[t] - orig;              // exclusive
}
__global__ __launch_bounds__(256) void k_scan_final(const int* __restrict__ counts,
                                                    const int* __restrict__ bsum_ex,
                                                    int* __restrict__ rowptr) {
    __shared__ int sd[256];
    const int i = blockIdx.x * 256 + threadIdx.x;
    const int orig = (i < NN) ? counts[i] : 0;
    sd[threadIdx.x] = orig;
    __syncthreads();
    for (int off = 1; off < 256; off <<= 1) {
        const int v = (threadIdx.x >= off) ? sd[threadIdx.x - off] : 0;
        __syncthreads();
        sd[threadIdx.x] += v;
        __syncthreads();
    }
    if (i < NN) rowptr[i] = bsum_ex[blockIdx.x] + sd[threadIdx.x] - orig;
    if (i == NN - 1) rowptr[NN] = ETOT;
}
__global__ __launch_bounds__(256) void k_self(const int* __restrict__ rowptr,
                                              int* __restrict__ srcs,
                                              int* __restrict__ cursor) {
    const int n = blockIdx.x * 256 + threadIdx.x;
    if (n < NN) { const int p = rowptr[n]; srcs[p] = n; cursor[n] = p + 1; }
}
__global__ __launch_bounds__(256) void k_scatter(const int* __restrict__ ei,
                                                 int* __restrict__ srcs,
                                                 int* __restrict__ cursor) {
    const int e = blockIdx.x * 256 + threadIdx.x;
    if (e < EE) {
        const int d = ei[EE + e];
        const int p = atomicAdd(&cursor[d], 1);
        srcs[p] = ei[e];
    }
}

// ================= BN1 scale/shift precompute =================
__global__ __launch_bounds__(256) void k_bnprep(
    const float* __restrict__ b1, const float* __restrict__ g1,
    const float* __restrict__ be1, const float* __restrict__ m1,
    const float* __restrict__ v1, float* __restrict__ scs, float* __restrict__ shs)
{
    const int k = threadIdx.x;                       // 256 == LH*HID
    const float sc = g1[k] * rsqrtf(v1[k] + BN_EPS);
    scs[k] = sc;
    shs[k] = (b1[k] - m1[k]) * sc + be1[k];
}

// ================= GEMM1: h1 = x @ w1 [K=128 -> N=256] + att coefficients ==========
// grid (ceil(NN/64), 4); block 256; 64x64 tile; 4x4 per-thread register tile.
__global__ __launch_bounds__(256) void k_gemm1(
    const float* __restrict__ x, const float* __restrict__ w,
    const float* __restrict__ asrc, const float* __restrict__ adst,
    float* __restrict__ h, float* __restrict__ as_, float* __restrict__ ad_)
{
    __shared__ float xs[128][64];    // [k][n]
    __shared__ float wsd[128][64];   // [k][j]
    const int n0 = blockIdx.x * 64;
    const int jt = blockIdx.y;                        // head
    const int j0 = jt * 64;
    const int t = threadIdx.x;

    {   // stage x (transposed)
        const int n = t & 63;
        const int ng = n0 + n;
        const bool ok = ng < NN;
        const int kq = t >> 6;
#pragma unroll
        for (int kk = 0; kk < 8; ++kk) {
            const int k4 = kq + kk * 4;
            float4 v = ok ? *(const float4*)&x[(size_t)ng * 128 + k4 * 4]
                          : make_float4(0.f, 0.f, 0.f, 0.f);
            xs[k4 * 4 + 0][n] = v.x;
            xs[k4 * 4 + 1][n] = v.y;
            xs[k4 * 4 + 2][n] = v.z;
            xs[k4 * 4 + 3][n] = v.w;
        }
    }
    {   // stage w tile
        const int j = (t & 15) * 4;
        const int kb = t >> 4;
#pragma unroll
        for (int kk = 0; kk < 8; ++kk) {
            const int k = kb + kk * 16;
            *(float4*)&wsd[k][j] = *(const float4*)&w[(size_t)k * 256 + j0 + j];
        }
    }
    __syncthreads();

    const int tx = t & 15, ty = t >> 4;
    float acc[4][4];
#pragma unroll
    for (int r = 0; r < 4; ++r)
#pragma unroll
        for (int c = 0; c < 4; ++c) acc[r][c] = 0.f;

    const float* ap = &xs[0][ty * 4];
    const float* bp = &wsd[0][tx * 4];
#pragma unroll 4
    for (int k = 0; k < 128; ++k) {
        const float4 a = *(const float4*)(ap + k * 64);
        const float4 b = *(const float4*)(bp + k * 64);
        acc[0][0] = fmaf(a.x, b.x, acc[0][0]); acc[0][1] = fmaf(a.x, b.y, acc[0][1]);
        acc[0][2] = fmaf(a.x, b.z, acc[0][2]); acc[0][3] = fmaf(a.x, b.w, acc[0][3]);
        acc[1][0] = fmaf(a.y, b.x, acc[1][0]); acc[1][1] = fmaf(a.y, b.y, acc[1][1]);
        acc[1][2] = fmaf(a.y, b.z, acc[1][2]); acc[1][3] = fmaf(a.y, b.w, acc[1][3]);
        acc[2][0] = fmaf(a.z, b.x, acc[2][0]); acc[2][1] = fmaf(a.z, b.y, acc[2][1]);
        acc[2][2] = fmaf(a.z, b.z, acc[2][2]); acc[2][3] = fmaf(a.z, b.w, acc[2][3]);
        acc[3][0] = fmaf(a.w, b.x, acc[3][0]); acc[3][1] = fmaf(a.w, b.y, acc[3][1]);
        acc[3][2] = fmaf(a.w, b.z, acc[3][2]); acc[3][3] = fmaf(a.w, b.w, acc[3][3]);
    }

    const float4 aw = *(const float4*)&asrc[j0 + tx * 4];
    const float4 dw = *(const float4*)&adst[j0 + tx * 4];
#pragma unroll
    for (int r = 0; r < 4; ++r) {
        const int ng = n0 + ty * 4 + r;
        const bool ok = ng < NN;
        if (ok)
            *(float4*)&h[(size_t)ng * 256 + j0 + tx * 4] =
                make_float4(acc[r][0], acc[r][1], acc[r][2], acc[r][3]);
        float s = acc[r][0] * aw.x + acc[r][1] * aw.y + acc[r][2] * aw.z + acc[r][3] * aw.w;
        float d = acc[r][0] * dw.x + acc[r][1] * dw.y + acc[r][2] * dw.z + acc[r][3] * dw.w;
        s = gsum16(s);
        d = gsum16(d);
        if (tx == 0 && ok) {
            as_[ng * 4 + jt] = s;
            ad_[ng * 4 + jt] = d;
        }
    }
}

// ================= GEMM2: (BN1+ELU)(agg1) @ w2 [K=256 -> N=128] + coefficients =====
// grid (ceil(NN/64), 2); K processed in two 128-chunks.
__global__ __launch_bounds__(256) void k_gemm2(
    const float* __restrict__ agg, const float* __restrict__ scs,
    const float* __restrict__ shs, const float* __restrict__ w,
    const float* __restrict__ asrc, const float* __restrict__ adst,
    float* __restrict__ h, float* __restrict__ as_, float* __restrict__ ad_)
{
    __shared__ float xs[128][64];    // [k][n] current K-chunk
    __shared__ float wsd[128][64];   // [k][j]
    const int n0 = blockIdx.x * 64;
    const int jt = blockIdx.y;                        // head
    const int j0 = jt * 64;
    const int t = threadIdx.x;
    const int tx = t & 15, ty = t >> 4;

    float acc[4][4];
#pragma unroll
    for (int r = 0; r < 4; ++r)
#pragma unroll
        for (int c = 0; c < 4; ++c) acc[r][c] = 0.f;

    for (int kc = 0; kc < 2; ++kc) {
        if (kc) __syncthreads();
        {   // stage agg1 chunk with BN1+ELU, transposed
            const int n = t & 63;
            const int ng = n0 + n;
            const bool ok = ng < NN;
            const int kq = t >> 6;
#pragma unroll
            for (int kk = 0; kk < 8; ++kk) {
                const int k4 = kq + kk * 4;
                const int kg = kc * 128 + k4 * 4;
                float4 v = ok ? *(const float4*)&agg[(size_t)ng * 256 + kg]
                              : make_float4(0.f, 0.f, 0.f, 0.f);
                const float4 sc = *(const float4*)&scs[kg];
                const float4 sh = *(const float4*)&shs[kg];
                float e0 = fmaf(v.x, sc.x, sh.x);
                float e1 = fmaf(v.y, sc.y, sh.y);
                float e2 = fmaf(v.z, sc.z, sh.z);
                float e3 = fmaf(v.w, sc.w, sh.w);
                xs[k4 * 4 + 0][n] = e0 > 0.f ? e0 : expm1f(e0);
                xs[k4 * 4 + 1][n] = e1 > 0.f ? e1 : expm1f(e1);
                xs[k4 * 4 + 2][n] = e2 > 0.f ? e2 : expm1f(e2);
                xs[k4 * 4 + 3][n] = e3 > 0.f ? e3 : expm1f(e3);
            }
        }
        {   // stage w2 chunk
            const int j = (t & 15) * 4;
            const int kb = t >> 4;
#pragma unroll
            for (int kk = 0; kk < 8; ++kk) {
                const int k = kb + kk * 16;
                *(float4*)&wsd[k][j] =
                    *(const float4*)&w[(size_t)(kc * 128 + k) * 128 + j0 + j];
            }
        }
        __syncthreads();

        const float* ap = &xs[0][ty * 4];
        const float* bp = &wsd[0][tx * 4];
#pragma unroll 4
        for (int k = 0; k < 128; ++k) {
            const float4 a = *(const float4*)(ap + k * 64);
            const float4 b = *(const float4*)(bp + k * 64);
            acc[0][0] = fmaf(a.x, b.x, acc[0][0]); acc[0][1] = fmaf(a.x, b.y, acc[0][1]);
            acc[0][2] = fmaf(a.x, b.z, acc[0][2]); acc[0][3] = fmaf(a.x, b.w, acc[0][3]);
            acc[1][0] = fmaf(a.y, b.x, acc[1][0]); acc[1][1] = fmaf(a.y, b.y, acc[1][1]);
            acc[1][2] = fmaf(a.y, b.z, acc[1][2]); acc[1][3] = fmaf(a.y, b.w, acc[1][3]);
            acc[2][0] = fmaf(a.z, b.x, acc[2][0]); acc[2][1] = fmaf(a.z, b.y, acc[2][1]);
            acc[2][2] = fmaf(a.z, b.z, acc[2][2]); acc[2][3] = fmaf(a.z, b.w, acc[2][3]);
            acc[3][0] = fmaf(a.w, b.x, acc[3][0]); acc[3][1] = fmaf(a.w, b.y, acc[3][1]);
            acc[3][2] = fmaf(a.w, b.z, acc[3][2]); acc[3][3] = fmaf(a.w, b.w, acc[3][3]);
        }
    }

    const float4 aw = *(const float4*)&asrc[j0 + tx * 4];
    const float4 dw = *(const float4*)&adst[j0 + tx * 4];
#pragma unroll
    for (int r = 0; r < 4; ++r) {
        const int ng = n0 + ty * 4 + r;
        const bool ok = ng < NN;
        if (ok)
            *(float4*)&h[(size_t)ng * 128 + j0 + tx * 4] =
                make_float4(acc[r][0], acc[r][1], acc[r][2], acc[r][3]);
        float s = acc[r][0] * aw.x + acc[r][1] * aw.y + acc[r][2] * aw.z + acc[r][3] * aw.w;
        float d = acc[r][0] * dw.x + acc[r][1] * dw.y + acc[r][2] * dw.z + acc[r][3] * dw.w;
        s = gsum16(s);
        d = gsum16(d);
        if (tx == 0 && ok) {
            as_[ng * 2 + jt] = s;
            ad_[ng * 2 + jt] = d;
        }
    }
}

// ================= layer-1 aggregation: online softmax + gather (CSR) =============
// one wave per destination node; writes normalized agg1.
__global__ __launch_bounds__(256) void k_agg1(
    const int* __restrict__ rowptr, const int* __restrict__ srcs,
    const float* __restrict__ hf, const float* __restrict__ as_,
    const float* __restrict__ ad_, float* __restrict__ outp)
{
    const int d = blockIdx.x * 4 + (threadIdx.x >> 6);
    if (d >= NN) return;
    const int lane = threadIdx.x & 63;
    const int r0 = rowptr[d], r1 = rowptr[d + 1];
    const float4 adv = *(const float4*)&ad_[d * 4];

    // single pass: online max + denominator, per head
    float m[4] = {-1e30f, -1e30f, -1e30f, -1e30f};
    float den[4] = {0.f, 0.f, 0.f, 0.f};
    for (int k = r0 + lane; k < r1; k += 64) {
        const int s = srcs[k];
        const float4 a = *(const float4*)&as_[s * 4];
        const float e[4] = {lrelu(a.x + adv.x), lrelu(a.y + adv.y),
                            lrelu(a.z + adv.z), lrelu(a.w + adv.w)};
#pragma unroll
        for (int hh = 0; hh < 4; ++hh) {
            const float nm = fmaxf(m[hh], e[hh]);
            den[hh] = den[hh] * expf(m[hh] - nm) + expf(e[hh] - nm);
            m[hh] = nm;
        }
    }
#pragma unroll
    for (int hh = 0; hh < 4; ++hh) {
        const float M = wmax(m[hh]);
        den[hh] = wsum(den[hh] * expf(m[hh] - M));
        m[hh] = M;
    }

    // feature pass: whole wave walks the edge list
    const int myh = lane >> 4;                    // 16 lanes per head
    const float myad = ((const float*)&adv)[myh];
    const float mymx = m[myh];
    float acc[4] = {0.f, 0.f, 0.f, 0.f};
    for (int k = r0; k < r1; ++k) {
        const int s = __builtin_amdgcn_readfirstlane(srcs[k]);
        const float p = expf(lrelu(as_[s * 4 + myh] + myad) - mymx);
        const float4 hv = *(const float4*)&hf[(size_t)s * 256 + lane * 4];
        acc[0] = fmaf(p, hv.x, acc[0]);
        acc[1] = fmaf(p, hv.y, acc[1]);
        acc[2] = fmaf(p, hv.z, acc[2]);
        acc[3] = fmaf(p, hv.w, acc[3]);
    }
    const float inv = 1.f / (den[myh] + 1e-16f);
    *(float4*)&outp[(size_t)d * 256 + lane * 4] =
        make_float4(acc[0] * inv, acc[1] * inv, acc[2] * inv, acc[3] * inv);
}

// ================= layer-2 aggregation + head-mean + BN2 + classifier ==============
__global__ __launch_bounds__(256) void k_agg2f(
    const int* __restrict__ rowptr, const int* __restrict__ srcs,
    const float* __restrict__ hf, const float* __restrict__ as_,
    const float* __restrict__ ad_,
    const float* __restrict__ b2, const float* __restrict__ g2,
    const float* __restrict__ be2, const float* __restrict__ m2,
    const float* __restrict__ v2, const float* __restrict__ wc,
    const float* __restrict__ bc, float* __restrict__ out)
{
    const int d = blockIdx.x * 4 + (threadIdx.x >> 6);
    if (d >= NN) return;
    const int lane = threadIdx.x & 63;
    const int r0 = rowptr[d], r1 = rowptr[d + 1];
    const float2 adv = *(const float2*)&ad_[d * 2];

    float m[2] = {-1e30f, -1e30f};
    float den[2] = {0.f, 0.f};
    for (int k = r0 + lane; k < r1; k += 64) {
        const int s = srcs[k];
        const float2 a = *(const float2*)&as_[s * 2];
        const float e[2] = {lrelu(a.x + adv.x), lrelu(a.y + adv.y)};
#pragma unroll
        for (int hh = 0; hh < 2; ++hh) {
            const float nm = fmaxf(m[hh], e[hh]);
            den[hh] = den[hh] * expf(m[hh] - nm) + expf(e[hh] - nm);
            m[hh] = nm;
        }
    }
#pragma unroll
    for (int hh = 0; hh < 2; ++hh) {
        const float M = wmax(m[hh]);
        den[hh] = wsum(den[hh] * expf(m[hh] - M));
        m[hh] = M;
    }

    const int myh = lane >> 5;                    // 32 lanes per head
    const float myad = myh ? adv.y : adv.x;
    const float mymx = m[myh];
    float acc0 = 0.f, acc1 = 0.f;
    for (int k = r0; k < r1; ++k) {
        const int s = __builtin_amdgcn_readfirstlane(srcs[k]);
        const float p = expf(lrelu(as_[s * 2 + myh] + myad) - mymx);
        const float2 hv = *(const float2*)&hf[(size_t)s * 128 + lane * 2];
        acc0 = fmaf(p, hv.x, acc0);
        acc1 = fmaf(p, hv.y, acc1);
    }
    const float inv = 1.f / (den[myh] + 1e-16f);
    float o0 = acc0 * inv, o1 = acc1 * inv;

    // head mean: cols (c, c+64) live in lanes (l, l^32)
    o0 = 0.5f * (o0 + __shfl_xor(o0, 32, 64));
    o1 = 0.5f * (o1 + __shfl_xor(o1, 32, 64));
    const int c0 = (lane & 31) * 2;
    const float2 b2v = *(const float2*)&b2[c0];
    const float2 g2v = *(const float2*)&g2[c0];
    const float2 be2v = *(const float2*)&be2[c0];
    const float2 m2v = *(const float2*)&m2[c0];
    const float2 v2v = *(const float2*)&v2[c0];
    o0 = (o0 + b2v.x - m2v.x) * (g2v.x * rsqrtf(v2v.x + BN_EPS)) + be2v.x;
    o1 = (o1 + b2v.y - m2v.y) * (g2v.y * rsqrtf(v2v.y + BN_EPS)) + be2v.y;
    const float4 wc4 = *(const float4*)&wc[c0 * 2];
    float q0 = o0 * wc4.x + o1 * wc4.z;
    float q1 = o0 * wc4.y + o1 * wc4.w;
    q0 = wsum(q0) * 0.5f;                         // halves are duplicated
    q1 = wsum(q1) * 0.5f;
    if (lane == 0) {
        out[d * 2 + 0] = q0 + bc[0];
        out[d * 2 + 1] = q1 + bc[1];
    }
}

extern "C" void kernel_launch(void* const* d_in, const int* in_sizes, int n_in,
                              void* d_out, int out_size, void* d_ws, size_t ws_size,
                              hipStream_t stream) {
    const float* x      = (const float*)d_in[0];
    const int*   ei     = (const int*)d_in[1];
    const float* w1     = (const float*)d_in[2];
    const float* a_src1 = (const float*)d_in[3];
    const float* a_dst1 = (const float*)d_in[4];
    const float* b1     = (const float*)d_in[5];
    const float* g1     = (const float*)d_in[6];
    const float* be1    = (const float*)d_in[7];
    const float* m1     = (const float*)d_in[8];
    const float* v1     = (const float*)d_in[9];
    const float* w2     = (const float*)d_in[10];
    const float* a_src2 = (const float*)d_in[11];
    const float* a_dst2 = (const float*)d_in[12];
    const float* b2     = (const float*)d_in[13];
    const float* g2     = (const float*)d_in[14];
    const float* be2    = (const float*)d_in[15];
    const float* m2     = (const float*)d_in[16];
    const float* v2     = (const float*)d_in[17];
    const float* wc     = (const float*)d_in[18];
    const float* bc     = (const float*)d_in[19];
    float* out = (float*)d_out;

    float* ws = (float*)d_ws;
    const size_t NA = (size_t)NN * 256;
    float* A = ws;            // h1 (NN*256); later h2 (NN*128)
    float* B = ws + NA;       // agg1 (NN*256)
    float* C = ws + 2 * NA;   // aux

    float* as1 = C;                       // NN*4
    float* ad1 = C + (size_t)NN * 4;      // NN*4
    float* as2 = C + (size_t)NN * 8;      // NN*2
    float* ad2 = C + (size_t)NN * 10;     // NN*2
    float* scs = C + (size_t)NN * 12;     // 256
    float* shs = scs + 256;               // 256
    int* counts = (int*)(shs + 256);      // NN (reused as cursor)
    int* rowptr = counts + NN;            // NN+1
    int* bsum   = rowptr + NN + 63;       // 512
    int* srcs   = bsum + 512;             // ETOT

    float* h1   = A;
    float* agg1 = B;
    float* h2   = A;                      // NN*128, reuses h1

    // ---- CSR build ----
    k_count_init<<<NBLK, 256, 0, stream>>>(counts);
    k_hist<<<(EE + 255) / 256, 256, 0, stream>>>(ei, counts);
    k_scan_bsum<<<NBLK, 256, 0, stream>>>(counts, bsum);
    k_scan_top<<<1, 512, 0, stream>>>(bsum, NBLK);
    k_scan_final<<<NBLK, 256, 0, stream>>>(counts, bsum, rowptr);
    k_self<<<NBLK, 256, 0, stream>>>(rowptr, srcs, counts);
    k_scatter<<<(EE + 255) / 256, 256, 0, stream>>>(ei, srcs, counts);
    k_bnprep<<<1, 256, 0, stream>>>(b1, g1, be1, m1, v1, scs, shs);

    // ---- layer 1 ----
    dim3 g1grid((NN + 63) / 64, 4);
    k_gemm1<<<g1grid, 256, 0, stream>>>(x, w1, a_src1, a_dst1, h1, as1, ad1);
    k_agg1<<<(NN + 3) / 4, 256, 0, stream>>>(rowptr, srcs, h1, as1, ad1, agg1);

    // ---- layer 2 ----
    dim3 g2grid((NN + 63) / 64, 2);
    k_gemm2<<<g2grid, 256, 0, stream>>>(agg1, scs, shs, w2, a_src2, a_dst2, h2, as2, ad2);
    k_agg2f<<<(NN + 3) / 4, 256, 0, stream>>>(rowptr, srcs, h2, as2, ad2,
                                              b2, g2, be2, m2, v2, wc, bc, out);
}

// Round 5
// 757.640 us; speedup vs baseline: 12.7133x; 1.2808x over previous
//
#include <hip/hip_runtime.h>
#include <hip/hip_fp16.h>
#include <math.h>

#define NN 100000
#define EE 1600000
#define ETOT (EE + NN)
#define BN_EPS 1e-5f
#define NEG_SLOPE 0.2f
#define NBLK ((NN + 255) / 256)   // 391

// ---------- helpers ----------
__device__ __forceinline__ float lrelu(float x) { return x > 0.f ? x : NEG_SLOPE * x; }
__device__ __forceinline__ float wsum(float v) {
#pragma unroll
    for (int m = 32; m; m >>= 1) v += __shfl_xor(v, m, 64);
    return v;
}
__device__ __forceinline__ float wmax(float v) {
#pragma unroll
    for (int m = 32; m; m >>= 1) v = fmaxf(v, __shfl_xor(v, m, 64));
    return v;
}
__device__ __forceinline__ float gsum16(float v) {   // reduce within 16-lane group
#pragma unroll
    for (int m = 1; m < 16; m <<= 1) v += __shfl_xor(v, m, 64);
    return v;
}
__device__ __forceinline__ void store_h4(__half* dst, float a, float b, float c, float d) {
    __half2 p0 = __float22half2_rn(make_float2(a, b));
    __half2 p1 = __float22half2_rn(make_float2(c, d));
    uint2 u;
    u.x = *reinterpret_cast<unsigned*>(&p0);
    u.y = *reinterpret_cast<unsigned*>(&p1);
    *reinterpret_cast<uint2*>(dst) = u;
}

// ================= CSR build =================
__global__ __launch_bounds__(256) void k_count_init(int* __restrict__ counts) {
    const int n = blockIdx.x * 256 + threadIdx.x;
    if (n < NN) counts[n] = 1;                       // self-loop
}
__global__ __launch_bounds__(256) void k_hist(const int* __restrict__ ei,
                                              int* __restrict__ counts) {
    const int e = blockIdx.x * 256 + threadIdx.x;
    if (e < EE) atomicAdd(&counts[ei[EE + e]], 1);
}
__global__ __launch_bounds__(256) void k_scan_bsum(const int* __restrict__ counts,
                                                   int* __restrict__ bsum) {
    __shared__ int sd[256];
    const int i = blockIdx.x * 256 + threadIdx.x;
    sd[threadIdx.x] = (i < NN) ? counts[i] : 0;
    __syncthreads();
    for (int s2 = 128; s2; s2 >>= 1) {
        if (threadIdx.x < s2) sd[threadIdx.x] += sd[threadIdx.x + s2];
        __syncthreads();
    }
    if (threadIdx.x == 0) bsum[blockIdx.x] = sd[0];
}
__global__ __launch_bounds__(512) void k_scan_top(int* __restrict__ bsum, int nb) {
    __shared__ int sd[512];
    const int t = threadIdx.x;
    const int orig = (t < nb) ? bsum[t] : 0;
    sd[t] = orig;
    __syncthreads();
    for (int off = 1; off < 512; off <<= 1) {
        const int v = (t >= off) ? sd[t - off] : 0;
        __syncthreads();
        sd[t] += v;
        __syncthreads();
    }
    if (t < nb) bsum[t] = sd[t] - orig;              // exclusive
}
__global__ __launch_bounds__(256) void k_scan_final(const int* __restrict__ counts,
                                                    const int* __restrict__ bsum_ex,
                                                    int* __restrict__ rowptr) {
    __shared__ int sd[256];
    const int i = blockIdx.x * 256 + threadIdx.x;
    const int orig = (i < NN) ? counts[i] : 0;
    sd[threadIdx.x] = orig;
    __syncthreads();
    for (int off = 1; off < 256; off <<= 1) {
        const int v = (threadIdx.x >= off) ? sd[threadIdx.x - off] : 0;
        __syncthreads();
        sd[threadIdx.x] += v;
        __syncthreads();
    }
    if (i < NN) rowptr[i] = bsum_ex[blockIdx.x] + sd[threadIdx.x] - orig;
    if (i == NN - 1) rowptr[NN] = ETOT;
}
__global__ __launch_bounds__(256) void k_self(const int* __restrict__ rowptr,
                                              int* __restrict__ srcs,
                                              int* __restrict__ cursor) {
    const int n = blockIdx.x * 256 + threadIdx.x;
    if (n < NN) { const int p = rowptr[n]; srcs[p] = n; cursor[n] = p + 1; }
}
__global__ __launch_bounds__(256) void k_scatter(const int* __restrict__ ei,
                                                 int* __restrict__ srcs,
                                                 int* __restrict__ cursor) {
    const int e = blockIdx.x * 256 + threadIdx.x;
    if (e < EE) {
        const int d = ei[EE + e];
        const int p = atomicAdd(&cursor[d], 1);
        srcs[p] = ei[e];
    }
}

// ================= BN1 scale/shift precompute =================
__global__ __launch_bounds__(256) void k_bnprep(
    const float* __restrict__ b1, const float* __restrict__ g1,
    const float* __restrict__ be1, const float* __restrict__ m1,
    const float* __restrict__ v1, float* __restrict__ scs, float* __restrict__ shs)
{
    const int k = threadIdx.x;                       // 256 == LH*HID
    const float sc = g1[k] * rsqrtf(v1[k] + BN_EPS);
    scs[k] = sc;
    shs[k] = (b1[k] - m1[k]) * sc + be1[k];
}

// ================= BN2/classifier collapse: wq[c][2]=s2*wc, cst = bc + const =====
__global__ __launch_bounds__(64) void k_prep2(
    const float* __restrict__ b2, const float* __restrict__ g2,
    const float* __restrict__ be2, const float* __restrict__ m2,
    const float* __restrict__ v2, const float* __restrict__ wc,
    const float* __restrict__ bc, float* __restrict__ wq, float* __restrict__ cst)
{
    const int c = threadIdx.x;                       // 0..63
    const float s2 = g2[c] * rsqrtf(v2[c] + BN_EPS);
    wq[c * 2 + 0] = s2 * wc[c * 2 + 0];
    wq[c * 2 + 1] = s2 * wc[c * 2 + 1];
    const float t = (b2[c] - m2[c]) * s2 + be2[c];
    const float c0 = wsum(t * wc[c * 2 + 0]);
    const float c1 = wsum(t * wc[c * 2 + 1]);
    if (c == 0) { cst[0] = c0 + bc[0]; cst[1] = c1 + bc[1]; }
}

// ================= GEMM1: h1(fp16) = x @ w1 [K=128 -> N=256] + att coefficients ====
__global__ __launch_bounds__(256) void k_gemm1(
    const float* __restrict__ x, const float* __restrict__ w,
    const float* __restrict__ asrc, const float* __restrict__ adst,
    __half* __restrict__ h, float* __restrict__ as_, float* __restrict__ ad_)
{
    __shared__ float xs[128][64];    // [k][n]
    __shared__ float wsd[128][64];   // [k][j]
    const int n0 = blockIdx.x * 64;
    const int jt = blockIdx.y;                        // head
    const int j0 = jt * 64;
    const int t = threadIdx.x;

    {   // stage x (transposed)
        const int n = t & 63;
        const int ng = n0 + n;
        const bool ok = ng < NN;
        const int kq = t >> 6;
#pragma unroll
        for (int kk = 0; kk < 8; ++kk) {
            const int k4 = kq + kk * 4;
            float4 v = ok ? *(const float4*)&x[(size_t)ng * 128 + k4 * 4]
                          : make_float4(0.f, 0.f, 0.f, 0.f);
            xs[k4 * 4 + 0][n] = v.x;
            xs[k4 * 4 + 1][n] = v.y;
            xs[k4 * 4 + 2][n] = v.z;
            xs[k4 * 4 + 3][n] = v.w;
        }
    }
    {   // stage w tile
        const int j = (t & 15) * 4;
        const int kb = t >> 4;
#pragma unroll
        for (int kk = 0; kk < 8; ++kk) {
            const int k = kb + kk * 16;
            *(float4*)&wsd[k][j] = *(const float4*)&w[(size_t)k * 256 + j0 + j];
        }
    }
    __syncthreads();

    const int tx = t & 15, ty = t >> 4;
    float acc[4][4];
#pragma unroll
    for (int r = 0; r < 4; ++r)
#pragma unroll
        for (int c = 0; c < 4; ++c) acc[r][c] = 0.f;

    const float* ap = &xs[0][ty * 4];
    const float* bp = &wsd[0][tx * 4];
#pragma unroll 4
    for (int k = 0; k < 128; ++k) {
        const float4 a = *(const float4*)(ap + k * 64);
        const float4 b = *(const float4*)(bp + k * 64);
        acc[0][0] = fmaf(a.x, b.x, acc[0][0]); acc[0][1] = fmaf(a.x, b.y, acc[0][1]);
        acc[0][2] = fmaf(a.x, b.z, acc[0][2]); acc[0][3] = fmaf(a.x, b.w, acc[0][3]);
        acc[1][0] = fmaf(a.y, b.x, acc[1][0]); acc[1][1] = fmaf(a.y, b.y, acc[1][1]);
        acc[1][2] = fmaf(a.y, b.z, acc[1][2]); acc[1][3] = fmaf(a.y, b.w, acc[1][3]);
        acc[2][0] = fmaf(a.z, b.x, acc[2][0]); acc[2][1] = fmaf(a.z, b.y, acc[2][1]);
        acc[2][2] = fmaf(a.z, b.z, acc[2][2]); acc[2][3] = fmaf(a.z, b.w, acc[2][3]);
        acc[3][0] = fmaf(a.w, b.x, acc[3][0]); acc[3][1] = fmaf(a.w, b.y, acc[3][1]);
        acc[3][2] = fmaf(a.w, b.z, acc[3][2]); acc[3][3] = fmaf(a.w, b.w, acc[3][3]);
    }

    const float4 aw = *(const float4*)&asrc[j0 + tx * 4];
    const float4 dw = *(const float4*)&adst[j0 + tx * 4];
#pragma unroll
    for (int r = 0; r < 4; ++r) {
        const int ng = n0 + ty * 4 + r;
        const bool ok = ng < NN;
        if (ok)
            store_h4(&h[(size_t)ng * 256 + j0 + tx * 4],
                     acc[r][0], acc[r][1], acc[r][2], acc[r][3]);
        float s = acc[r][0] * aw.x + acc[r][1] * aw.y + acc[r][2] * aw.z + acc[r][3] * aw.w;
        float d = acc[r][0] * dw.x + acc[r][1] * dw.y + acc[r][2] * dw.z + acc[r][3] * dw.w;
        s = gsum16(s);
        d = gsum16(d);
        if (tx == 0 && ok) {
            as_[ng * 4 + jt] = s;
            ad_[ng * 4 + jt] = d;
        }
    }
}

// ================= GEMM2: (BN1+ELU)(agg1) @ w2 -> {as2, ad2, q} only ===============
// q[j][head][cls] = sum_c h2[j][head*64+c] * wq[c][cls]; h2 never materialized.
__global__ __launch_bounds__(256) void k_gemm2(
    const float* __restrict__ agg, const float* __restrict__ scs,
    const float* __restrict__ shs, const float* __restrict__ w,
    const float* __restrict__ asrc, const float* __restrict__ adst,
    const float* __restrict__ wq,
    float* __restrict__ as_, float* __restrict__ ad_, float* __restrict__ qv)
{
    __shared__ float xs[128][64];    // [k][n] current K-chunk
    __shared__ float wsd[128][64];   // [k][j]
    const int n0 = blockIdx.x * 64;
    const int jt = blockIdx.y;                        // head
    const int j0 = jt * 64;
    const int t = threadIdx.x;
    const int tx = t & 15, ty = t >> 4;

    float acc[4][4];
#pragma unroll
    for (int r = 0; r < 4; ++r)
#pragma unroll
        for (int c = 0; c < 4; ++c) acc[r][c] = 0.f;

    for (int kc = 0; kc < 2; ++kc) {
        if (kc) __syncthreads();
        {   // stage agg1 chunk with BN1+ELU, transposed
            const int n = t & 63;
            const int ng = n0 + n;
            const bool ok = ng < NN;
            const int kq = t >> 6;
#pragma unroll
            for (int kk = 0; kk < 8; ++kk) {
                const int k4 = kq + kk * 4;
                const int kg = kc * 128 + k4 * 4;
                float4 v = ok ? *(const float4*)&agg[(size_t)ng * 256 + kg]
                              : make_float4(0.f, 0.f, 0.f, 0.f);
                const float4 sc = *(const float4*)&scs[kg];
                const float4 sh = *(const float4*)&shs[kg];
                float e0 = fmaf(v.x, sc.x, sh.x);
                float e1 = fmaf(v.y, sc.y, sh.y);
                float e2 = fmaf(v.z, sc.z, sh.z);
                float e3 = fmaf(v.w, sc.w, sh.w);
                xs[k4 * 4 + 0][n] = e0 > 0.f ? e0 : expm1f(e0);
                xs[k4 * 4 + 1][n] = e1 > 0.f ? e1 : expm1f(e1);
                xs[k4 * 4 + 2][n] = e2 > 0.f ? e2 : expm1f(e2);
                xs[k4 * 4 + 3][n] = e3 > 0.f ? e3 : expm1f(e3);
            }
        }
        {   // stage w2 chunk
            const int j = (t & 15) * 4;
            const int kb = t >> 4;
#pragma unroll
            for (int kk = 0; kk < 8; ++kk) {
                const int k = kb + kk * 16;
                *(float4*)&wsd[k][j] =
                    *(const float4*)&w[(size_t)(kc * 128 + k) * 128 + j0 + j];
            }
        }
        __syncthreads();

        const float* ap = &xs[0][ty * 4];
        const float* bp = &wsd[0][tx * 4];
#pragma unroll 4
        for (int k = 0; k < 128; ++k) {
            const float4 a = *(const float4*)(ap + k * 64);
            const float4 b = *(const float4*)(bp + k * 64);
            acc[0][0] = fmaf(a.x, b.x, acc[0][0]); acc[0][1] = fmaf(a.x, b.y, acc[0][1]);
            acc[0][2] = fmaf(a.x, b.z, acc[0][2]); acc[0][3] = fmaf(a.x, b.w, acc[0][3]);
            acc[1][0] = fmaf(a.y, b.x, acc[1][0]); acc[1][1] = fmaf(a.y, b.y, acc[1][1]);
            acc[1][2] = fmaf(a.y, b.z, acc[1][2]); acc[1][3] = fmaf(a.y, b.w, acc[1][3]);
            acc[2][0] = fmaf(a.z, b.x, acc[2][0]); acc[2][1] = fmaf(a.z, b.y, acc[2][1]);
            acc[2][2] = fmaf(a.z, b.z, acc[2][2]); acc[2][3] = fmaf(a.z, b.w, acc[2][3]);
            acc[3][0] = fmaf(a.w, b.x, acc[3][0]); acc[3][1] = fmaf(a.w, b.y, acc[3][1]);
            acc[3][2] = fmaf(a.w, b.z, acc[3][2]); acc[3][3] = fmaf(a.w, b.w, acc[3][3]);
        }
    }

    const float4 aw = *(const float4*)&asrc[j0 + tx * 4];
    const float4 dw = *(const float4*)&adst[j0 + tx * 4];
    // wq rows for this thread's 4 head-local cols (tx*4 .. tx*4+3)
    const float4 wqa = *(const float4*)&wq[(tx * 4) * 2];       // c0:{0,1}, c1:{0,1}
    const float4 wqb = *(const float4*)&wq[(tx * 4 + 2) * 2];   // c2:{0,1}, c3:{0,1}
#pragma unroll
    for (int r = 0; r < 4; ++r) {
        const int ng = n0 + ty * 4 + r;
        const bool ok = ng < NN;
        float s = acc[r][0] * aw.x + acc[r][1] * aw.y + acc[r][2] * aw.z + acc[r][3] * aw.w;
        float d = acc[r][0] * dw.x + acc[r][1] * dw.y + acc[r][2] * dw.z + acc[r][3] * dw.w;
        float q0 = acc[r][0] * wqa.x + acc[r][1] * wqa.z + acc[r][2] * wqb.x + acc[r][3] * wqb.z;
        float q1 = acc[r][0] * wqa.y + acc[r][1] * wqa.w + acc[r][2] * wqb.y + acc[r][3] * wqb.w;
        s = gsum16(s);
        d = gsum16(d);
        q0 = gsum16(q0);
        q1 = gsum16(q1);
        if (tx == 0 && ok) {
            as_[ng * 2 + jt] = s;
            ad_[ng * 2 + jt] = d;
            qv[ng * 4 + jt * 2 + 0] = q0;
            qv[ng * 4 + jt * 2 + 1] = q1;
        }
    }
}

// ================= layer-1 aggregation: online softmax + fp16 gather (CSR) =========
__global__ __launch_bounds__(256) void k_agg1(
    const int* __restrict__ rowptr, const int* __restrict__ srcs,
    const __half* __restrict__ hf, const float* __restrict__ as_,
    const float* __restrict__ ad_, float* __restrict__ outp)
{
    const int d = blockIdx.x * 4 + (threadIdx.x >> 6);
    if (d >= NN) return;
    const int lane = threadIdx.x & 63;
    const int r0 = rowptr[d], r1 = rowptr[d + 1];
    const float4 adv = *(const float4*)&ad_[d * 4];

    // single pass: online max + denominator, per head
    float m[4] = {-1e30f, -1e30f, -1e30f, -1e30f};
    float den[4] = {0.f, 0.f, 0.f, 0.f};
    for (int k = r0 + lane; k < r1; k += 64) {
        const int s = srcs[k];
        const float4 a = *(const float4*)&as_[s * 4];
        const float e[4] = {lrelu(a.x + adv.x), lrelu(a.y + adv.y),
                            lrelu(a.z + adv.z), lrelu(a.w + adv.w)};
#pragma unroll
        for (int hh = 0; hh < 4; ++hh) {
            const float nm = fmaxf(m[hh], e[hh]);
            den[hh] = den[hh] * expf(m[hh] - nm) + expf(e[hh] - nm);
            m[hh] = nm;
        }
    }
#pragma unroll
    for (int hh = 0; hh < 4; ++hh) {
        const float M = wmax(m[hh]);
        den[hh] = wsum(den[hh] * expf(m[hh] - M));
        m[hh] = M;
    }

    // feature pass: whole wave walks the edge list; fp16 rows, 8B per lane
    const int myh = lane >> 4;                    // 16 lanes per head
    const float myad = ((const float*)&adv)[myh];
    const float mymx = m[myh];
    float acc[4] = {0.f, 0.f, 0.f, 0.f};
    for (int k = r0; k < r1; ++k) {
        const int s = __builtin_amdgcn_readfirstlane(srcs[k]);
        const float p = expf(lrelu(as_[s * 4 + myh] + myad) - mymx);
        const uint2 u = *reinterpret_cast<const uint2*>(&hf[(size_t)s * 256 + lane * 4]);
        const float2 f0 = __half22float2(*reinterpret_cast<const __half2*>(&u.x));
        const float2 f1 = __half22float2(*reinterpret_cast<const __half2*>(&u.y));
        acc[0] = fmaf(p, f0.x, acc[0]);
        acc[1] = fmaf(p, f0.y, acc[1]);
        acc[2] = fmaf(p, f1.x, acc[2]);
        acc[3] = fmaf(p, f1.y, acc[3]);
    }
    const float inv = 1.f / (den[myh] + 1e-16f);
    *(float4*)&outp[(size_t)d * 256 + lane * 4] =
        make_float4(acc[0] * inv, acc[1] * inv, acc[2] * inv, acc[3] * inv);
}

// ================= layer-2: single-pass online softmax over q (24B/edge) ===========
__global__ __launch_bounds__(256) void k_agg2q(
    const int* __restrict__ rowptr, const int* __restrict__ srcs,
    const float* __restrict__ as_, const float* __restrict__ ad_,
    const float* __restrict__ qv, const float* __restrict__ cst,
    float* __restrict__ out)
{
    const int d = blockIdx.x * 4 + (threadIdx.x >> 6);
    if (d >= NN) return;
    const int lane = threadIdx.x & 63;
    const int r0 = rowptr[d], r1 = rowptr[d + 1];
    const float2 adv = *(const float2*)&ad_[d * 2];

    float m0 = -1e30f, m1 = -1e30f, den0 = 0.f, den1 = 0.f;
    float qa00 = 0.f, qa01 = 0.f, qa10 = 0.f, qa11 = 0.f;
    for (int k = r0 + lane; k < r1; k += 64) {
        const int s = srcs[k];
        const float2 a = *(const float2*)&as_[s * 2];
        const float4 q = *(const float4*)&qv[s * 4];
        const float e0 = lrelu(a.x + adv.x);
        const float e1 = lrelu(a.y + adv.y);
        float nm = fmaxf(m0, e0);
        float sc = expf(m0 - nm);
        float p = expf(e0 - nm);
        den0 = den0 * sc + p;
        qa00 = qa00 * sc + p * q.x;
        qa01 = qa01 * sc + p * q.y;
        m0 = nm;
        nm = fmaxf(m1, e1);
        sc = expf(m1 - nm);
        p = expf(e1 - nm);
        den1 = den1 * sc + p;
        qa10 = qa10 * sc + p * q.z;
        qa11 = qa11 * sc + p * q.w;
        m1 = nm;
    }
    const float M0 = wmax(m0), M1 = wmax(m1);
    const float s0 = expf(m0 - M0), s1 = expf(m1 - M1);
    den0 = wsum(den0 * s0);
    den1 = wsum(den1 * s1);
    qa00 = wsum(qa00 * s0);
    qa01 = wsum(qa01 * s0);
    qa10 = wsum(qa10 * s1);
    qa11 = wsum(qa11 * s1);
    if (lane == 0) {
        const float i0 = 1.f / (den0 + 1e-16f);
        const float i1 = 1.f / (den1 + 1e-16f);
        out[d * 2 + 0] = cst[0] + 0.5f * (qa00 * i0 + qa10 * i1);
        out[d * 2 + 1] = cst[1] + 0.5f * (qa01 * i0 + qa11 * i1);
    }
}

extern "C" void kernel_launch(void* const* d_in, const int* in_sizes, int n_in,
                              void* d_out, int out_size, void* d_ws, size_t ws_size,
                              hipStream_t stream) {
    const float* x      = (const float*)d_in[0];
    const int*   ei     = (const int*)d_in[1];
    const float* w1     = (const float*)d_in[2];
    const float* a_src1 = (const float*)d_in[3];
    const float* a_dst1 = (const float*)d_in[4];
    const float* b1     = (const float*)d_in[5];
    const float* g1     = (const float*)d_in[6];
    const float* be1    = (const float*)d_in[7];
    const float* m1     = (const float*)d_in[8];
    const float* v1     = (const float*)d_in[9];
    const float* w2     = (const float*)d_in[10];
    const float* a_src2 = (const float*)d_in[11];
    const float* a_dst2 = (const float*)d_in[12];
    const float* b2     = (const float*)d_in[13];
    const float* g2     = (const float*)d_in[14];
    const float* be2    = (const float*)d_in[15];
    const float* m2     = (const float*)d_in[16];
    const float* v2     = (const float*)d_in[17];
    const float* wc     = (const float*)d_in[18];
    const float* bc     = (const float*)d_in[19];
    float* out = (float*)d_out;

    float* ws = (float*)d_ws;
    const size_t NA = (size_t)NN * 256;
    float* A = ws;            // h1 as fp16 (occupies first NA/2 floats)
    float* B = ws + NA;       // agg1 (NN*256 fp32)
    float* C = ws + 2 * NA;   // aux

    float* as1 = C;                       // NN*4
    float* ad1 = C + (size_t)NN * 4;      // NN*4
    float* as2 = C + (size_t)NN * 8;      // NN*2
    float* ad2 = C + (size_t)NN * 10;     // NN*2
    float* qv  = C + (size_t)NN * 12;     // NN*4
    float* scs = C + (size_t)NN * 16;     // 256
    float* shs = scs + 256;               // 256
    float* wq  = shs + 256;               // 128
    float* cst = wq + 128;                // 2 (+pad)
    int* counts = (int*)(cst + 64);       // NN (reused as cursor)
    int* rowptr = counts + NN;            // NN+1
    int* bsum   = rowptr + NN + 63;       // 512
    int* srcs   = bsum + 512;             // ETOT

    __half* h1 = (__half*)A;
    float* agg1 = B;

    // ---- CSR build ----
    k_count_init<<<NBLK, 256, 0, stream>>>(counts);
    k_hist<<<(EE + 255) / 256, 256, 0, stream>>>(ei, counts);
    k_scan_bsum<<<NBLK, 256, 0, stream>>>(counts, bsum);
    k_scan_top<<<1, 512, 0, stream>>>(bsum, NBLK);
    k_scan_final<<<NBLK, 256, 0, stream>>>(counts, bsum, rowptr);
    k_self<<<NBLK, 256, 0, stream>>>(rowptr, srcs, counts);
    k_scatter<<<(EE + 255) / 256, 256, 0, stream>>>(ei, srcs, counts);
    k_bnprep<<<1, 256, 0, stream>>>(b1, g1, be1, m1, v1, scs, shs);
    k_prep2<<<1, 64, 0, stream>>>(b2, g2, be2, m2, v2, wc, bc, wq, cst);

    // ---- layer 1 ----
    dim3 g1grid((NN + 63) / 64, 4);
    k_gemm1<<<g1grid, 256, 0, stream>>>(x, w1, a_src1, a_dst1, h1, as1, ad1);
    k_agg1<<<(NN + 3) / 4, 256, 0, stream>>>(rowptr, srcs, h1, as1, ad1, agg1);

    // ---- layer 2 ----
    dim3 g2grid((NN + 63) / 64, 2);
    k_gemm2<<<g2grid, 256, 0, stream>>>(agg1, scs, shs, w2, a_src2, a_dst2, wq,
                                        as2, ad2, qv);
    k_agg2q<<<(NN + 3) / 4, 256, 0, stream>>>(rowptr, srcs, as2, ad2, qv, cst, out);
}

// Round 6
// 660.947 us; speedup vs baseline: 14.5732x; 1.1463x over previous
//
#include <hip/hip_runtime.h>
#include <hip/hip_fp16.h>
#include <math.h>

#define NN 100000
#define EE 1600000
#define ETOT (EE + NN)
#define BN_EPS 1e-5f
#define NEG_SLOPE 0.2f
#define NBLK ((NN + 255) / 256)   // 391

// ---------- helpers ----------
__device__ __forceinline__ float lrelu(float x) { return fmaxf(x, NEG_SLOPE * x); }
__device__ __forceinline__ float wsum(float v) {
#pragma unroll
    for (int m = 32; m; m >>= 1) v += __shfl_xor(v, m, 64);
    return v;
}
__device__ __forceinline__ float gsum16(float v) {   // reduce within 16-lane group
#pragma unroll
    for (int m = 1; m < 16; m <<= 1) v += __shfl_xor(v, m, 64);
    return v;
}
__device__ __forceinline__ void store_h4(__half* dst, float a, float b, float c, float d) {
    __half2 p0 = __float22half2_rn(make_float2(a, b));
    __half2 p1 = __float22half2_rn(make_float2(c, d));
    uint2 u;
    u.x = *reinterpret_cast<unsigned*>(&p0);
    u.y = *reinterpret_cast<unsigned*>(&p1);
    *reinterpret_cast<uint2*>(dst) = u;
}
__device__ __forceinline__ float sel4(float4 v, int i) {   // branchless select, no scratch
    float lo = (i & 1) ? v.y : v.x;
    float hi = (i & 1) ? v.w : v.z;
    return (i & 2) ? hi : lo;
}

// ================= CSR build =================
__global__ __launch_bounds__(256) void k_count_init(int* __restrict__ counts) {
    const int n = blockIdx.x * 256 + threadIdx.x;
    if (n < NN) counts[n] = 1;                       // self-loop
}
__global__ __launch_bounds__(256) void k_hist(const int* __restrict__ ei,
                                              int* __restrict__ counts) {
    const int e = blockIdx.x * 256 + threadIdx.x;
    if (e < EE) atomicAdd(&counts[ei[EE + e]], 1);
}
__global__ __launch_bounds__(256) void k_scan_bsum(const int* __restrict__ counts,
                                                   int* __restrict__ bsum) {
    __shared__ int sd[256];
    const int i = blockIdx.x * 256 + threadIdx.x;
    sd[threadIdx.x] = (i < NN) ? counts[i] : 0;
    __syncthreads();
    for (int s2 = 128; s2; s2 >>= 1) {
        if (threadIdx.x < s2) sd[threadIdx.x] += sd[threadIdx.x + s2];
        __syncthreads();
    }
    if (threadIdx.x == 0) bsum[blockIdx.x] = sd[0];
}
__global__ __launch_bounds__(512) void k_scan_top(int* __restrict__ bsum, int nb) {
    __shared__ int sd[512];
    const int t = threadIdx.x;
    const int orig = (t < nb) ? bsum[t] : 0;
    sd[t] = orig;
    __syncthreads();
    for (int off = 1; off < 512; off <<= 1) {
        const int v = (t >= off) ? sd[t - off] : 0;
        __syncthreads();
        sd[t] += v;
        __syncthreads();
    }
    if (t < nb) bsum[t] = sd[t] - orig;              // exclusive
}
__global__ __launch_bounds__(256) void k_scan_final(const int* __restrict__ counts,
                                                    const int* __restrict__ bsum_ex,
                                                    int* __restrict__ rowptr) {
    __shared__ int sd[256];
    const int i = blockIdx.x * 256 + threadIdx.x;
    const int orig = (i < NN) ? counts[i] : 0;
    sd[threadIdx.x] = orig;
    __syncthreads();
    for (int off = 1; off < 256; off <<= 1) {
        const int v = (threadIdx.x >= off) ? sd[threadIdx.x - off] : 0;
        __syncthreads();
        sd[threadIdx.x] += v;
        __syncthreads();
    }
    if (i < NN) rowptr[i] = bsum_ex[blockIdx.x] + sd[threadIdx.x] - orig;
    if (i == NN - 1) rowptr[NN] = ETOT;
}
__global__ __launch_bounds__(256) void k_self(const int* __restrict__ rowptr,
                                              int* __restrict__ srcs,
                                              int* __restrict__ cursor) {
    const int n = blockIdx.x * 256 + threadIdx.x;
    if (n < NN) { const int p = rowptr[n]; srcs[p] = n; cursor[n] = p + 1; }
}
__global__ __launch_bounds__(256) void k_scatter(const int* __restrict__ ei,
                                                 int* __restrict__ srcs,
                                                 int* __restrict__ cursor) {
    const int e = blockIdx.x * 256 + threadIdx.x;
    if (e < EE) {
        const int d = ei[EE + e];
        const int p = atomicAdd(&cursor[d], 1);
        srcs[p] = ei[e];
    }
}

// ================= BN1 scale/shift precompute =================
__global__ __launch_bounds__(256) void k_bnprep(
    const float* __restrict__ b1, const float* __restrict__ g1,
    const float* __restrict__ be1, const float* __restrict__ m1,
    const float* __restrict__ v1, float* __restrict__ scs, float* __restrict__ shs)
{
    const int k = threadIdx.x;                       // 256 == LH*HID
    const float sc = g1[k] * rsqrtf(v1[k] + BN_EPS);
    scs[k] = sc;
    shs[k] = (b1[k] - m1[k]) * sc + be1[k];
}

// ================= BN2/classifier collapse: wq[c][2]=s2*wc, cst = bc + const =====
__global__ __launch_bounds__(64) void k_prep2(
    const float* __restrict__ b2, const float* __restrict__ g2,
    const float* __restrict__ be2, const float* __restrict__ m2,
    const float* __restrict__ v2, const float* __restrict__ wc,
    const float* __restrict__ bc, float* __restrict__ wq, float* __restrict__ cst)
{
    const int c = threadIdx.x;                       // 0..63
    const float s2 = g2[c] * rsqrtf(v2[c] + BN_EPS);
    wq[c * 2 + 0] = s2 * wc[c * 2 + 0];
    wq[c * 2 + 1] = s2 * wc[c * 2 + 1];
    const float t = (b2[c] - m2[c]) * s2 + be2[c];
    const float c0 = wsum(t * wc[c * 2 + 0]);
    const float c1 = wsum(t * wc[c * 2 + 1]);
    if (c == 0) { cst[0] = c0 + bc[0]; cst[1] = c1 + bc[1]; }
}

// ================= GEMM1: h1(fp16) = x @ w1 [K=128 -> N=256] + att coefficients ====
__global__ __launch_bounds__(256) void k_gemm1(
    const float* __restrict__ x, const float* __restrict__ w,
    const float* __restrict__ asrc, const float* __restrict__ adst,
    __half* __restrict__ h, float* __restrict__ as_, float* __restrict__ ad_)
{
    __shared__ float xs[128][64];    // [k][n]
    __shared__ float wsd[128][64];   // [k][j]
    const int n0 = blockIdx.x * 64;
    const int jt = blockIdx.y;                        // head
    const int j0 = jt * 64;
    const int t = threadIdx.x;

    {   // stage x (transposed)
        const int n = t & 63;
        const int ng = n0 + n;
        const bool ok = ng < NN;
        const int kq = t >> 6;
#pragma unroll
        for (int kk = 0; kk < 8; ++kk) {
            const int k4 = kq + kk * 4;
            float4 v = ok ? *(const float4*)&x[(size_t)ng * 128 + k4 * 4]
                          : make_float4(0.f, 0.f, 0.f, 0.f);
            xs[k4 * 4 + 0][n] = v.x;
            xs[k4 * 4 + 1][n] = v.y;
            xs[k4 * 4 + 2][n] = v.z;
            xs[k4 * 4 + 3][n] = v.w;
        }
    }
    {   // stage w tile
        const int j = (t & 15) * 4;
        const int kb = t >> 4;
#pragma unroll
        for (int kk = 0; kk < 8; ++kk) {
            const int k = kb + kk * 16;
            *(float4*)&wsd[k][j] = *(const float4*)&w[(size_t)k * 256 + j0 + j];
        }
    }
    __syncthreads();

    const int tx = t & 15, ty = t >> 4;
    float acc[4][4];
#pragma unroll
    for (int r = 0; r < 4; ++r)
#pragma unroll
        for (int c = 0; c < 4; ++c) acc[r][c] = 0.f;

    const float* ap = &xs[0][ty * 4];
    const float* bp = &wsd[0][tx * 4];
#pragma unroll 4
    for (int k = 0; k < 128; ++k) {
        const float4 a = *(const float4*)(ap + k * 64);
        const float4 b = *(const float4*)(bp + k * 64);
        acc[0][0] = fmaf(a.x, b.x, acc[0][0]); acc[0][1] = fmaf(a.x, b.y, acc[0][1]);
        acc[0][2] = fmaf(a.x, b.z, acc[0][2]); acc[0][3] = fmaf(a.x, b.w, acc[0][3]);
        acc[1][0] = fmaf(a.y, b.x, acc[1][0]); acc[1][1] = fmaf(a.y, b.y, acc[1][1]);
        acc[1][2] = fmaf(a.y, b.z, acc[1][2]); acc[1][3] = fmaf(a.y, b.w, acc[1][3]);
        acc[2][0] = fmaf(a.z, b.x, acc[2][0]); acc[2][1] = fmaf(a.z, b.y, acc[2][1]);
        acc[2][2] = fmaf(a.z, b.z, acc[2][2]); acc[2][3] = fmaf(a.z, b.w, acc[2][3]);
        acc[3][0] = fmaf(a.w, b.x, acc[3][0]); acc[3][1] = fmaf(a.w, b.y, acc[3][1]);
        acc[3][2] = fmaf(a.w, b.z, acc[3][2]); acc[3][3] = fmaf(a.w, b.w, acc[3][3]);
    }

    const float4 aw = *(const float4*)&asrc[j0 + tx * 4];
    const float4 dw = *(const float4*)&adst[j0 + tx * 4];
#pragma unroll
    for (int r = 0; r < 4; ++r) {
        const int ng = n0 + ty * 4 + r;
        const bool ok = ng < NN;
        if (ok)
            store_h4(&h[(size_t)ng * 256 + j0 + tx * 4],
                     acc[r][0], acc[r][1], acc[r][2], acc[r][3]);
        float s = acc[r][0] * aw.x + acc[r][1] * aw.y + acc[r][2] * aw.z + acc[r][3] * aw.w;
        float d = acc[r][0] * dw.x + acc[r][1] * dw.y + acc[r][2] * dw.z + acc[r][3] * dw.w;
        s = gsum16(s);
        d = gsum16(d);
        if (tx == 0 && ok) {
            as_[ng * 4 + jt] = s;
            ad_[ng * 4 + jt] = d;
        }
    }
}

// ================= GEMM2: (BN1+ELU)(agg1) @ w2 -> {as2, ad2, q} only ===============
__global__ __launch_bounds__(256) void k_gemm2(
    const float* __restrict__ agg, const float* __restrict__ scs,
    const float* __restrict__ shs, const float* __restrict__ w,
    const float* __restrict__ asrc, const float* __restrict__ adst,
    const float* __restrict__ wq,
    float* __restrict__ as_, float* __restrict__ ad_, float* __restrict__ qv)
{
    __shared__ float xs[128][64];    // [k][n] current K-chunk
    __shared__ float wsd[128][64];   // [k][j]
    const int n0 = blockIdx.x * 64;
    const int jt = blockIdx.y;                        // head
    const int j0 = jt * 64;
    const int t = threadIdx.x;
    const int tx = t & 15, ty = t >> 4;

    float acc[4][4];
#pragma unroll
    for (int r = 0; r < 4; ++r)
#pragma unroll
        for (int c = 0; c < 4; ++c) acc[r][c] = 0.f;

    for (int kc = 0; kc < 2; ++kc) {
        if (kc) __syncthreads();
        {   // stage agg1 chunk with BN1+ELU, transposed
            const int n = t & 63;
            const int ng = n0 + n;
            const bool ok = ng < NN;
            const int kq = t >> 6;
#pragma unroll
            for (int kk = 0; kk < 8; ++kk) {
                const int k4 = kq + kk * 4;
                const int kg = kc * 128 + k4 * 4;
                float4 v = ok ? *(const float4*)&agg[(size_t)ng * 256 + kg]
                              : make_float4(0.f, 0.f, 0.f, 0.f);
                const float4 sc = *(const float4*)&scs[kg];
                const float4 sh = *(const float4*)&shs[kg];
                float e0 = fmaf(v.x, sc.x, sh.x);
                float e1 = fmaf(v.y, sc.y, sh.y);
                float e2 = fmaf(v.z, sc.z, sh.z);
                float e3 = fmaf(v.w, sc.w, sh.w);
                xs[k4 * 4 + 0][n] = e0 > 0.f ? e0 : expm1f(e0);
                xs[k4 * 4 + 1][n] = e1 > 0.f ? e1 : expm1f(e1);
                xs[k4 * 4 + 2][n] = e2 > 0.f ? e2 : expm1f(e2);
                xs[k4 * 4 + 3][n] = e3 > 0.f ? e3 : expm1f(e3);
            }
        }
        {   // stage w2 chunk
            const int j = (t & 15) * 4;
            const int kb = t >> 4;
#pragma unroll
            for (int kk = 0; kk < 8; ++kk) {
                const int k = kb + kk * 16;
                *(float4*)&wsd[k][j] =
                    *(const float4*)&w[(size_t)(kc * 128 + k) * 128 + j0 + j];
            }
        }
        __syncthreads();

        const float* ap = &xs[0][ty * 4];
        const float* bp = &wsd[0][tx * 4];
#pragma unroll 4
        for (int k = 0; k < 128; ++k) {
            const float4 a = *(const float4*)(ap + k * 64);
            const float4 b = *(const float4*)(bp + k * 64);
            acc[0][0] = fmaf(a.x, b.x, acc[0][0]); acc[0][1] = fmaf(a.x, b.y, acc[0][1]);
            acc[0][2] = fmaf(a.x, b.z, acc[0][2]); acc[0][3] = fmaf(a.x, b.w, acc[0][3]);
            acc[1][0] = fmaf(a.y, b.x, acc[1][0]); acc[1][1] = fmaf(a.y, b.y, acc[1][1]);
            acc[1][2] = fmaf(a.y, b.z, acc[1][2]); acc[1][3] = fmaf(a.y, b.w, acc[1][3]);
            acc[2][0] = fmaf(a.z, b.x, acc[2][0]); acc[2][1] = fmaf(a.z, b.y, acc[2][1]);
            acc[2][2] = fmaf(a.z, b.z, acc[2][2]); acc[2][3] = fmaf(a.z, b.w, acc[2][3]);
            acc[3][0] = fmaf(a.w, b.x, acc[3][0]); acc[3][1] = fmaf(a.w, b.y, acc[3][1]);
            acc[3][2] = fmaf(a.w, b.z, acc[3][2]); acc[3][3] = fmaf(a.w, b.w, acc[3][3]);
        }
    }

    const float4 aw = *(const float4*)&asrc[j0 + tx * 4];
    const float4 dw = *(const float4*)&adst[j0 + tx * 4];
    const float4 wqa = *(const float4*)&wq[(tx * 4) * 2];       // c0:{0,1}, c1:{0,1}
    const float4 wqb = *(const float4*)&wq[(tx * 4 + 2) * 2];   // c2:{0,1}, c3:{0,1}
#pragma unroll
    for (int r = 0; r < 4; ++r) {
        const int ng = n0 + ty * 4 + r;
        const bool ok = ng < NN;
        float s = acc[r][0] * aw.x + acc[r][1] * aw.y + acc[r][2] * aw.z + acc[r][3] * aw.w;
        float d = acc[r][0] * dw.x + acc[r][1] * dw.y + acc[r][2] * dw.z + acc[r][3] * dw.w;
        float q0 = acc[r][0] * wqa.x + acc[r][1] * wqa.z + acc[r][2] * wqb.x + acc[r][3] * wqb.z;
        float q1 = acc[r][0] * wqa.y + acc[r][1] * wqa.w + acc[r][2] * wqb.y + acc[r][3] * wqb.w;
        s = gsum16(s);
        d = gsum16(d);
        q0 = gsum16(q0);
        q1 = gsum16(q1);
        if (tx == 0 && ok) {
            as_[ng * 2 + jt] = s;
            ad_[ng * 2 + jt] = d;
            qv[ng * 4 + jt * 2 + 0] = q0;
            qv[ng * 4 + jt * 2 + 1] = q1;
        }
    }
}

// ================= layer-1 aggregation: shift-free softmax + fp16 gather ===========
// one wave per dst node. pass1: den per head, stash p (<=64 edges) in LDS.
// pass2: 2 edges/iter, 32 lanes x 16B per edge.
__global__ __launch_bounds__(256) void k_agg1(
    const int* __restrict__ rowptr, const int* __restrict__ srcs,
    const __half* __restrict__ hf, const float* __restrict__ as_,
    const float* __restrict__ ad_, float* __restrict__ outp)
{
    __shared__ float pbuf[4][64][4];
    const int wv = threadIdx.x >> 6;
    const int d = blockIdx.x * 4 + wv;
    if (d >= NN) return;
    const int lane = threadIdx.x & 63;
    const int r0 = rowptr[d], r1 = rowptr[d + 1];
    const float4 adv = *(const float4*)&ad_[d * 4];

    // pass 1: denominators (shift-free: e is O(+-10), exp safe in fp32)
    float den0 = 0.f, den1 = 0.f, den2 = 0.f, den3 = 0.f;
    for (int k = r0 + lane; k < r1; k += 64) {
        const int s = srcs[k];
        const float4 a = *(const float4*)&as_[s * 4];
        const float p0 = __expf(lrelu(a.x + adv.x));
        const float p1 = __expf(lrelu(a.y + adv.y));
        const float p2 = __expf(lrelu(a.z + adv.z));
        const float p3 = __expf(lrelu(a.w + adv.w));
        const int loc = k - r0;
        if (loc < 64) *(float4*)&pbuf[wv][loc][0] = make_float4(p0, p1, p2, p3);
        den0 += p0; den1 += p1; den2 += p2; den3 += p3;
    }
    den0 = wsum(den0); den1 = wsum(den1); den2 = wsum(den2); den3 = wsum(den3);

    // pass 2: two edges per iteration
    const int g = lane >> 5, wl = lane & 31;
    const int headw = wl >> 3;                      // head of this lane's col block
    const float myad = sel4(adv, headw);
    const __half* hbase = hf + wl * 8;
    float acc[8] = {0.f, 0.f, 0.f, 0.f, 0.f, 0.f, 0.f, 0.f};
    for (int k = r0; k < r1; k += 2) {
        const int kk = k + g;
        if (kk < r1) {
            const int s = srcs[kk];
            const int loc = kk - r0;
            float p;
            if (loc < 64) p = pbuf[wv][loc][headw];
            else          p = __expf(lrelu(as_[s * 4 + headw] + myad));
            const uint4 u = *reinterpret_cast<const uint4*>(hbase + (size_t)s * 256);
            const float2 f0 = __half22float2(*reinterpret_cast<const __half2*>(&u.x));
            const float2 f1 = __half22float2(*reinterpret_cast<const __half2*>(&u.y));
            const float2 f2 = __half22float2(*reinterpret_cast<const __half2*>(&u.z));
            const float2 f3 = __half22float2(*reinterpret_cast<const __half2*>(&u.w));
            acc[0] = fmaf(p, f0.x, acc[0]); acc[1] = fmaf(p, f0.y, acc[1]);
            acc[2] = fmaf(p, f1.x, acc[2]); acc[3] = fmaf(p, f1.y, acc[3]);
            acc[4] = fmaf(p, f2.x, acc[4]); acc[5] = fmaf(p, f2.y, acc[5]);
            acc[6] = fmaf(p, f3.x, acc[6]); acc[7] = fmaf(p, f3.y, acc[7]);
        }
    }
    // combine halves (edges split across g), normalize, store
    const float deng = sel4(make_float4(den0, den1, den2, den3), headw);
    const float inv = 1.f / (deng + 1e-16f);
#pragma unroll
    for (int i = 0; i < 8; ++i)
        acc[i] = (acc[i] + __shfl_xor(acc[i], 32, 64)) * inv;
    float* op = &outp[(size_t)d * 256 + wl * 8 + g * 4];
    if (g == 0) *(float4*)op = make_float4(acc[0], acc[1], acc[2], acc[3]);
    else        *(float4*)op = make_float4(acc[4], acc[5], acc[6], acc[7]);
}

// ================= layer-2: single-pass shift-free softmax over q ==================
__global__ __launch_bounds__(256) void k_agg2q(
    const int* __restrict__ rowptr, const int* __restrict__ srcs,
    const float* __restrict__ as_, const float* __restrict__ ad_,
    const float* __restrict__ qv, const float* __restrict__ cst,
    float* __restrict__ out)
{
    const int d = blockIdx.x * 4 + (threadIdx.x >> 6);
    if (d >= NN) return;
    const int lane = threadIdx.x & 63;
    const int r0 = rowptr[d], r1 = rowptr[d + 1];
    const float2 adv = *(const float2*)&ad_[d * 2];

    float den0 = 0.f, den1 = 0.f;
    float qa00 = 0.f, qa01 = 0.f, qa10 = 0.f, qa11 = 0.f;
    for (int k = r0 + lane; k < r1; k += 64) {
        const int s = srcs[k];
        const float2 a = *(const float2*)&as_[s * 2];
        const float4 q = *(const float4*)&qv[s * 4];
        const float p0 = __expf(lrelu(a.x + adv.x));
        const float p1 = __expf(lrelu(a.y + adv.y));
        den0 += p0; den1 += p1;
        qa00 = fmaf(p0, q.x, qa00); qa01 = fmaf(p0, q.y, qa01);
        qa10 = fmaf(p1, q.z, qa10); qa11 = fmaf(p1, q.w, qa11);
    }
    den0 = wsum(den0); den1 = wsum(den1);
    qa00 = wsum(qa00); qa01 = wsum(qa01);
    qa10 = wsum(qa10); qa11 = wsum(qa11);
    if (lane == 0) {
        const float i0 = 1.f / (den0 + 1e-16f);
        const float i1 = 1.f / (den1 + 1e-16f);
        out[d * 2 + 0] = cst[0] + 0.5f * (qa00 * i0 + qa10 * i1);
        out[d * 2 + 1] = cst[1] + 0.5f * (qa01 * i0 + qa11 * i1);
    }
}

extern "C" void kernel_launch(void* const* d_in, const int* in_sizes, int n_in,
                              void* d_out, int out_size, void* d_ws, size_t ws_size,
                              hipStream_t stream) {
    const float* x      = (const float*)d_in[0];
    const int*   ei     = (const int*)d_in[1];
    const float* w1     = (const float*)d_in[2];
    const float* a_src1 = (const float*)d_in[3];
    const float* a_dst1 = (const float*)d_in[4];
    const float* b1     = (const float*)d_in[5];
    const float* g1     = (const float*)d_in[6];
    const float* be1    = (const float*)d_in[7];
    const float* m1     = (const float*)d_in[8];
    const float* v1     = (const float*)d_in[9];
    const float* w2     = (const float*)d_in[10];
    const float* a_src2 = (const float*)d_in[11];
    const float* a_dst2 = (const float*)d_in[12];
    const float* b2     = (const float*)d_in[13];
    const float* g2     = (const float*)d_in[14];
    const float* be2    = (const float*)d_in[15];
    const float* m2     = (const float*)d_in[16];
    const float* v2     = (const float*)d_in[17];
    const float* wc     = (const float*)d_in[18];
    const float* bc     = (const float*)d_in[19];
    float* out = (float*)d_out;

    float* ws = (float*)d_ws;
    const size_t NA = (size_t)NN * 256;
    float* A = ws;            // h1 as fp16 (occupies first NA/2 floats)
    float* B = ws + NA;       // agg1 (NN*256 fp32)
    float* C = ws + 2 * NA;   // aux

    float* as1 = C;                       // NN*4
    float* ad1 = C + (size_t)NN * 4;      // NN*4
    float* as2 = C + (size_t)NN * 8;      // NN*2
    float* ad2 = C + (size_t)NN * 10;     // NN*2
    float* qv  = C + (size_t)NN * 12;     // NN*4
    float* scs = C + (size_t)NN * 16;     // 256
    float* shs = scs + 256;               // 256
    float* wq  = shs + 256;               // 128
    float* cst = wq + 128;                // 2 (+pad)
    int* counts = (int*)(cst + 64);       // NN (reused as cursor)
    int* rowptr = counts + NN;            // NN+1
    int* bsum   = rowptr + NN + 63;       // 512
    int* srcs   = bsum + 512;             // ETOT

    __half* h1 = (__half*)A;
    float* agg1 = B;

    // ---- CSR build ----
    k_count_init<<<NBLK, 256, 0, stream>>>(counts);
    k_hist<<<(EE + 255) / 256, 256, 0, stream>>>(ei, counts);
    k_scan_bsum<<<NBLK, 256, 0, stream>>>(counts, bsum);
    k_scan_top<<<1, 512, 0, stream>>>(bsum, NBLK);
    k_scan_final<<<NBLK, 256, 0, stream>>>(counts, bsum, rowptr);
    k_self<<<NBLK, 256, 0, stream>>>(rowptr, srcs, counts);
    k_scatter<<<(EE + 255) / 256, 256, 0, stream>>>(ei, srcs, counts);
    k_bnprep<<<1, 256, 0, stream>>>(b1, g1, be1, m1, v1, scs, shs);
    k_prep2<<<1, 64, 0, stream>>>(b2, g2, be2, m2, v2, wc, bc, wq, cst);

    // ---- layer 1 ----
    dim3 g1grid((NN + 63) / 64, 4);
    k_gemm1<<<g1grid, 256, 0, stream>>>(x, w1, a_src1, a_dst1, h1, as1, ad1);
    k_agg1<<<(NN + 3) / 4, 256, 0, stream>>>(rowptr, srcs, h1, as1, ad1, agg1);

    // ---- layer 2 ----
    dim3 g2grid((NN + 63) / 64, 2);
    k_gemm2<<<g2grid, 256, 0, stream>>>(agg1, scs, shs, w2, a_src2, a_dst2, wq,
                                        as2, ad2, qv);
    k_agg2q<<<(NN + 3) / 4, 256, 0, stream>>>(rowptr, srcs, as2, ad2, qv, cst, out);
}

// Round 7
// 580.683 us; speedup vs baseline: 16.5876x; 1.1382x over previous
//
#include <hip/hip_runtime.h>
#include <hip/hip_fp16.h>
#include <math.h>

#define NN 100000
#define EE 1600000
#define ETOT (EE + NN)
#define BN_EPS 1e-5f
#define NEG_SLOPE 0.2f
#define NBLK ((NN + 255) / 256)   // 391
#define MTILE 128
#define GX ((NN + MTILE - 1) / MTILE)   // 782

// ---------- helpers ----------
__device__ __forceinline__ float lrelu(float x) { return fmaxf(x, NEG_SLOPE * x); }
__device__ __forceinline__ float wsum(float v) {
#pragma unroll
    for (int m = 32; m; m >>= 1) v += __shfl_xor(v, m, 64);
    return v;
}
__device__ __forceinline__ float gsum16(float v) {
#pragma unroll
    for (int m = 1; m < 16; m <<= 1) v += __shfl_xor(v, m, 64);
    return v;
}
__device__ __forceinline__ float gsum8(float v) {
#pragma unroll
    for (int m = 1; m < 8; m <<= 1) v += __shfl_xor(v, m, 64);
    return v;
}
__device__ __forceinline__ float sel4(float4 v, int i) {
    float lo = (i & 1) ? v.y : v.x;
    float hi = (i & 1) ? v.w : v.z;
    return (i & 2) ? hi : lo;
}

// ================= CSR build =================
__global__ __launch_bounds__(256) void k_count_init(int* __restrict__ counts) {
    const int n = blockIdx.x * 256 + threadIdx.x;
    if (n < NN) counts[n] = 1;                       // self-loop
}
__global__ __launch_bounds__(256) void k_hist(const int* __restrict__ ei,
                                              int* __restrict__ counts) {
    const int e = blockIdx.x * 256 + threadIdx.x;
    if (e < EE) atomicAdd(&counts[ei[EE + e]], 1);
}
__global__ __launch_bounds__(256) void k_scan_bsum(const int* __restrict__ counts,
                                                   int* __restrict__ bsum) {
    __shared__ int sd[256];
    const int i = blockIdx.x * 256 + threadIdx.x;
    sd[threadIdx.x] = (i < NN) ? counts[i] : 0;
    __syncthreads();
    for (int s2 = 128; s2; s2 >>= 1) {
        if (threadIdx.x < s2) sd[threadIdx.x] += sd[threadIdx.x + s2];
        __syncthreads();
    }
    if (threadIdx.x == 0) bsum[blockIdx.x] = sd[0];
}
__global__ __launch_bounds__(512) void k_scan_top(int* __restrict__ bsum, int nb) {
    __shared__ int sd[512];
    const int t = threadIdx.x;
    const int orig = (t < nb) ? bsum[t] : 0;
    sd[t] = orig;
    __syncthreads();
    for (int off = 1; off < 512; off <<= 1) {
        const int v = (t >= off) ? sd[t - off] : 0;
        __syncthreads();
        sd[t] += v;
        __syncthreads();
    }
    if (t < nb) bsum[t] = sd[t] - orig;              // exclusive
}
__global__ __launch_bounds__(256) void k_scan_final(const int* __restrict__ counts,
                                                    const int* __restrict__ bsum_ex,
                                                    int* __restrict__ rowptr) {
    __shared__ int sd[256];
    const int i = blockIdx.x * 256 + threadIdx.x;
    const int orig = (i < NN) ? counts[i] : 0;
    sd[threadIdx.x] = orig;
    __syncthreads();
    for (int off = 1; off < 256; off <<= 1) {
        const int v = (threadIdx.x >= off) ? sd[threadIdx.x - off] : 0;
        __syncthreads();
        sd[threadIdx.x] += v;
        __syncthreads();
    }
    if (i < NN) rowptr[i] = bsum_ex[blockIdx.x] + sd[threadIdx.x] - orig;
    if (i == NN - 1) rowptr[NN] = ETOT;
}
__global__ __launch_bounds__(256) void k_self(const int* __restrict__ rowptr,
                                              int* __restrict__ srcs,
                                              int* __restrict__ cursor) {
    const int n = blockIdx.x * 256 + threadIdx.x;
    if (n < NN) { const int p = rowptr[n]; srcs[p] = n; cursor[n] = p + 1; }
}
__global__ __launch_bounds__(256) void k_scatter(const int* __restrict__ ei,
                                                 int* __restrict__ srcs,
                                                 int* __restrict__ cursor) {
    const int e = blockIdx.x * 256 + threadIdx.x;
    if (e < EE) {
        const int d = ei[EE + e];
        const int p = atomicAdd(&cursor[d], 1);
        srcs[p] = ei[e];
    }
}

// ================= BN1 scale/shift precompute =================
__global__ __launch_bounds__(256) void k_bnprep(
    const float* __restrict__ b1, const float* __restrict__ g1,
    const float* __restrict__ be1, const float* __restrict__ m1,
    const float* __restrict__ v1, float* __restrict__ scs, float* __restrict__ shs)
{
    const int k = threadIdx.x;                       // 256 == LH*HID
    const float sc = g1[k] * rsqrtf(v1[k] + BN_EPS);
    scs[k] = sc;
    shs[k] = (b1[k] - m1[k]) * sc + be1[k];
}

// ================= BN2/classifier collapse: wq[c][2]=s2*wc, cst = bc + const =====
__global__ __launch_bounds__(64) void k_prep2(
    const float* __restrict__ b2, const float* __restrict__ g2,
    const float* __restrict__ be2, const float* __restrict__ m2,
    const float* __restrict__ v2, const float* __restrict__ wc,
    const float* __restrict__ bc, float* __restrict__ wq, float* __restrict__ cst)
{
    const int c = threadIdx.x;                       // 0..63
    const float s2 = g2[c] * rsqrtf(v2[c] + BN_EPS);
    wq[c * 2 + 0] = s2 * wc[c * 2 + 0];
    wq[c * 2 + 1] = s2 * wc[c * 2 + 1];
    const float t = (b2[c] - m2[c]) * s2 + be2[c];
    const float c0 = wsum(t * wc[c * 2 + 0]);
    const float c1 = wsum(t * wc[c * 2 + 1]);
    if (c == 0) { cst[0] = c0 + bc[0]; cst[1] = c1 + bc[1]; }
}

// ================= GEMM1: h1(fp16) = x @ w1 [K=128 -> N=256] + att coefficients ====
// grid (GX, 2); block 256 = 16x16; 128x128 tile; 8x8 per-thread register tile.
__global__ __launch_bounds__(256) void k_gemm1(
    const float* __restrict__ x, const float* __restrict__ w,
    const float* __restrict__ asrc, const float* __restrict__ adst,
    __half* __restrict__ h, float* __restrict__ as_, float* __restrict__ ad_)
{
    __shared__ float xs[64][128];    // [k][m]
    __shared__ float wsd[64][128];   // [k][j]
    const int n0 = blockIdx.x * MTILE;
    const int yt = blockIdx.y;
    const int jbase = yt * 128;
    const int t = threadIdx.x;
    const int tx = t & 15, ty = t >> 4;

    float acc[8][8];
#pragma unroll
    for (int r = 0; r < 8; ++r)
#pragma unroll
        for (int c = 0; c < 8; ++c) acc[r][c] = 0.f;

    for (int kc = 0; kc < 2; ++kc) {
        if (kc) __syncthreads();
        {   // stage x chunk transposed: xs[k][m]
            const int m = t & 127;
            const int ng = n0 + m;
            const bool ok = ng < NN;
            const int kq0 = (t >> 7) * 8;
#pragma unroll
            for (int kk = 0; kk < 8; ++kk) {
                const int kq = kq0 + kk;
                const float4 v = ok
                    ? *(const float4*)&x[(size_t)ng * 128 + kc * 64 + kq * 4]
                    : make_float4(0.f, 0.f, 0.f, 0.f);
                xs[kq * 4 + 0][m] = v.x;
                xs[kq * 4 + 1][m] = v.y;
                xs[kq * 4 + 2][m] = v.z;
                xs[kq * 4 + 3][m] = v.w;
            }
        }
        {   // stage w chunk: wsd[k][j]
            const int j4 = t & 31;
            const int k0 = t >> 5;
#pragma unroll
            for (int kk = 0; kk < 8; ++kk) {
                const int k = k0 + kk * 8;
                *(float4*)&wsd[k][j4 * 4] =
                    *(const float4*)&w[(size_t)(kc * 64 + k) * 256 + jbase + j4 * 4];
            }
        }
        __syncthreads();

        const float* ap = &xs[0][ty * 8];
        const float* bp = &wsd[0][tx * 8];
#pragma unroll 2
        for (int k = 0; k < 64; ++k) {
            float a[8], b[8];
            *(float4*)&a[0] = *(const float4*)(ap + k * 128);
            *(float4*)&a[4] = *(const float4*)(ap + k * 128 + 4);
            *(float4*)&b[0] = *(const float4*)(bp + k * 128);
            *(float4*)&b[4] = *(const float4*)(bp + k * 128 + 4);
#pragma unroll
            for (int r = 0; r < 8; ++r)
#pragma unroll
                for (int c = 0; c < 8; ++c)
                    acc[r][c] = fmaf(a[r], b[c], acc[r][c]);
        }
    }

    // epilogue
    const int j0g = jbase + tx * 8;
    const int head = j0g >> 6;
    float aw[8], dw[8];
#pragma unroll
    for (int c = 0; c < 8; ++c) { aw[c] = asrc[j0g + c]; dw[c] = adst[j0g + c]; }
#pragma unroll
    for (int r = 0; r < 8; ++r) {
        const int ng = n0 + ty * 8 + r;
        const bool ok = ng < NN;
        if (ok) {
            __half2 h0 = __float22half2_rn(make_float2(acc[r][0], acc[r][1]));
            __half2 h1v = __float22half2_rn(make_float2(acc[r][2], acc[r][3]));
            __half2 h2v = __float22half2_rn(make_float2(acc[r][4], acc[r][5]));
            __half2 h3v = __float22half2_rn(make_float2(acc[r][6], acc[r][7]));
            uint4 u;
            u.x = *reinterpret_cast<unsigned*>(&h0);
            u.y = *reinterpret_cast<unsigned*>(&h1v);
            u.z = *reinterpret_cast<unsigned*>(&h2v);
            u.w = *reinterpret_cast<unsigned*>(&h3v);
            *reinterpret_cast<uint4*>(&h[(size_t)ng * 256 + j0g]) = u;
        }
        float s = 0.f, d = 0.f;
#pragma unroll
        for (int c = 0; c < 8; ++c) {
            s = fmaf(acc[r][c], aw[c], s);
            d = fmaf(acc[r][c], dw[c], d);
        }
        s = gsum8(s);
        d = gsum8(d);
        if ((tx & 7) == 0 && ok) {
            as_[ng * 4 + head] = s;
            ad_[ng * 4 + head] = d;
        }
    }
}

// ================= GEMM2: (BN1+ELU)(agg1) @ w2 [K=256 -> N=128] -> {as2,ad2,q} =====
// grid (GX); block 256 = 16x16; 128x128 tile; 8x8 per-thread; h2 never stored.
__global__ __launch_bounds__(256) void k_gemm2(
    const float* __restrict__ agg, const float* __restrict__ scs,
    const float* __restrict__ shs, const float* __restrict__ w,
    const float* __restrict__ asrc, const float* __restrict__ adst,
    const float* __restrict__ wq,
    float* __restrict__ as_, float* __restrict__ ad_, float* __restrict__ qv)
{
    __shared__ float xs[64][128];    // [k][m]
    __shared__ float wsd[64][128];   // [k][j]
    const int n0 = blockIdx.x * MTILE;
    const int t = threadIdx.x;
    const int tx = t & 15, ty = t >> 4;

    float acc[8][8];
#pragma unroll
    for (int r = 0; r < 8; ++r)
#pragma unroll
        for (int c = 0; c < 8; ++c) acc[r][c] = 0.f;

    for (int kc = 0; kc < 4; ++kc) {
        if (kc) __syncthreads();
        {   // stage agg1 chunk with BN1 + ELU (fast exp), transposed
            const int m = t & 127;
            const int ng = n0 + m;
            const bool ok = ng < NN;
            const int kq0 = (t >> 7) * 8;
#pragma unroll
            for (int kk = 0; kk < 8; ++kk) {
                const int kq = kq0 + kk;
                const int kg = kc * 64 + kq * 4;
                const float4 v = ok
                    ? *(const float4*)&agg[(size_t)ng * 256 + kg]
                    : make_float4(0.f, 0.f, 0.f, 0.f);
                const float4 sc = *(const float4*)&scs[kg];
                const float4 sh = *(const float4*)&shs[kg];
                const float e0 = fmaf(v.x, sc.x, sh.x);
                const float e1 = fmaf(v.y, sc.y, sh.y);
                const float e2 = fmaf(v.z, sc.z, sh.z);
                const float e3 = fmaf(v.w, sc.w, sh.w);
                xs[kq * 4 + 0][m] = e0 > 0.f ? e0 : __expf(e0) - 1.f;
                xs[kq * 4 + 1][m] = e1 > 0.f ? e1 : __expf(e1) - 1.f;
                xs[kq * 4 + 2][m] = e2 > 0.f ? e2 : __expf(e2) - 1.f;
                xs[kq * 4 + 3][m] = e3 > 0.f ? e3 : __expf(e3) - 1.f;
            }
        }
        {   // stage w2 chunk
            const int j4 = t & 31;
            const int k0 = t >> 5;
#pragma unroll
            for (int kk = 0; kk < 8; ++kk) {
                const int k = k0 + kk * 8;
                *(float4*)&wsd[k][j4 * 4] =
                    *(const float4*)&w[(size_t)(kc * 64 + k) * 128 + j4 * 4];
            }
        }
        __syncthreads();

        const float* ap = &xs[0][ty * 8];
        const float* bp = &wsd[0][tx * 8];
#pragma unroll 2
        for (int k = 0; k < 64; ++k) {
            float a[8], b[8];
            *(float4*)&a[0] = *(const float4*)(ap + k * 128);
            *(float4*)&a[4] = *(const float4*)(ap + k * 128 + 4);
            *(float4*)&b[0] = *(const float4*)(bp + k * 128);
            *(float4*)&b[4] = *(const float4*)(bp + k * 128 + 4);
#pragma unroll
            for (int r = 0; r < 8; ++r)
#pragma unroll
                for (int c = 0; c < 8; ++c)
                    acc[r][c] = fmaf(a[r], b[c], acc[r][c]);
        }
    }

    // epilogue: as2/ad2/q only
    const int j0 = tx * 8;
    const int head = tx >> 3;
    const int cl = (tx & 7) * 8;                      // head-local col base
    float aw[8], dw[8], wq0[8], wq1[8];
#pragma unroll
    for (int c = 0; c < 8; ++c) {
        aw[c] = asrc[j0 + c];
        dw[c] = adst[j0 + c];
        wq0[c] = wq[(cl + c) * 2 + 0];
        wq1[c] = wq[(cl + c) * 2 + 1];
    }
#pragma unroll
    for (int r = 0; r < 8; ++r) {
        const int ng = n0 + ty * 8 + r;
        float s = 0.f, d = 0.f, q0 = 0.f, q1 = 0.f;
#pragma unroll
        for (int c = 0; c < 8; ++c) {
            s = fmaf(acc[r][c], aw[c], s);
            d = fmaf(acc[r][c], dw[c], d);
            q0 = fmaf(acc[r][c], wq0[c], q0);
            q1 = fmaf(acc[r][c], wq1[c], q1);
        }
        s = gsum8(s);
        d = gsum8(d);
        q0 = gsum8(q0);
        q1 = gsum8(q1);
        if ((tx & 7) == 0 && ng < NN) {
            as_[ng * 2 + head] = s;
            ad_[ng * 2 + head] = d;
            qv[ng * 4 + head * 2 + 0] = q0;
            qv[ng * 4 + head * 2 + 1] = q1;
        }
    }
}

// ================= layer-1 aggregation: single-pass shift-free softmax =============
// one wave per dst node; 2 edges/iter (one per 32-lane half); p computed per lane.
__global__ __launch_bounds__(256) void k_agg1(
    const int* __restrict__ rowptr, const int* __restrict__ srcs,
    const __half* __restrict__ hf, const float* __restrict__ as_,
    const float* __restrict__ ad_, float* __restrict__ outp)
{
    const int d = blockIdx.x * 4 + (threadIdx.x >> 6);
    if (d >= NN) return;
    const int lane = threadIdx.x & 63;
    const int r0 = rowptr[d], r1 = rowptr[d + 1];
    const int g = lane >> 5, wl = lane & 31;
    const int headw = wl >> 3;                        // head of this lane's col block
    const float4 adv = *(const float4*)&ad_[d * 4];
    const float myad = sel4(adv, headw);
    const __half* hbase = hf + wl * 8;

    float den = 0.f;
    float acc[8] = {0.f, 0.f, 0.f, 0.f, 0.f, 0.f, 0.f, 0.f};
    for (int k = r0 + g; k < r1; k += 2) {
        const int s = srcs[k];
        const float p = __expf(lrelu(as_[s * 4 + headw] + myad));
        den += p;
        const uint4 u = *reinterpret_cast<const uint4*>(hbase + (size_t)s * 256);
        const float2 f0 = __half22float2(*reinterpret_cast<const __half2*>(&u.x));
        const float2 f1 = __half22float2(*reinterpret_cast<const __half2*>(&u.y));
        const float2 f2 = __half22float2(*reinterpret_cast<const __half2*>(&u.z));
        const float2 f3 = __half22float2(*reinterpret_cast<const __half2*>(&u.w));
        acc[0] = fmaf(p, f0.x, acc[0]); acc[1] = fmaf(p, f0.y, acc[1]);
        acc[2] = fmaf(p, f1.x, acc[2]); acc[3] = fmaf(p, f1.y, acc[3]);
        acc[4] = fmaf(p, f2.x, acc[4]); acc[5] = fmaf(p, f2.y, acc[5]);
        acc[6] = fmaf(p, f3.x, acc[6]); acc[7] = fmaf(p, f3.y, acc[7]);
    }
    den += __shfl_xor(den, 32, 64);                   // combine halves
    const float inv = 1.f / (den + 1e-16f);
#pragma unroll
    for (int i = 0; i < 8; ++i)
        acc[i] = (acc[i] + __shfl_xor(acc[i], 32, 64)) * inv;
    float* op = &outp[(size_t)d * 256 + wl * 8 + g * 4];
    if (g == 0) *(float4*)op = make_float4(acc[0], acc[1], acc[2], acc[3]);
    else        *(float4*)op = make_float4(acc[4], acc[5], acc[6], acc[7]);
}

// ================= layer-2: single-pass softmax over q; 16 lanes per node ==========
__global__ __launch_bounds__(256) void k_agg2q(
    const int* __restrict__ rowptr, const int* __restrict__ srcs,
    const float* __restrict__ as_, const float* __restrict__ ad_,
    const float* __restrict__ qv, const float* __restrict__ cst,
    float* __restrict__ out)
{
    const int d = blockIdx.x * 16 + (threadIdx.x >> 4);
    if (d >= NN) return;
    const int il = threadIdx.x & 15;
    const int r0 = rowptr[d], r1 = rowptr[d + 1];
    const float2 adv = *(const float2*)&ad_[d * 2];

    float den0 = 0.f, den1 = 0.f;
    float qa00 = 0.f, qa01 = 0.f, qa10 = 0.f, qa11 = 0.f;
    for (int k = r0 + il; k < r1; k += 16) {
        const int s = srcs[k];
        const float2 a = *(const float2*)&as_[s * 2];
        const float4 q = *(const float4*)&qv[s * 4];
        const float p0 = __expf(lrelu(a.x + adv.x));
        const float p1 = __expf(lrelu(a.y + adv.y));
        den0 += p0; den1 += p1;
        qa00 = fmaf(p0, q.x, qa00); qa01 = fmaf(p0, q.y, qa01);
        qa10 = fmaf(p1, q.z, qa10); qa11 = fmaf(p1, q.w, qa11);
    }
    den0 = gsum16(den0); den1 = gsum16(den1);
    qa00 = gsum16(qa00); qa01 = gsum16(qa01);
    qa10 = gsum16(qa10); qa11 = gsum16(qa11);
    if (il == 0) {
        const float i0 = 1.f / (den0 + 1e-16f);
        const float i1 = 1.f / (den1 + 1e-16f);
        out[d * 2 + 0] = cst[0] + 0.5f * (qa00 * i0 + qa10 * i1);
        out[d * 2 + 1] = cst[1] + 0.5f * (qa01 * i0 + qa11 * i1);
    }
}

extern "C" void kernel_launch(void* const* d_in, const int* in_sizes, int n_in,
                              void* d_out, int out_size, void* d_ws, size_t ws_size,
                              hipStream_t stream) {
    const float* x      = (const float*)d_in[0];
    const int*   ei     = (const int*)d_in[1];
    const float* w1     = (const float*)d_in[2];
    const float* a_src1 = (const float*)d_in[3];
    const float* a_dst1 = (const float*)d_in[4];
    const float* b1     = (const float*)d_in[5];
    const float* g1     = (const float*)d_in[6];
    const float* be1    = (const float*)d_in[7];
    const float* m1     = (const float*)d_in[8];
    const float* v1     = (const float*)d_in[9];
    const float* w2     = (const float*)d_in[10];
    const float* a_src2 = (const float*)d_in[11];
    const float* a_dst2 = (const float*)d_in[12];
    const float* b2     = (const float*)d_in[13];
    const float* g2     = (const float*)d_in[14];
    const float* be2    = (const float*)d_in[15];
    const float* m2     = (const float*)d_in[16];
    const float* v2     = (const float*)d_in[17];
    const float* wc     = (const float*)d_in[18];
    const float* bc     = (const float*)d_in[19];
    float* out = (float*)d_out;

    float* ws = (float*)d_ws;
    const size_t NA = (size_t)NN * 256;
    float* A = ws;            // h1 as fp16 (first NA/2 floats)
    float* B = ws + NA;       // agg1 (NN*256 fp32)
    float* C = ws + 2 * NA;   // aux

    float* as1 = C;                       // NN*4
    float* ad1 = C + (size_t)NN * 4;      // NN*4
    float* as2 = C + (size_t)NN * 8;      // NN*2
    float* ad2 = C + (size_t)NN * 10;     // NN*2
    float* qv  = C + (size_t)NN * 12;     // NN*4
    float* scs = C + (size_t)NN * 16;     // 256
    float* shs = scs + 256;               // 256
    float* wq  = shs + 256;               // 128
    float* cst = wq + 128;                // 2 (+pad)
    int* counts = (int*)(cst + 64);       // NN (reused as cursor)
    int* rowptr = counts + NN;            // NN+1
    int* bsum   = rowptr + NN + 63;       // 512
    int* srcs   = bsum + 512;             // ETOT

    __half* h1 = (__half*)A;
    float* agg1 = B;

    // ---- CSR build ----
    k_count_init<<<NBLK, 256, 0, stream>>>(counts);
    k_hist<<<(EE + 255) / 256, 256, 0, stream>>>(ei, counts);
    k_scan_bsum<<<NBLK, 256, 0, stream>>>(counts, bsum);
    k_scan_top<<<1, 512, 0, stream>>>(bsum, NBLK);
    k_scan_final<<<NBLK, 256, 0, stream>>>(counts, bsum, rowptr);
    k_self<<<NBLK, 256, 0, stream>>>(rowptr, srcs, counts);
    k_scatter<<<(EE + 255) / 256, 256, 0, stream>>>(ei, srcs, counts);
    k_bnprep<<<1, 256, 0, stream>>>(b1, g1, be1, m1, v1, scs, shs);
    k_prep2<<<1, 64, 0, stream>>>(b2, g2, be2, m2, v2, wc, bc, wq, cst);

    // ---- layer 1 ----
    dim3 g1grid(GX, 2);
    k_gemm1<<<g1grid, 256, 0, stream>>>(x, w1, a_src1, a_dst1, h1, as1, ad1);
    k_agg1<<<(NN + 3) / 4, 256, 0, stream>>>(rowptr, srcs, h1, as1, ad1, agg1);

    // ---- layer 2 ----
    k_gemm2<<<GX, 256, 0, stream>>>(agg1, scs, shs, w2, a_src2, a_dst2, wq,
                                    as2, ad2, qv);
    k_agg2q<<<(NN + 15) / 16, 256, 0, stream>>>(rowptr, srcs, as2, ad2, qv, cst, out);
}

// Round 8
// 489.835 us; speedup vs baseline: 19.6640x; 1.1855x over previous
//
#include <hip/hip_runtime.h>
#include <hip/hip_fp16.h>
#include <math.h>

#define NN 100000
#define EE 1600000
#define ETOT (EE + NN)
#define BN_EPS 1e-5f
#define NEG_SLOPE 0.2f
#define NBLK ((NN + 255) / 256)   // 391
#define GXM ((NN + 127) / 128)    // 782

typedef _Float16 half8 __attribute__((ext_vector_type(8)));
typedef _Float16 half4v __attribute__((ext_vector_type(4)));
typedef float f32x4 __attribute__((ext_vector_type(4)));

// ---------- helpers ----------
__device__ __forceinline__ float lrelu(float x) { return fmaxf(x, NEG_SLOPE * x); }
__device__ __forceinline__ float wsum(float v) {
#pragma unroll
    for (int m = 32; m; m >>= 1) v += __shfl_xor(v, m, 64);
    return v;
}
__device__ __forceinline__ float gsum16(float v) {
#pragma unroll
    for (int m = 1; m < 16; m <<= 1) v += __shfl_xor(v, m, 64);
    return v;
}
__device__ __forceinline__ float sel4(float4 v, int i) {
    float lo = (i & 1) ? v.y : v.x;
    float hi = (i & 1) ? v.w : v.z;
    return (i & 2) ? hi : lo;
}

// ================= CSR build =================
__global__ __launch_bounds__(256) void k_count_init(int* __restrict__ counts) {
    const int n = blockIdx.x * 256 + threadIdx.x;
    if (n < NN) counts[n] = 1;                       // self-loop
}
__global__ __launch_bounds__(256) void k_hist(const int* __restrict__ ei,
                                              int* __restrict__ counts) {
    const int e = blockIdx.x * 256 + threadIdx.x;
    if (e < EE) atomicAdd(&counts[ei[EE + e]], 1);
}
__global__ __launch_bounds__(256) void k_scan_bsum(const int* __restrict__ counts,
                                                   int* __restrict__ bsum) {
    __shared__ int sd[256];
    const int i = blockIdx.x * 256 + threadIdx.x;
    sd[threadIdx.x] = (i < NN) ? counts[i] : 0;
    __syncthreads();
    for (int s2 = 128; s2; s2 >>= 1) {
        if (threadIdx.x < s2) sd[threadIdx.x] += sd[threadIdx.x + s2];
        __syncthreads();
    }
    if (threadIdx.x == 0) bsum[blockIdx.x] = sd[0];
}
__global__ __launch_bounds__(512) void k_scan_top(int* __restrict__ bsum, int nb) {
    __shared__ int sd[512];
    const int t = threadIdx.x;
    const int orig = (t < nb) ? bsum[t] : 0;
    sd[t] = orig;
    __syncthreads();
    for (int off = 1; off < 512; off <<= 1) {
        const int v = (t >= off) ? sd[t - off] : 0;
        __syncthreads();
        sd[t] += v;
        __syncthreads();
    }
    if (t < nb) bsum[t] = sd[t] - orig;              // exclusive
}
__global__ __launch_bounds__(256) void k_scan_final(const int* __restrict__ counts,
                                                    const int* __restrict__ bsum_ex,
                                                    int* __restrict__ rowptr) {
    __shared__ int sd[256];
    const int i = blockIdx.x * 256 + threadIdx.x;
    const int orig = (i < NN) ? counts[i] : 0;
    sd[threadIdx.x] = orig;
    __syncthreads();
    for (int off = 1; off < 256; off <<= 1) {
        const int v = (threadIdx.x >= off) ? sd[threadIdx.x - off] : 0;
        __syncthreads();
        sd[threadIdx.x] += v;
        __syncthreads();
    }
    if (i < NN) rowptr[i] = bsum_ex[blockIdx.x] + sd[threadIdx.x] - orig;
    if (i == NN - 1) rowptr[NN] = ETOT;
}
__global__ __launch_bounds__(256) void k_self(const int* __restrict__ rowptr,
                                              int* __restrict__ srcs,
                                              int* __restrict__ cursor) {
    const int n = blockIdx.x * 256 + threadIdx.x;
    if (n < NN) { const int p = rowptr[n]; srcs[p] = n; cursor[n] = p + 1; }
}
__global__ __launch_bounds__(256) void k_scatter(const int* __restrict__ ei,
                                                 int* __restrict__ srcs,
                                                 int* __restrict__ cursor) {
    const int e = blockIdx.x * 256 + threadIdx.x;
    if (e < EE) {
        const int d = ei[EE + e];
        const int p = atomicAdd(&cursor[d], 1);
        srcs[p] = ei[e];
    }
}

// ================= small prep =================
__global__ __launch_bounds__(256) void k_bnprep(
    const float* __restrict__ b1, const float* __restrict__ g1,
    const float* __restrict__ be1, const float* __restrict__ m1,
    const float* __restrict__ v1, float* __restrict__ scs, float* __restrict__ shs)
{
    const int k = threadIdx.x;                       // 256 == LH*HID
    const float sc = g1[k] * rsqrtf(v1[k] + BN_EPS);
    scs[k] = sc;
    shs[k] = (b1[k] - m1[k]) * sc + be1[k];
}
__global__ __launch_bounds__(64) void k_prep2(
    const float* __restrict__ b2, const float* __restrict__ g2,
    const float* __restrict__ be2, const float* __restrict__ m2,
    const float* __restrict__ v2, const float* __restrict__ wc,
    const float* __restrict__ bc, float* __restrict__ wq, float* __restrict__ cst)
{
    const int c = threadIdx.x;                       // 0..63
    const float s2 = g2[c] * rsqrtf(v2[c] + BN_EPS);
    wq[c * 2 + 0] = s2 * wc[c * 2 + 0];
    wq[c * 2 + 1] = s2 * wc[c * 2 + 1];
    const float t = (b2[c] - m2[c]) * s2 + be2[c];
    const float c0 = wsum(t * wc[c * 2 + 0]);
    const float c1 = wsum(t * wc[c * 2 + 1]);
    if (c == 0) { cst[0] = c0 + bc[0]; cst[1] = c1 + bc[1]; }
}
// wt1[n][k] = (fp16) w1[k][n]  (w1: [128][256])
__global__ __launch_bounds__(256) void k_wcvt1(const float* __restrict__ w,
                                               _Float16* __restrict__ wt) {
    const int idx = blockIdx.x * 256 + threadIdx.x;  // 32768
    const int n = idx >> 7, k = idx & 127;
    wt[idx] = (_Float16)w[k * 256 + n];
}
// wt2[n][k] = (fp16) w2[k][n]  (w2: [256][128])
__global__ __launch_bounds__(256) void k_wcvt2(const float* __restrict__ w,
                                               _Float16* __restrict__ wt) {
    const int idx = blockIdx.x * 256 + threadIdx.x;  // 32768
    const int n = idx >> 8, k = idx & 255;
    wt[idx] = (_Float16)w[k * 128 + n];
}

// ================= MFMA GEMM1: h1(fp16) = x @ w1 [100k x 128 -> x 256] ==========
// block 256 thr / 4 waves (2M x 2N), tile M=128 N=256; B-frags straight from L2.
__global__ __launch_bounds__(256) void k_gemm1m(
    const float* __restrict__ x, const _Float16* __restrict__ wt,   // wt[256][128]
    _Float16* __restrict__ h)
{
    __shared__ _Float16 xs[128][136];
    const int n0 = blockIdx.x * 128;
    const int t = threadIdx.x;

    const float* xbase = x + (size_t)n0 * 128;       // tile is contiguous
#pragma unroll
    for (int i = 0; i < 16; ++i) {
        const int f = i * 1024 + t * 4;
        const int m = f >> 7, k = f & 127;
        float4 v = make_float4(0.f, 0.f, 0.f, 0.f);
        if (n0 + m < NN) v = *(const float4*)(xbase + f);
        half4v hv = { (_Float16)v.x, (_Float16)v.y, (_Float16)v.z, (_Float16)v.w };
        *(half4v*)&xs[m][k] = hv;
    }
    __syncthreads();

    const int l = t & 63, w = t >> 6;
    const int m0w = (w & 1) * 64, n0w = (w >> 1) * 128;
    const int lc = l & 15, kq = (l >> 4) * 8;

    const f32x4 fzero = {0.f, 0.f, 0.f, 0.f};
    f32x4 acc[4][8];
#pragma unroll
    for (int r = 0; r < 4; ++r)
#pragma unroll
        for (int c = 0; c < 8; ++c) acc[r][c] = fzero;

#pragma unroll
    for (int ks = 0; ks < 4; ++ks) {
        const int k0 = ks * 32 + kq;
        const half8 a0 = *(const half8*)&xs[m0w + 0  + lc][k0];
        const half8 a1 = *(const half8*)&xs[m0w + 16 + lc][k0];
        const half8 a2 = *(const half8*)&xs[m0w + 32 + lc][k0];
        const half8 a3 = *(const half8*)&xs[m0w + 48 + lc][k0];
#pragma unroll
        for (int c = 0; c < 8; ++c) {
            const half8 b = *(const half8*)&wt[(size_t)(n0w + c * 16 + lc) * 128 + k0];
            acc[0][c] = __builtin_amdgcn_mfma_f32_16x16x32_f16(a0, b, acc[0][c], 0, 0, 0);
            acc[1][c] = __builtin_amdgcn_mfma_f32_16x16x32_f16(a1, b, acc[1][c], 0, 0, 0);
            acc[2][c] = __builtin_amdgcn_mfma_f32_16x16x32_f16(a2, b, acc[2][c], 0, 0, 0);
            acc[3][c] = __builtin_amdgcn_mfma_f32_16x16x32_f16(a3, b, acc[3][c], 0, 0, 0);
        }
    }

    const int lr = (l >> 4) * 4;                     // D: row=(l>>4)*4+reg, col=l&15
#pragma unroll
    for (int r = 0; r < 4; ++r) {
#pragma unroll
        for (int i = 0; i < 4; ++i) {
            const int rg = n0 + m0w + r * 16 + lr + i;
            if (rg < NN) {
                _Float16* hp = h + (size_t)rg * 256 + n0w + lc;
#pragma unroll
                for (int c = 0; c < 8; ++c)
                    hp[c * 16] = (_Float16)acc[r][c][i];
            }
        }
    }
}

// ================= MFMA GEMM2: h2(fp16) = ELU(BN1(agg1)) @ w2 [K=256 -> N=128] =====
__global__ __launch_bounds__(256) void k_gemm2m(
    const float* __restrict__ agg, const float* __restrict__ scs,
    const float* __restrict__ shs, const _Float16* __restrict__ wt, // wt[128][256]
    _Float16* __restrict__ h)
{
    __shared__ _Float16 xs[128][136];
    const int n0 = blockIdx.x * 128;
    const int t = threadIdx.x;
    const int l = t & 63, w = t >> 6;
    const int m0w = (w & 1) * 64, n0w = (w >> 1) * 64;
    const int lc = l & 15, kq = (l >> 4) * 8;

    const f32x4 fzero = {0.f, 0.f, 0.f, 0.f};
    f32x4 acc[4][4];
#pragma unroll
    for (int r = 0; r < 4; ++r)
#pragma unroll
        for (int c = 0; c < 4; ++c) acc[r][c] = fzero;

    const float* abase = agg + (size_t)n0 * 256;
    for (int kc = 0; kc < 2; ++kc) {
        if (kc) __syncthreads();
#pragma unroll
        for (int i = 0; i < 16; ++i) {
            const int f = i * 1024 + t * 4;
            const int m = f >> 7, k4 = f & 127;
            const int kg = kc * 128 + k4;
            float4 v = make_float4(0.f, 0.f, 0.f, 0.f);
            if (n0 + m < NN) v = *(const float4*)(abase + (size_t)m * 256 + kg);
            const float4 sc = *(const float4*)&scs[kg];
            const float4 sh = *(const float4*)&shs[kg];
            float e0 = fmaf(v.x, sc.x, sh.x);
            float e1 = fmaf(v.y, sc.y, sh.y);
            float e2 = fmaf(v.z, sc.z, sh.z);
            float e3 = fmaf(v.w, sc.w, sh.w);
            e0 = e0 > 0.f ? e0 : __expf(e0) - 1.f;
            e1 = e1 > 0.f ? e1 : __expf(e1) - 1.f;
            e2 = e2 > 0.f ? e2 : __expf(e2) - 1.f;
            e3 = e3 > 0.f ? e3 : __expf(e3) - 1.f;
            half4v hv = { (_Float16)e0, (_Float16)e1, (_Float16)e2, (_Float16)e3 };
            *(half4v*)&xs[m][k4] = hv;
        }
        __syncthreads();

#pragma unroll
        for (int ks = 0; ks < 4; ++ks) {
            const int k0 = ks * 32 + kq;             // LDS-local k
            const int kgf = kc * 128 + k0;           // global k for B
            const half8 a0 = *(const half8*)&xs[m0w + 0  + lc][k0];
            const half8 a1 = *(const half8*)&xs[m0w + 16 + lc][k0];
            const half8 a2 = *(const half8*)&xs[m0w + 32 + lc][k0];
            const half8 a3 = *(const half8*)&xs[m0w + 48 + lc][k0];
#pragma unroll
            for (int c = 0; c < 4; ++c) {
                const half8 b = *(const half8*)&wt[(size_t)(n0w + c * 16 + lc) * 256 + kgf];
                acc[0][c] = __builtin_amdgcn_mfma_f32_16x16x32_f16(a0, b, acc[0][c], 0, 0, 0);
                acc[1][c] = __builtin_amdgcn_mfma_f32_16x16x32_f16(a1, b, acc[1][c], 0, 0, 0);
                acc[2][c] = __builtin_amdgcn_mfma_f32_16x16x32_f16(a2, b, acc[2][c], 0, 0, 0);
                acc[3][c] = __builtin_amdgcn_mfma_f32_16x16x32_f16(a3, b, acc[3][c], 0, 0, 0);
            }
        }
    }

    const int lr = (l >> 4) * 4;
#pragma unroll
    for (int r = 0; r < 4; ++r) {
#pragma unroll
        for (int i = 0; i < 4; ++i) {
            const int rg = n0 + m0w + r * 16 + lr + i;
            if (rg < NN) {
                _Float16* hp = h + (size_t)rg * 128 + n0w + lc;
#pragma unroll
                for (int c = 0; c < 4; ++c)
                    hp[c * 16] = (_Float16)acc[r][c][i];
            }
        }
    }
}

// ================= coefficient kernels =================
// as1/ad1 from h1 (16 lanes per node, 16 cols each; head = j>>2)
__global__ __launch_bounds__(256) void k_coef1(
    const _Float16* __restrict__ h, const float* __restrict__ asrc,
    const float* __restrict__ adst, float* __restrict__ as_, float* __restrict__ ad_)
{
    const int gid = blockIdx.x * 256 + threadIdx.x;
    const int n = gid >> 4;
    if (n >= NN) return;
    const int j = gid & 15;
    const int c0 = j * 16;
    const half8 u0 = *(const half8*)&h[(size_t)n * 256 + c0];
    const half8 u1 = *(const half8*)&h[(size_t)n * 256 + c0 + 8];
    float s = 0.f, d = 0.f;
#pragma unroll
    for (int i = 0; i < 8; ++i) {
        const float f0 = (float)u0[i], f1 = (float)u1[i];
        s = fmaf(f0, asrc[c0 + i], fmaf(f1, asrc[c0 + 8 + i], s));
        d = fmaf(f0, adst[c0 + i], fmaf(f1, adst[c0 + 8 + i], d));
    }
    s += __shfl_xor(s, 1, 64); s += __shfl_xor(s, 2, 64);
    d += __shfl_xor(d, 1, 64); d += __shfl_xor(d, 2, 64);
    if ((j & 3) == 0) {
        as_[n * 4 + (j >> 2)] = s;
        ad_[n * 4 + (j >> 2)] = d;
    }
}
// as2/ad2/qv from h2 (16 lanes per node, 8 cols each; head = j>>3)
__global__ __launch_bounds__(256) void k_coef2(
    const _Float16* __restrict__ h, const float* __restrict__ asrc,
    const float* __restrict__ adst, const float* __restrict__ wq,
    float* __restrict__ as_, float* __restrict__ ad_, float* __restrict__ qv)
{
    const int gid = blockIdx.x * 256 + threadIdx.x;
    const int n = gid >> 4;
    if (n >= NN) return;
    const int j = gid & 15;
    const int c0 = j * 8;
    const half8 u = *(const half8*)&h[(size_t)n * 128 + c0];
    float s = 0.f, d = 0.f, q0 = 0.f, q1 = 0.f;
#pragma unroll
    for (int i = 0; i < 8; ++i) {
        const float f = (float)u[i];
        const int cl = (c0 + i) & 63;
        s = fmaf(f, asrc[c0 + i], s);
        d = fmaf(f, adst[c0 + i], d);
        q0 = fmaf(f, wq[cl * 2 + 0], q0);
        q1 = fmaf(f, wq[cl * 2 + 1], q1);
    }
    s += __shfl_xor(s, 1, 64);  s += __shfl_xor(s, 2, 64);  s += __shfl_xor(s, 4, 64);
    d += __shfl_xor(d, 1, 64);  d += __shfl_xor(d, 2, 64);  d += __shfl_xor(d, 4, 64);
    q0 += __shfl_xor(q0, 1, 64); q0 += __shfl_xor(q0, 2, 64); q0 += __shfl_xor(q0, 4, 64);
    q1 += __shfl_xor(q1, 1, 64); q1 += __shfl_xor(q1, 2, 64); q1 += __shfl_xor(q1, 4, 64);
    if ((j & 7) == 0) {
        const int hh = j >> 3;
        as_[n * 2 + hh] = s;
        ad_[n * 2 + hh] = d;
        qv[n * 4 + hh * 2 + 0] = q0;
        qv[n * 4 + hh * 2 + 1] = q1;
    }
}

// ================= layer-1 aggregation: single-pass shift-free softmax =============
__global__ __launch_bounds__(256) void k_agg1(
    const int* __restrict__ rowptr, const int* __restrict__ srcs,
    const __half* __restrict__ hf, const float* __restrict__ as_,
    const float* __restrict__ ad_, float* __restrict__ outp)
{
    const int d = blockIdx.x * 4 + (threadIdx.x >> 6);
    if (d >= NN) return;
    const int lane = threadIdx.x & 63;
    const int r0 = rowptr[d], r1 = rowptr[d + 1];
    const int g = lane >> 5, wl = lane & 31;
    const int headw = wl >> 3;
    const float4 adv = *(const float4*)&ad_[d * 4];
    const float myad = sel4(adv, headw);
    const __half* hbase = hf + wl * 8;

    float den = 0.f;
    float acc[8] = {0.f, 0.f, 0.f, 0.f, 0.f, 0.f, 0.f, 0.f};
    for (int k = r0 + g; k < r1; k += 2) {
        const int s = srcs[k];
        const float p = __expf(lrelu(as_[s * 4 + headw] + myad));
        den += p;
        const uint4 u = *reinterpret_cast<const uint4*>(hbase + (size_t)s * 256);
        const float2 f0 = __half22float2(*reinterpret_cast<const __half2*>(&u.x));
        const float2 f1 = __half22float2(*reinterpret_cast<const __half2*>(&u.y));
        const float2 f2 = __half22float2(*reinterpret_cast<const __half2*>(&u.z));
        const float2 f3 = __half22float2(*reinterpret_cast<const __half2*>(&u.w));
        acc[0] = fmaf(p, f0.x, acc[0]); acc[1] = fmaf(p, f0.y, acc[1]);
        acc[2] = fmaf(p, f1.x, acc[2]); acc[3] = fmaf(p, f1.y, acc[3]);
        acc[4] = fmaf(p, f2.x, acc[4]); acc[5] = fmaf(p, f2.y, acc[5]);
        acc[6] = fmaf(p, f3.x, acc[6]); acc[7] = fmaf(p, f3.y, acc[7]);
    }
    den += __shfl_xor(den, 32, 64);
    const float inv = 1.f / (den + 1e-16f);
#pragma unroll
    for (int i = 0; i < 8; ++i)
        acc[i] = (acc[i] + __shfl_xor(acc[i], 32, 64)) * inv;
    float* op = &outp[(size_t)d * 256 + wl * 8 + g * 4];
    if (g == 0) *(float4*)op = make_float4(acc[0], acc[1], acc[2], acc[3]);
    else        *(float4*)op = make_float4(acc[4], acc[5], acc[6], acc[7]);
}

// ================= layer-2: single-pass softmax over q; 16 lanes per node ==========
__global__ __launch_bounds__(256) void k_agg2q(
    const int* __restrict__ rowptr, const int* __restrict__ srcs,
    const float* __restrict__ as_, const float* __restrict__ ad_,
    const float* __restrict__ qv, const float* __restrict__ cst,
    float* __restrict__ out)
{
    const int d = blockIdx.x * 16 + (threadIdx.x >> 4);
    if (d >= NN) return;
    const int il = threadIdx.x & 15;
    const int r0 = rowptr[d], r1 = rowptr[d + 1];
    const float2 adv = *(const float2*)&ad_[d * 2];

    float den0 = 0.f, den1 = 0.f;
    float qa00 = 0.f, qa01 = 0.f, qa10 = 0.f, qa11 = 0.f;
    for (int k = r0 + il; k < r1; k += 16) {
        const int s = srcs[k];
        const float2 a = *(const float2*)&as_[s * 2];
        const float4 q = *(const float4*)&qv[s * 4];
        const float p0 = __expf(lrelu(a.x + adv.x));
        const float p1 = __expf(lrelu(a.y + adv.y));
        den0 += p0; den1 += p1;
        qa00 = fmaf(p0, q.x, qa00); qa01 = fmaf(p0, q.y, qa01);
        qa10 = fmaf(p1, q.z, qa10); qa11 = fmaf(p1, q.w, qa11);
    }
    den0 = gsum16(den0); den1 = gsum16(den1);
    qa00 = gsum16(qa00); qa01 = gsum16(qa01);
    qa10 = gsum16(qa10); qa11 = gsum16(qa11);
    if (il == 0) {
        const float i0 = 1.f / (den0 + 1e-16f);
        const float i1 = 1.f / (den1 + 1e-16f);
        out[d * 2 + 0] = cst[0] + 0.5f * (qa00 * i0 + qa10 * i1);
        out[d * 2 + 1] = cst[1] + 0.5f * (qa01 * i0 + qa11 * i1);
    }
}

extern "C" void kernel_launch(void* const* d_in, const int* in_sizes, int n_in,
                              void* d_out, int out_size, void* d_ws, size_t ws_size,
                              hipStream_t stream) {
    const float* x      = (const float*)d_in[0];
    const int*   ei     = (const int*)d_in[1];
    const float* w1     = (const float*)d_in[2];
    const float* a_src1 = (const float*)d_in[3];
    const float* a_dst1 = (const float*)d_in[4];
    const float* b1     = (const float*)d_in[5];
    const float* g1     = (const float*)d_in[6];
    const float* be1    = (const float*)d_in[7];
    const float* m1     = (const float*)d_in[8];
    const float* v1     = (const float*)d_in[9];
    const float* w2     = (const float*)d_in[10];
    const float* a_src2 = (const float*)d_in[11];
    const float* a_dst2 = (const float*)d_in[12];
    const float* b2     = (const float*)d_in[13];
    const float* g2     = (const float*)d_in[14];
    const float* be2    = (const float*)d_in[15];
    const float* m2     = (const float*)d_in[16];
    const float* v2     = (const float*)d_in[17];
    const float* wc     = (const float*)d_in[18];
    const float* bc     = (const float*)d_in[19];
    float* out = (float*)d_out;

    float* ws = (float*)d_ws;
    _Float16* h1 = (_Float16*)ws;                         // NN*256 halves
    float* agg1  = ws + (size_t)NN * 128;                 // NN*256 fp32
    _Float16* h2 = (_Float16*)(agg1 + (size_t)NN * 256);  // NN*128 halves
    float* C = agg1 + (size_t)NN * 256 + (size_t)NN * 64;

    float* as1 = C;                        // NN*4
    float* ad1 = C + (size_t)NN * 4;       // NN*4
    float* as2 = C + (size_t)NN * 8;       // NN*2
    float* ad2 = C + (size_t)NN * 10;      // NN*2
    float* qv  = C + (size_t)NN * 12;      // NN*4
    float* scs = C + (size_t)NN * 16;      // 256
    float* shs = scs + 256;                // 256
    float* wq  = shs + 256;                // 128
    float* cst = wq + 128;                 // 64 (2 + pad)
    _Float16* wt1 = (_Float16*)(cst + 64);         // 32768 halves = 16384 floats
    _Float16* wt2 = wt1 + 32768;                   // 32768 halves
    int* counts = (int*)(cst + 64 + 16384 + 16384);
    int* rowptr = counts + NN;
    int* bsum   = rowptr + NN + 63;
    int* srcs   = bsum + 512;

    // ---- CSR build + prep ----
    k_count_init<<<NBLK, 256, 0, stream>>>(counts);
    k_hist<<<(EE + 255) / 256, 256, 0, stream>>>(ei, counts);
    k_scan_bsum<<<NBLK, 256, 0, stream>>>(counts, bsum);
    k_scan_top<<<1, 512, 0, stream>>>(bsum, NBLK);
    k_scan_final<<<NBLK, 256, 0, stream>>>(counts, bsum, rowptr);
    k_self<<<NBLK, 256, 0, stream>>>(rowptr, srcs, counts);
    k_scatter<<<(EE + 255) / 256, 256, 0, stream>>>(ei, srcs, counts);
    k_bnprep<<<1, 256, 0, stream>>>(b1, g1, be1, m1, v1, scs, shs);
    k_prep2<<<1, 64, 0, stream>>>(b2, g2, be2, m2, v2, wc, bc, wq, cst);
    k_wcvt1<<<128, 256, 0, stream>>>(w1, wt1);
    k_wcvt2<<<128, 256, 0, stream>>>(w2, wt2);

    // ---- layer 1 ----
    k_gemm1m<<<GXM, 256, 0, stream>>>(x, wt1, h1);
    k_coef1<<<(NN * 16 + 255) / 256, 256, 0, stream>>>(h1, a_src1, a_dst1, as1, ad1);
    k_agg1<<<(NN + 3) / 4, 256, 0, stream>>>(rowptr, srcs, (const __half*)h1,
                                             as1, ad1, agg1);

    // ---- layer 2 ----
    k_gemm2m<<<GXM, 256, 0, stream>>>(agg1, scs, shs, wt2, h2);
    k_coef2<<<(NN * 16 + 255) / 256, 256, 0, stream>>>(h2, a_src2, a_dst2, wq,
                                                       as2, ad2, qv);
    k_agg2q<<<(NN + 15) / 16, 256, 0, stream>>>(rowptr, srcs, as2, ad2, qv, cst, out);
}

// Round 9
// 478.639 us; speedup vs baseline: 20.1240x; 1.0234x over previous
//
#include <hip/hip_runtime.h>
#include <hip/hip_fp16.h>
#include <math.h>

#define NN 100000
#define EE 1600000
#define ETOT (EE + NN)
#define BN_EPS 1e-5f
#define NEG_SLOPE 0.2f
#define NBLK ((NN + 255) / 256)   // 391
#define GXM ((NN + 127) / 128)    // 782

typedef _Float16 half8 __attribute__((ext_vector_type(8)));
typedef _Float16 half4v __attribute__((ext_vector_type(4)));
typedef float f32x4 __attribute__((ext_vector_type(4)));

// ---------- helpers ----------
__device__ __forceinline__ float lrelu(float x) { return fmaxf(x, NEG_SLOPE * x); }
__device__ __forceinline__ float wsum(float v) {
#pragma unroll
    for (int m = 32; m; m >>= 1) v += __shfl_xor(v, m, 64);
    return v;
}
__device__ __forceinline__ float gsum16(float v) {
#pragma unroll
    for (int m = 1; m < 16; m <<= 1) v += __shfl_xor(v, m, 64);
    return v;
}
__device__ __forceinline__ float sel4(float4 v, int i) {
    float lo = (i & 1) ? v.y : v.x;
    float hi = (i & 1) ? v.w : v.z;
    return (i & 2) ? hi : lo;
}
__device__ __forceinline__ unsigned packh2(float a, float b) {
    __half2 p = __float22half2_rn(make_float2(a, b));
    return *reinterpret_cast<unsigned*>(&p);
}

// ================= CSR build =================
__global__ __launch_bounds__(256) void k_hist(const int* __restrict__ ei,
                                              int* __restrict__ counts) {
    const int e = blockIdx.x * 256 + threadIdx.x;
    if (e < EE) atomicAdd(&counts[ei[EE + e]], 1);
}
// counts[i]+1 accounts for the self-loop (counts was memset to 0 before hist)
__global__ __launch_bounds__(256) void k_scan_bsum(const int* __restrict__ counts,
                                                   int* __restrict__ bsum) {
    __shared__ int sd[256];
    const int i = blockIdx.x * 256 + threadIdx.x;
    sd[threadIdx.x] = (i < NN) ? counts[i] + 1 : 0;
    __syncthreads();
    for (int s2 = 128; s2; s2 >>= 1) {
        if (threadIdx.x < s2) sd[threadIdx.x] += sd[threadIdx.x + s2];
        __syncthreads();
    }
    if (threadIdx.x == 0) bsum[blockIdx.x] = sd[0];
}
__global__ __launch_bounds__(512) void k_scan_top(int* __restrict__ bsum, int nb) {
    __shared__ int sd[512];
    const int t = threadIdx.x;
    const int orig = (t < nb) ? bsum[t] : 0;
    sd[t] = orig;
    __syncthreads();
    for (int off = 1; off < 512; off <<= 1) {
        const int v = (t >= off) ? sd[t - off] : 0;
        __syncthreads();
        sd[t] += v;
        __syncthreads();
    }
    if (t < nb) bsum[t] = sd[t] - orig;              // exclusive
}
// rowptr + self-loop emit + cursor init, one pass
__global__ __launch_bounds__(256) void k_scan_final(const int* __restrict__ counts,
                                                    const int* __restrict__ bsum_ex,
                                                    int* __restrict__ rowptr,
                                                    int* __restrict__ srcs,
                                                    int* __restrict__ cursor) {
    __shared__ int sd[256];
    const int i = blockIdx.x * 256 + threadIdx.x;
    const int orig = (i < NN) ? counts[i] + 1 : 0;
    sd[threadIdx.x] = orig;
    __syncthreads();
    for (int off = 1; off < 256; off <<= 1) {
        const int v = (threadIdx.x >= off) ? sd[threadIdx.x - off] : 0;
        __syncthreads();
        sd[threadIdx.x] += v;
        __syncthreads();
    }
    if (i < NN) {
        const int rp = bsum_ex[blockIdx.x] + sd[threadIdx.x] - orig;
        rowptr[i] = rp;
        srcs[rp] = i;                                // self-loop first
        cursor[i] = rp + 1;                          // cursor aliases counts (safe: own idx)
        if (i == NN - 1) rowptr[NN] = ETOT;
    }
}
__global__ __launch_bounds__(256) void k_scatter(const int* __restrict__ ei,
                                                 int* __restrict__ srcs,
                                                 int* __restrict__ cursor) {
    const int e = blockIdx.x * 256 + threadIdx.x;
    if (e < EE) {
        const int d = ei[EE + e];
        const int p = atomicAdd(&cursor[d], 1);
        srcs[p] = ei[e];
    }
}

// ================= combined prep: BN1 fold | BN2/cls fold | w1^T fp16 | w2^T fp16 ===
__global__ __launch_bounds__(256) void k_prep(
    const float* __restrict__ b1, const float* __restrict__ g1,
    const float* __restrict__ be1, const float* __restrict__ m1,
    const float* __restrict__ v1,
    const float* __restrict__ b2, const float* __restrict__ g2,
    const float* __restrict__ be2, const float* __restrict__ m2,
    const float* __restrict__ v2, const float* __restrict__ wc,
    const float* __restrict__ bc,
    const float* __restrict__ w1, const float* __restrict__ w2,
    float* __restrict__ scs, float* __restrict__ shs,
    float* __restrict__ wq, float* __restrict__ cst,
    _Float16* __restrict__ wt1, _Float16* __restrict__ wt2)
{
    const int b = blockIdx.x, t = threadIdx.x;
    if (b == 0) {
        const float sc = g1[t] * rsqrtf(v1[t] + BN_EPS);
        scs[t] = sc;
        shs[t] = (b1[t] - m1[t]) * sc + be1[t];
    } else if (b == 1) {
        if (t < 64) {
            const float s2 = g2[t] * rsqrtf(v2[t] + BN_EPS);
            wq[t * 2 + 0] = s2 * wc[t * 2 + 0];
            wq[t * 2 + 1] = s2 * wc[t * 2 + 1];
            const float tv = (b2[t] - m2[t]) * s2 + be2[t];
            const float c0 = wsum(tv * wc[t * 2 + 0]);
            const float c1 = wsum(tv * wc[t * 2 + 1]);
            if (t == 0) { cst[0] = c0 + bc[0]; cst[1] = c1 + bc[1]; }
        }
    } else if (b < 130) {
        const int idx = (b - 2) * 256 + t;           // wt1[n][k] = w1[k][n]
        const int n = idx >> 7, k = idx & 127;
        wt1[idx] = (_Float16)w1[k * 256 + n];
    } else {
        const int idx = (b - 130) * 256 + t;         // wt2[n][k] = w2[k][n]
        const int n = idx >> 8, k = idx & 255;
        wt2[idx] = (_Float16)w2[k * 128 + n];
    }
}

// ================= MFMA GEMM1: h1(fp16) = x @ w1, + as1/ad1 in epilogue ===========
__global__ __launch_bounds__(256) void k_gemm1m(
    const float* __restrict__ x, const _Float16* __restrict__ wt,   // wt[256][128]
    const float* __restrict__ asrc, const float* __restrict__ adst,
    _Float16* __restrict__ h, float* __restrict__ as_, float* __restrict__ ad_)
{
    __shared__ _Float16 xs[128][136];
    const int n0 = blockIdx.x * 128;
    const int t = threadIdx.x;

    const float* xbase = x + (size_t)n0 * 128;
#pragma unroll
    for (int i = 0; i < 16; ++i) {
        const int f = i * 1024 + t * 4;
        const int m = f >> 7, k = f & 127;
        float4 v = make_float4(0.f, 0.f, 0.f, 0.f);
        if (n0 + m < NN) v = *(const float4*)(xbase + f);
        half4v hv = { (_Float16)v.x, (_Float16)v.y, (_Float16)v.z, (_Float16)v.w };
        *(half4v*)&xs[m][k] = hv;
    }
    __syncthreads();

    const int l = t & 63, w = t >> 6;
    const int m0w = (w & 1) * 64, n0w = (w >> 1) * 128;
    const int lc = l & 15, kq = (l >> 4) * 8, lr = (l >> 4) * 4;

    const f32x4 fzero = {0.f, 0.f, 0.f, 0.f};
    f32x4 acc[4][8];
#pragma unroll
    for (int r = 0; r < 4; ++r)
#pragma unroll
        for (int c = 0; c < 8; ++c) acc[r][c] = fzero;

#pragma unroll
    for (int ks = 0; ks < 4; ++ks) {
        const int k0 = ks * 32 + kq;
        const half8 a0 = *(const half8*)&xs[m0w + 0  + lc][k0];
        const half8 a1 = *(const half8*)&xs[m0w + 16 + lc][k0];
        const half8 a2 = *(const half8*)&xs[m0w + 32 + lc][k0];
        const half8 a3 = *(const half8*)&xs[m0w + 48 + lc][k0];
#pragma unroll
        for (int c = 0; c < 8; ++c) {
            const half8 b = *(const half8*)&wt[(size_t)(n0w + c * 16 + lc) * 128 + k0];
            acc[0][c] = __builtin_amdgcn_mfma_f32_16x16x32_f16(a0, b, acc[0][c], 0, 0, 0);
            acc[1][c] = __builtin_amdgcn_mfma_f32_16x16x32_f16(a1, b, acc[1][c], 0, 0, 0);
            acc[2][c] = __builtin_amdgcn_mfma_f32_16x16x32_f16(a2, b, acc[2][c], 0, 0, 0);
            acc[3][c] = __builtin_amdgcn_mfma_f32_16x16x32_f16(a3, b, acc[3][c], 0, 0, 0);
        }
    }

    // h1 store
#pragma unroll
    for (int r = 0; r < 4; ++r) {
#pragma unroll
        for (int i = 0; i < 4; ++i) {
            const int rg = n0 + m0w + r * 16 + lr + i;
            if (rg < NN) {
                _Float16* hp = h + (size_t)rg * 256 + n0w + lc;
#pragma unroll
                for (int c = 0; c < 8; ++c)
                    hp[c * 16] = (_Float16)acc[r][c][i];
            }
        }
    }

    // fused coefficients: heads headA = n0w>>6, headA+1
    float awv[8], dwv[8];
#pragma unroll
    for (int c = 0; c < 8; ++c) {
        awv[c] = asrc[n0w + c * 16 + lc];
        dwv[c] = adst[n0w + c * 16 + lc];
    }
    const int headA = n0w >> 6;
#pragma unroll
    for (int r = 0; r < 4; ++r) {
#pragma unroll
        for (int i = 0; i < 4; ++i) {
            float sA = 0.f, dA = 0.f, sB = 0.f, dB = 0.f;
#pragma unroll
            for (int c = 0; c < 4; ++c) {
                sA = fmaf(acc[r][c][i], awv[c], sA);
                dA = fmaf(acc[r][c][i], dwv[c], dA);
                sB = fmaf(acc[r][c + 4][i], awv[c + 4], sB);
                dB = fmaf(acc[r][c + 4][i], dwv[c + 4], dB);
            }
            sA = gsum16(sA); dA = gsum16(dA); sB = gsum16(sB); dB = gsum16(dB);
            const int rg = n0 + m0w + r * 16 + lr + i;
            if (lc == 0 && rg < NN) {
                as_[rg * 4 + headA] = sA;
                ad_[rg * 4 + headA] = dA;
                as_[rg * 4 + headA + 1] = sB;
                ad_[rg * 4 + headA + 1] = dB;
            }
        }
    }
}

// ================= MFMA GEMM2: ELU(BN1(agg1)) @ w2 -> {as2, ad2, qv} only ==========
__global__ __launch_bounds__(256) void k_gemm2m(
    const __half* __restrict__ agg, const float* __restrict__ scs,
    const float* __restrict__ shs, const _Float16* __restrict__ wt, // wt[128][256]
    const float* __restrict__ asrc, const float* __restrict__ adst,
    const float* __restrict__ wq,
    float* __restrict__ as_, float* __restrict__ ad_, float* __restrict__ qv)
{
    __shared__ _Float16 xs[128][136];
    const int n0 = blockIdx.x * 128;
    const int t = threadIdx.x;
    const int l = t & 63, w = t >> 6;
    const int m0w = (w & 1) * 64, n0w = (w >> 1) * 64;
    const int lc = l & 15, kq = (l >> 4) * 8, lr = (l >> 4) * 4;

    const f32x4 fzero = {0.f, 0.f, 0.f, 0.f};
    f32x4 acc[4][4];
#pragma unroll
    for (int r = 0; r < 4; ++r)
#pragma unroll
        for (int c = 0; c < 4; ++c) acc[r][c] = fzero;

    const __half* abase = agg + (size_t)n0 * 256;
    for (int kc = 0; kc < 2; ++kc) {
        if (kc) __syncthreads();
#pragma unroll
        for (int i = 0; i < 8; ++i) {
            const int f = i * 2048 + t * 8;
            const int m = f >> 7, k8 = f & 127;
            const int kg = kc * 128 + k8;
            float vf[8];
            if (n0 + m < NN) {
                const half8 v = *(const half8*)(abase + (size_t)m * 256 + kg);
#pragma unroll
                for (int u = 0; u < 8; ++u) vf[u] = (float)v[u];
            } else {
#pragma unroll
                for (int u = 0; u < 8; ++u) vf[u] = 0.f;
            }
            half8 hv;
#pragma unroll
            for (int u = 0; u < 8; ++u) {
                float e = fmaf(vf[u], scs[kg + u], shs[kg + u]);
                e = e > 0.f ? e : __expf(e) - 1.f;
                hv[u] = (_Float16)e;
            }
            *(half8*)&xs[m][k8] = hv;
        }
        __syncthreads();

#pragma unroll
        for (int ks = 0; ks < 4; ++ks) {
            const int k0 = ks * 32 + kq;
            const int kgf = kc * 128 + k0;
            const half8 a0 = *(const half8*)&xs[m0w + 0  + lc][k0];
            const half8 a1 = *(const half8*)&xs[m0w + 16 + lc][k0];
            const half8 a2 = *(const half8*)&xs[m0w + 32 + lc][k0];
            const half8 a3 = *(const half8*)&xs[m0w + 48 + lc][k0];
#pragma unroll
            for (int c = 0; c < 4; ++c) {
                const half8 b = *(const half8*)&wt[(size_t)(n0w + c * 16 + lc) * 256 + kgf];
                acc[0][c] = __builtin_amdgcn_mfma_f32_16x16x32_f16(a0, b, acc[0][c], 0, 0, 0);
                acc[1][c] = __builtin_amdgcn_mfma_f32_16x16x32_f16(a1, b, acc[1][c], 0, 0, 0);
                acc[2][c] = __builtin_amdgcn_mfma_f32_16x16x32_f16(a2, b, acc[2][c], 0, 0, 0);
                acc[3][c] = __builtin_amdgcn_mfma_f32_16x16x32_f16(a3, b, acc[3][c], 0, 0, 0);
            }
        }
    }

    // fused epilogue: s, d, q0, q1 per row for this wave's head
    const int head = n0w >> 6;
    float awv[4], dwv[4], wq0[4], wq1[4];
#pragma unroll
    for (int c = 0; c < 4; ++c) {
        const int j = n0w + c * 16 + lc;             // global col
        const int cl = j & 63;                       // head-local col
        awv[c] = asrc[j];
        dwv[c] = adst[j];
        wq0[c] = wq[cl * 2 + 0];
        wq1[c] = wq[cl * 2 + 1];
    }
#pragma unroll
    for (int r = 0; r < 4; ++r) {
#pragma unroll
        for (int i = 0; i < 4; ++i) {
            float s = 0.f, d = 0.f, q0 = 0.f, q1 = 0.f;
#pragma unroll
            for (int c = 0; c < 4; ++c) {
                s = fmaf(acc[r][c][i], awv[c], s);
                d = fmaf(acc[r][c][i], dwv[c], d);
                q0 = fmaf(acc[r][c][i], wq0[c], q0);
                q1 = fmaf(acc[r][c][i], wq1[c], q1);
            }
            s = gsum16(s); d = gsum16(d); q0 = gsum16(q0); q1 = gsum16(q1);
            const int rg = n0 + m0w + r * 16 + lr + i;
            if (lc == 0 && rg < NN) {
                as_[rg * 2 + head] = s;
                ad_[rg * 2 + head] = d;
                qv[rg * 4 + head * 2 + 0] = q0;
                qv[rg * 4 + head * 2 + 1] = q1;
            }
        }
    }
}

// ================= layer-1 aggregation: single-pass softmax, fp16 in/out ===========
__global__ __launch_bounds__(256) void k_agg1(
    const int* __restrict__ rowptr, const int* __restrict__ srcs,
    const __half* __restrict__ hf, const float* __restrict__ as_,
    const float* __restrict__ ad_, __half* __restrict__ outp)
{
    const int d = blockIdx.x * 4 + (threadIdx.x >> 6);
    if (d >= NN) return;
    const int lane = threadIdx.x & 63;
    const int r0 = rowptr[d], r1 = rowptr[d + 1];
    const int g = lane >> 5, wl = lane & 31;
    const int headw = wl >> 3;
    const float4 adv = *(const float4*)&ad_[d * 4];
    const float myad = sel4(adv, headw);
    const __half* hbase = hf + wl * 8;

    float den = 0.f;
    float acc[8] = {0.f, 0.f, 0.f, 0.f, 0.f, 0.f, 0.f, 0.f};
    for (int k = r0 + g; k < r1; k += 2) {
        const int s = srcs[k];
        const float p = __expf(lrelu(as_[s * 4 + headw] + myad));
        den += p;
        const uint4 u = *reinterpret_cast<const uint4*>(hbase + (size_t)s * 256);
        const float2 f0 = __half22float2(*reinterpret_cast<const __half2*>(&u.x));
        const float2 f1 = __half22float2(*reinterpret_cast<const __half2*>(&u.y));
        const float2 f2 = __half22float2(*reinterpret_cast<const __half2*>(&u.z));
        const float2 f3 = __half22float2(*reinterpret_cast<const __half2*>(&u.w));
        acc[0] = fmaf(p, f0.x, acc[0]); acc[1] = fmaf(p, f0.y, acc[1]);
        acc[2] = fmaf(p, f1.x, acc[2]); acc[3] = fmaf(p, f1.y, acc[3]);
        acc[4] = fmaf(p, f2.x, acc[4]); acc[5] = fmaf(p, f2.y, acc[5]);
        acc[6] = fmaf(p, f3.x, acc[6]); acc[7] = fmaf(p, f3.y, acc[7]);
    }
    den += __shfl_xor(den, 32, 64);
    const float inv = 1.f / (den + 1e-16f);
#pragma unroll
    for (int i = 0; i < 8; ++i)
        acc[i] = (acc[i] + __shfl_xor(acc[i], 32, 64)) * inv;
    __half* op = &outp[(size_t)d * 256 + wl * 8 + g * 4];
    uint2 u;
    if (g == 0) { u.x = packh2(acc[0], acc[1]); u.y = packh2(acc[2], acc[3]); }
    else        { u.x = packh2(acc[4], acc[5]); u.y = packh2(acc[6], acc[7]); }
    *reinterpret_cast<uint2*>(op) = u;
}

// ================= layer-2: single-pass softmax over q; 16 lanes per node ==========
__global__ __launch_bounds__(256) void k_agg2q(
    const int* __restrict__ rowptr, const int* __restrict__ srcs,
    const float* __restrict__ as_, const float* __restrict__ ad_,
    const float* __restrict__ qv, const float* __restrict__ cst,
    float* __restrict__ out)
{
    const int d = blockIdx.x * 16 + (threadIdx.x >> 4);
    if (d >= NN) return;
    const int il = threadIdx.x & 15;
    const int r0 = rowptr[d], r1 = rowptr[d + 1];
    const float2 adv = *(const float2*)&ad_[d * 2];

    float den0 = 0.f, den1 = 0.f;
    float qa00 = 0.f, qa01 = 0.f, qa10 = 0.f, qa11 = 0.f;
    for (int k = r0 + il; k < r1; k += 16) {
        const int s = srcs[k];
        const float2 a = *(const float2*)&as_[s * 2];
        const float4 q = *(const float4*)&qv[s * 4];
        const float p0 = __expf(lrelu(a.x + adv.x));
        const float p1 = __expf(lrelu(a.y + adv.y));
        den0 += p0; den1 += p1;
        qa00 = fmaf(p0, q.x, qa00); qa01 = fmaf(p0, q.y, qa01);
        qa10 = fmaf(p1, q.z, qa10); qa11 = fmaf(p1, q.w, qa11);
    }
    den0 = gsum16(den0); den1 = gsum16(den1);
    qa00 = gsum16(qa00); qa01 = gsum16(qa01);
    qa10 = gsum16(qa10); qa11 = gsum16(qa11);
    if (il == 0) {
        const float i0 = 1.f / (den0 + 1e-16f);
        const float i1 = 1.f / (den1 + 1e-16f);
        out[d * 2 + 0] = cst[0] + 0.5f * (qa00 * i0 + qa10 * i1);
        out[d * 2 + 1] = cst[1] + 0.5f * (qa01 * i0 + qa11 * i1);
    }
}

extern "C" void kernel_launch(void* const* d_in, const int* in_sizes, int n_in,
                              void* d_out, int out_size, void* d_ws, size_t ws_size,
                              hipStream_t stream) {
    const float* x      = (const float*)d_in[0];
    const int*   ei     = (const int*)d_in[1];
    const float* w1     = (const float*)d_in[2];
    const float* a_src1 = (const float*)d_in[3];
    const float* a_dst1 = (const float*)d_in[4];
    const float* b1     = (const float*)d_in[5];
    const float* g1     = (const float*)d_in[6];
    const float* be1    = (const float*)d_in[7];
    const float* m1     = (const float*)d_in[8];
    const float* v1     = (const float*)d_in[9];
    const float* w2     = (const float*)d_in[10];
    const float* a_src2 = (const float*)d_in[11];
    const float* a_dst2 = (const float*)d_in[12];
    const float* b2     = (const float*)d_in[13];
    const float* g2     = (const float*)d_in[14];
    const float* be2    = (const float*)d_in[15];
    const float* m2     = (const float*)d_in[16];
    const float* v2     = (const float*)d_in[17];
    const float* wc     = (const float*)d_in[18];
    const float* bc     = (const float*)d_in[19];
    float* out = (float*)d_out;

    float* ws = (float*)d_ws;
    _Float16* h1   = (_Float16*)ws;                       // NN*256 halves (12.8M fl)
    __half*  agg1h = (__half*)(ws + (size_t)NN * 128);    // NN*256 halves (12.8M fl)
    float* C = ws + (size_t)NN * 256;

    float* as1 = C;                        // NN*4
    float* ad1 = C + (size_t)NN * 4;       // NN*4
    float* as2 = C + (size_t)NN * 8;       // NN*2
    float* ad2 = C + (size_t)NN * 10;      // NN*2
    float* qv  = C + (size_t)NN * 12;      // NN*4
    float* scs = C + (size_t)NN * 16;      // 256
    float* shs = scs + 256;                // 256
    float* wq  = shs + 256;                // 128
    float* cst = wq + 128;                 // 64 (2 + pad)
    _Float16* wt1 = (_Float16*)(cst + 64); // 32768 halves
    _Float16* wt2 = wt1 + 32768;           // 32768 halves
    int* counts = (int*)(cst + 64 + 16384 + 16384);   // NN (reused as cursor)
    int* rowptr = counts + NN;                        // NN+1
    int* bsum   = rowptr + NN + 63;                   // 512
    int* srcs   = bsum + 512;                         // ETOT

    // ---- CSR build + prep ----
    hipMemsetAsync(counts, 0, (size_t)NN * sizeof(int), stream);
    k_hist<<<(EE + 255) / 256, 256, 0, stream>>>(ei, counts);
    k_scan_bsum<<<NBLK, 256, 0, stream>>>(counts, bsum);
    k_scan_top<<<1, 512, 0, stream>>>(bsum, NBLK);
    k_scan_final<<<NBLK, 256, 0, stream>>>(counts, bsum, rowptr, srcs, counts);
    k_scatter<<<(EE + 255) / 256, 256, 0, stream>>>(ei, srcs, counts);
    k_prep<<<258, 256, 0, stream>>>(b1, g1, be1, m1, v1, b2, g2, be2, m2, v2,
                                    wc, bc, w1, w2, scs, shs, wq, cst, wt1, wt2);

    // ---- layer 1 ----
    k_gemm1m<<<GXM, 256, 0, stream>>>(x, wt1, a_src1, a_dst1, h1, as1, ad1);
    k_agg1<<<(NN + 3) / 4, 256, 0, stream>>>(rowptr, srcs, (const __half*)h1,
                                             as1, ad1, agg1h);

    // ---- layer 2 ----
    k_gemm2m<<<GXM, 256, 0, stream>>>(agg1h, scs, shs, wt2, a_src2, a_dst2, wq,
                                      as2, ad2, qv);
    k_agg2q<<<(NN + 15) / 16, 256, 0, stream>>>(rowptr, srcs, as2, ad2, qv, cst, out);
}

// Round 10
// 456.564 us; speedup vs baseline: 21.0970x; 1.0484x over previous
//
#include <hip/hip_runtime.h>
#include <hip/hip_fp16.h>
#include <math.h>

#define NN 100000
#define EE 1600000
#define ETOT (EE + NN)
#define BN_EPS 1e-5f
#define NEG_SLOPE 0.2f
#define NBLK ((NN + 255) / 256)   // 391
#define GXM ((NN + 127) / 128)    // 782

typedef _Float16 half8 __attribute__((ext_vector_type(8)));
typedef _Float16 half4v __attribute__((ext_vector_type(4)));
typedef float f32x4 __attribute__((ext_vector_type(4)));

// ---------- helpers ----------
__device__ __forceinline__ float lrelu(float x) { return fmaxf(x, NEG_SLOPE * x); }
__device__ __forceinline__ float wsum(float v) {
#pragma unroll
    for (int m = 32; m; m >>= 1) v += __shfl_xor(v, m, 64);
    return v;
}
__device__ __forceinline__ float gsum16(float v) {
#pragma unroll
    for (int m = 1; m < 16; m <<= 1) v += __shfl_xor(v, m, 64);
    return v;
}
__device__ __forceinline__ float sel4(float4 v, int i) {
    float lo = (i & 1) ? v.y : v.x;
    float hi = (i & 1) ? v.w : v.z;
    return (i & 2) ? hi : lo;
}
__device__ __forceinline__ unsigned packh2(float a, float b) {
    __half2 p = __float22half2_rn(make_float2(a, b));
    return *reinterpret_cast<unsigned*>(&p);
}

// ================= CSR build =================
__global__ __launch_bounds__(256) void k_hist(const int* __restrict__ ei,
                                              int* __restrict__ counts) {
    const int e = blockIdx.x * 256 + threadIdx.x;
    if (e < EE) atomicAdd(&counts[ei[EE + e]], 1);
}
__global__ __launch_bounds__(256) void k_scan_bsum(const int* __restrict__ counts,
                                                   int* __restrict__ bsum) {
    __shared__ int sd[256];
    const int i = blockIdx.x * 256 + threadIdx.x;
    sd[threadIdx.x] = (i < NN) ? counts[i] + 1 : 0;   // +1 = self-loop
    __syncthreads();
    for (int s2 = 128; s2; s2 >>= 1) {
        if (threadIdx.x < s2) sd[threadIdx.x] += sd[threadIdx.x + s2];
        __syncthreads();
    }
    if (threadIdx.x == 0) bsum[blockIdx.x] = sd[0];
}
__global__ __launch_bounds__(512) void k_scan_top(int* __restrict__ bsum, int nb) {
    __shared__ int sd[512];
    const int t = threadIdx.x;
    const int orig = (t < nb) ? bsum[t] : 0;
    sd[t] = orig;
    __syncthreads();
    for (int off = 1; off < 512; off <<= 1) {
        const int v = (t >= off) ? sd[t - off] : 0;
        __syncthreads();
        sd[t] += v;
        __syncthreads();
    }
    if (t < nb) bsum[t] = sd[t] - orig;              // exclusive
}
__global__ __launch_bounds__(256) void k_scan_final(const int* __restrict__ counts,
                                                    const int* __restrict__ bsum_ex,
                                                    int* __restrict__ rowptr,
                                                    int* __restrict__ srcs,
                                                    int* __restrict__ cursor) {
    __shared__ int sd[256];
    const int i = blockIdx.x * 256 + threadIdx.x;
    const int orig = (i < NN) ? counts[i] + 1 : 0;
    sd[threadIdx.x] = orig;
    __syncthreads();
    for (int off = 1; off < 256; off <<= 1) {
        const int v = (threadIdx.x >= off) ? sd[threadIdx.x - off] : 0;
        __syncthreads();
        sd[threadIdx.x] += v;
        __syncthreads();
    }
    if (i < NN) {
        const int rp = bsum_ex[blockIdx.x] + sd[threadIdx.x] - orig;
        rowptr[i] = rp;
        srcs[rp] = i;                                // self-loop first
        cursor[i] = rp + 1;
        if (i == NN - 1) rowptr[NN] = ETOT;
    }
}
__global__ __launch_bounds__(256) void k_scatter(const int* __restrict__ ei,
                                                 int* __restrict__ srcs,
                                                 int* __restrict__ cursor) {
    const int e = blockIdx.x * 256 + threadIdx.x;
    if (e < EE) {
        const int d = ei[EE + e];
        const int p = atomicAdd(&cursor[d], 1);
        srcs[p] = ei[e];
    }
}

// ============ combined prep: BN folds | w^T fp16 | zero counts ============
__global__ __launch_bounds__(256) void k_prep(
    const float* __restrict__ b1, const float* __restrict__ g1,
    const float* __restrict__ be1, const float* __restrict__ m1,
    const float* __restrict__ v1,
    const float* __restrict__ b2, const float* __restrict__ g2,
    const float* __restrict__ be2, const float* __restrict__ m2,
    const float* __restrict__ v2, const float* __restrict__ wc,
    const float* __restrict__ bc,
    const float* __restrict__ w1, const float* __restrict__ w2,
    float* __restrict__ scs, float* __restrict__ shs,
    float* __restrict__ wq, float* __restrict__ cst,
    _Float16* __restrict__ wt1, _Float16* __restrict__ wt2,
    int* __restrict__ counts)
{
    const int b = blockIdx.x, t = threadIdx.x;
    if (b == 0) {
        const float sc = g1[t] * rsqrtf(v1[t] + BN_EPS);
        scs[t] = sc;
        shs[t] = (b1[t] - m1[t]) * sc + be1[t];
    } else if (b == 1) {
        if (t < 64) {
            const float s2 = g2[t] * rsqrtf(v2[t] + BN_EPS);
            wq[t * 2 + 0] = s2 * wc[t * 2 + 0];
            wq[t * 2 + 1] = s2 * wc[t * 2 + 1];
            const float tv = (b2[t] - m2[t]) * s2 + be2[t];
            const float c0 = wsum(tv * wc[t * 2 + 0]);
            const float c1 = wsum(tv * wc[t * 2 + 1]);
            if (t == 0) { cst[0] = c0 + bc[0]; cst[1] = c1 + bc[1]; }
        }
    } else if (b < 130) {
        const int idx = (b - 2) * 256 + t;           // wt1[n][k] = w1[k][n]
        const int n = idx >> 7, k = idx & 127;
        wt1[idx] = (_Float16)w1[k * 256 + n];
    } else if (b < 258) {
        const int idx = (b - 130) * 256 + t;         // wt2[n][k] = w2[k][n]
        const int n = idx >> 8, k = idx & 255;
        wt2[idx] = (_Float16)w2[k * 128 + n];
    } else {
        const int i = (b - 258) * 256 + t;
        if (i < NN) counts[i] = 0;
    }
}

// ================= MFMA GEMM1: h1(fp16) = x @ w1, + as1/ad1 in epilogue ===========
__global__ __launch_bounds__(256) void k_gemm1m(
    const float* __restrict__ x, const _Float16* __restrict__ wt,   // wt[256][128]
    const float* __restrict__ asrc, const float* __restrict__ adst,
    _Float16* __restrict__ h, float* __restrict__ as_, float* __restrict__ ad_)
{
    __shared__ _Float16 xs[128][136];
    const int n0 = blockIdx.x * 128;
    const int t = threadIdx.x;

    const float* xbase = x + (size_t)n0 * 128;
#pragma unroll
    for (int i = 0; i < 16; ++i) {
        const int f = i * 1024 + t * 4;
        const int m = f >> 7, k = f & 127;
        float4 v = make_float4(0.f, 0.f, 0.f, 0.f);
        if (n0 + m < NN) v = *(const float4*)(xbase + f);
        half4v hv = { (_Float16)v.x, (_Float16)v.y, (_Float16)v.z, (_Float16)v.w };
        *(half4v*)&xs[m][k] = hv;
    }
    __syncthreads();

    const int l = t & 63, w = t >> 6;
    const int m0w = (w & 1) * 64, n0w = (w >> 1) * 128;
    const int lc = l & 15, kq = (l >> 4) * 8, lr = (l >> 4) * 4;

    const f32x4 fzero = {0.f, 0.f, 0.f, 0.f};
    f32x4 acc[4][8];
#pragma unroll
    for (int r = 0; r < 4; ++r)
#pragma unroll
        for (int c = 0; c < 8; ++c) acc[r][c] = fzero;

#pragma unroll
    for (int ks = 0; ks < 4; ++ks) {
        const int k0 = ks * 32 + kq;
        const half8 a0 = *(const half8*)&xs[m0w + 0  + lc][k0];
        const half8 a1 = *(const half8*)&xs[m0w + 16 + lc][k0];
        const half8 a2 = *(const half8*)&xs[m0w + 32 + lc][k0];
        const half8 a3 = *(const half8*)&xs[m0w + 48 + lc][k0];
#pragma unroll
        for (int c = 0; c < 8; ++c) {
            const half8 b = *(const half8*)&wt[(size_t)(n0w + c * 16 + lc) * 128 + k0];
            acc[0][c] = __builtin_amdgcn_mfma_f32_16x16x32_f16(a0, b, acc[0][c], 0, 0, 0);
            acc[1][c] = __builtin_amdgcn_mfma_f32_16x16x32_f16(a1, b, acc[1][c], 0, 0, 0);
            acc[2][c] = __builtin_amdgcn_mfma_f32_16x16x32_f16(a2, b, acc[2][c], 0, 0, 0);
            acc[3][c] = __builtin_amdgcn_mfma_f32_16x16x32_f16(a3, b, acc[3][c], 0, 0, 0);
        }
    }

    // h1 store
#pragma unroll
    for (int r = 0; r < 4; ++r) {
#pragma unroll
        for (int i = 0; i < 4; ++i) {
            const int rg = n0 + m0w + r * 16 + lr + i;
            if (rg < NN) {
                _Float16* hp = h + (size_t)rg * 256 + n0w + lc;
#pragma unroll
                for (int c = 0; c < 8; ++c)
                    hp[c * 16] = (_Float16)acc[r][c][i];
            }
        }
    }

    // fused coefficients
    float awv[8], dwv[8];
#pragma unroll
    for (int c = 0; c < 8; ++c) {
        awv[c] = asrc[n0w + c * 16 + lc];
        dwv[c] = adst[n0w + c * 16 + lc];
    }
    const int headA = n0w >> 6;
#pragma unroll
    for (int r = 0; r < 4; ++r) {
#pragma unroll
        for (int i = 0; i < 4; ++i) {
            float sA = 0.f, dA = 0.f, sB = 0.f, dB = 0.f;
#pragma unroll
            for (int c = 0; c < 4; ++c) {
                sA = fmaf(acc[r][c][i], awv[c], sA);
                dA = fmaf(acc[r][c][i], dwv[c], dA);
                sB = fmaf(acc[r][c + 4][i], awv[c + 4], sB);
                dB = fmaf(acc[r][c + 4][i], dwv[c + 4], dB);
            }
            sA = gsum16(sA); dA = gsum16(dA); sB = gsum16(sB); dB = gsum16(dB);
            const int rg = n0 + m0w + r * 16 + lr + i;
            if (lc == 0 && rg < NN) {
                as_[rg * 4 + headA] = sA;
                ad_[rg * 4 + headA] = dA;
                as_[rg * 4 + headA + 1] = sB;
                ad_[rg * 4 + headA + 1] = dB;
            }
        }
    }
}

// ====== MFMA GEMM2: ELU(BN1(agg1)) @ w2 -> {ad2, pack{as2,q}} only ======
__global__ __launch_bounds__(256) void k_gemm2m(
    const __half* __restrict__ agg, const float* __restrict__ scs,
    const float* __restrict__ shs, const _Float16* __restrict__ wt, // wt[128][256]
    const float* __restrict__ asrc, const float* __restrict__ adst,
    const float* __restrict__ wq,
    float* __restrict__ ad_, uint2* __restrict__ pack)   // pack: 2 uint2 per node
{
    __shared__ _Float16 xs[128][136];
    const int n0 = blockIdx.x * 128;
    const int t = threadIdx.x;
    const int l = t & 63, w = t >> 6;
    const int m0w = (w & 1) * 64, n0w = (w >> 1) * 64;
    const int lc = l & 15, kq = (l >> 4) * 8, lr = (l >> 4) * 4;

    const f32x4 fzero = {0.f, 0.f, 0.f, 0.f};
    f32x4 acc[4][4];
#pragma unroll
    for (int r = 0; r < 4; ++r)
#pragma unroll
        for (int c = 0; c < 4; ++c) acc[r][c] = fzero;

    const __half* abase = agg + (size_t)n0 * 256;
    for (int kc = 0; kc < 2; ++kc) {
        if (kc) __syncthreads();
#pragma unroll
        for (int i = 0; i < 8; ++i) {
            const int f = i * 2048 + t * 8;
            const int m = f >> 7, k8 = f & 127;
            const int kg = kc * 128 + k8;
            float vf[8];
            if (n0 + m < NN) {
                const half8 v = *(const half8*)(abase + (size_t)m * 256 + kg);
#pragma unroll
                for (int u = 0; u < 8; ++u) vf[u] = (float)v[u];
            } else {
#pragma unroll
                for (int u = 0; u < 8; ++u) vf[u] = 0.f;
            }
            half8 hv;
#pragma unroll
            for (int u = 0; u < 8; ++u) {
                float e = fmaf(vf[u], scs[kg + u], shs[kg + u]);
                e = e > 0.f ? e : __expf(e) - 1.f;
                hv[u] = (_Float16)e;
            }
            *(half8*)&xs[m][k8] = hv;
        }
        __syncthreads();

#pragma unroll
        for (int ks = 0; ks < 4; ++ks) {
            const int k0 = ks * 32 + kq;
            const int kgf = kc * 128 + k0;
            const half8 a0 = *(const half8*)&xs[m0w + 0  + lc][k0];
            const half8 a1 = *(const half8*)&xs[m0w + 16 + lc][k0];
            const half8 a2 = *(const half8*)&xs[m0w + 32 + lc][k0];
            const half8 a3 = *(const half8*)&xs[m0w + 48 + lc][k0];
#pragma unroll
            for (int c = 0; c < 4; ++c) {
                const half8 b = *(const half8*)&wt[(size_t)(n0w + c * 16 + lc) * 256 + kgf];
                acc[0][c] = __builtin_amdgcn_mfma_f32_16x16x32_f16(a0, b, acc[0][c], 0, 0, 0);
                acc[1][c] = __builtin_amdgcn_mfma_f32_16x16x32_f16(a1, b, acc[1][c], 0, 0, 0);
                acc[2][c] = __builtin_amdgcn_mfma_f32_16x16x32_f16(a2, b, acc[2][c], 0, 0, 0);
                acc[3][c] = __builtin_amdgcn_mfma_f32_16x16x32_f16(a3, b, acc[3][c], 0, 0, 0);
            }
        }
    }

    // fused epilogue: per row: s, d, q0, q1 for this wave's head
    const int head = n0w >> 6;
    float awv[4], dwv[4], wq0[4], wq1[4];
#pragma unroll
    for (int c = 0; c < 4; ++c) {
        const int j = n0w + c * 16 + lc;
        const int cl = j & 63;
        awv[c] = asrc[j];
        dwv[c] = adst[j];
        wq0[c] = wq[cl * 2 + 0];
        wq1[c] = wq[cl * 2 + 1];
    }
#pragma unroll
    for (int r = 0; r < 4; ++r) {
#pragma unroll
        for (int i = 0; i < 4; ++i) {
            float s = 0.f, d = 0.f, q0 = 0.f, q1 = 0.f;
#pragma unroll
            for (int c = 0; c < 4; ++c) {
                s = fmaf(acc[r][c][i], awv[c], s);
                d = fmaf(acc[r][c][i], dwv[c], d);
                q0 = fmaf(acc[r][c][i], wq0[c], q0);
                q1 = fmaf(acc[r][c][i], wq1[c], q1);
            }
            s = gsum16(s); d = gsum16(d); q0 = gsum16(q0); q1 = gsum16(q1);
            const int rg = n0 + m0w + r * 16 + lr + i;
            if (lc == 0 && rg < NN) {
                ad_[rg * 2 + head] = d;
                uint2 u;
                u.x = __float_as_uint(s);
                u.y = packh2(q0, q1);
                pack[rg * 2 + head] = u;   // 8B per head -> 16B per node
            }
        }
    }
}

// ===== layer-1 aggregation: single-pass softmax, 2x-unrolled gather (MLP) =====
__global__ __launch_bounds__(256) void k_agg1(
    const int* __restrict__ rowptr, const int* __restrict__ srcs,
    const __half* __restrict__ hf, const float* __restrict__ as_,
    const float* __restrict__ ad_, __half* __restrict__ outp)
{
    const int d = blockIdx.x * 4 + (threadIdx.x >> 6);
    if (d >= NN) return;
    const int lane = threadIdx.x & 63;
    const int r0 = rowptr[d], r1 = rowptr[d + 1];
    const int g = lane >> 5, wl = lane & 31;
    const int headw = wl >> 3;
    const float4 adv = *(const float4*)&ad_[d * 4];
    const float myad = sel4(adv, headw);
    const __half* hbase = hf + wl * 8;

    float den = 0.f;
    float acc[8] = {0.f, 0.f, 0.f, 0.f, 0.f, 0.f, 0.f, 0.f};
    int k = r0 + g;
    for (; k + 2 < r1; k += 4) {                     // 2 edges per half per iter
        const int s0 = srcs[k];
        const int s1 = srcs[k + 2];
        const float p0 = __expf(lrelu(as_[s0 * 4 + headw] + myad));
        const float p1 = __expf(lrelu(as_[s1 * 4 + headw] + myad));
        const uint4 u0 = *reinterpret_cast<const uint4*>(hbase + (size_t)s0 * 256);
        const uint4 u1 = *reinterpret_cast<const uint4*>(hbase + (size_t)s1 * 256);
        den += p0 + p1;
        const float2 a0 = __half22float2(*reinterpret_cast<const __half2*>(&u0.x));
        const float2 a1 = __half22float2(*reinterpret_cast<const __half2*>(&u0.y));
        const float2 a2 = __half22float2(*reinterpret_cast<const __half2*>(&u0.z));
        const float2 a3 = __half22float2(*reinterpret_cast<const __half2*>(&u0.w));
        acc[0] = fmaf(p0, a0.x, acc[0]); acc[1] = fmaf(p0, a0.y, acc[1]);
        acc[2] = fmaf(p0, a1.x, acc[2]); acc[3] = fmaf(p0, a1.y, acc[3]);
        acc[4] = fmaf(p0, a2.x, acc[4]); acc[5] = fmaf(p0, a2.y, acc[5]);
        acc[6] = fmaf(p0, a3.x, acc[6]); acc[7] = fmaf(p0, a3.y, acc[7]);
        const float2 b0 = __half22float2(*reinterpret_cast<const __half2*>(&u1.x));
        const float2 b1 = __half22float2(*reinterpret_cast<const __half2*>(&u1.y));
        const float2 b2 = __half22float2(*reinterpret_cast<const __half2*>(&u1.z));
        const float2 b3 = __half22float2(*reinterpret_cast<const __half2*>(&u1.w));
        acc[0] = fmaf(p1, b0.x, acc[0]); acc[1] = fmaf(p1, b0.y, acc[1]);
        acc[2] = fmaf(p1, b1.x, acc[2]); acc[3] = fmaf(p1, b1.y, acc[3]);
        acc[4] = fmaf(p1, b2.x, acc[4]); acc[5] = fmaf(p1, b2.y, acc[5]);
        acc[6] = fmaf(p1, b3.x, acc[6]); acc[7] = fmaf(p1, b3.y, acc[7]);
    }
    if (k < r1) {                                    // remainder (at most one)
        const int s = srcs[k];
        const float p = __expf(lrelu(as_[s * 4 + headw] + myad));
        den += p;
        const uint4 u = *reinterpret_cast<const uint4*>(hbase + (size_t)s * 256);
        const float2 f0 = __half22float2(*reinterpret_cast<const __half2*>(&u.x));
        const float2 f1 = __half22float2(*reinterpret_cast<const __half2*>(&u.y));
        const float2 f2 = __half22float2(*reinterpret_cast<const __half2*>(&u.z));
        const float2 f3 = __half22float2(*reinterpret_cast<const __half2*>(&u.w));
        acc[0] = fmaf(p, f0.x, acc[0]); acc[1] = fmaf(p, f0.y, acc[1]);
        acc[2] = fmaf(p, f1.x, acc[2]); acc[3] = fmaf(p, f1.y, acc[3]);
        acc[4] = fmaf(p, f2.x, acc[4]); acc[5] = fmaf(p, f2.y, acc[5]);
        acc[6] = fmaf(p, f3.x, acc[6]); acc[7] = fmaf(p, f3.y, acc[7]);
    }
    den += __shfl_xor(den, 32, 64);
    const float inv = 1.f / (den + 1e-16f);
#pragma unroll
    for (int i = 0; i < 8; ++i)
        acc[i] = (acc[i] + __shfl_xor(acc[i], 32, 64)) * inv;
    __half* op = &outp[(size_t)d * 256 + wl * 8 + g * 4];
    uint2 u;
    if (g == 0) { u.x = packh2(acc[0], acc[1]); u.y = packh2(acc[2], acc[3]); }
    else        { u.x = packh2(acc[4], acc[5]); u.y = packh2(acc[6], acc[7]); }
    *reinterpret_cast<uint2*>(op) = u;
}

// ====== layer-2: single-pass softmax; one 16B record gather per edge ======
__global__ __launch_bounds__(256) void k_agg2q(
    const int* __restrict__ rowptr, const int* __restrict__ srcs,
    const uint4* __restrict__ pack, const float* __restrict__ ad_,
    const float* __restrict__ cst, float* __restrict__ out)
{
    const int d = blockIdx.x * 16 + (threadIdx.x >> 4);
    if (d >= NN) return;
    const int il = threadIdx.x & 15;
    const int r0 = rowptr[d], r1 = rowptr[d + 1];
    const float2 adv = *(const float2*)&ad_[d * 2];

    float den0 = 0.f, den1 = 0.f;
    float qa00 = 0.f, qa01 = 0.f, qa10 = 0.f, qa11 = 0.f;
    for (int k = r0 + il; k < r1; k += 16) {
        const int s = srcs[k];
        const uint4 rec = pack[s];                   // {as2_0, q0h2, as2_1, q1h2}
        const float a0 = __uint_as_float(rec.x);
        const float a1 = __uint_as_float(rec.z);
        const float2 q0 = __half22float2(*reinterpret_cast<const __half2*>(&rec.y));
        const float2 q1 = __half22float2(*reinterpret_cast<const __half2*>(&rec.w));
        const float p0 = __expf(lrelu(a0 + adv.x));
        const float p1 = __expf(lrelu(a1 + adv.y));
        den0 += p0; den1 += p1;
        qa00 = fmaf(p0, q0.x, qa00); qa01 = fmaf(p0, q0.y, qa01);
        qa10 = fmaf(p1, q1.x, qa10); qa11 = fmaf(p1, q1.y, qa11);
    }
    den0 = gsum16(den0); den1 = gsum16(den1);
    qa00 = gsum16(qa00); qa01 = gsum16(qa01);
    qa10 = gsum16(qa10); qa11 = gsum16(qa11);
    if (il == 0) {
        const float i0 = 1.f / (den0 + 1e-16f);
        const float i1 = 1.f / (den1 + 1e-16f);
        out[d * 2 + 0] = cst[0] + 0.5f * (qa00 * i0 + qa10 * i1);
        out[d * 2 + 1] = cst[1] + 0.5f * (qa01 * i0 + qa11 * i1);
    }
}

extern "C" void kernel_launch(void* const* d_in, const int* in_sizes, int n_in,
                              void* d_out, int out_size, void* d_ws, size_t ws_size,
                              hipStream_t stream) {
    const float* x      = (const float*)d_in[0];
    const int*   ei     = (const int*)d_in[1];
    const float* w1     = (const float*)d_in[2];
    const float* a_src1 = (const float*)d_in[3];
    const float* a_dst1 = (const float*)d_in[4];
    const float* b1     = (const float*)d_in[5];
    const float* g1     = (const float*)d_in[6];
    const float* be1    = (const float*)d_in[7];
    const float* m1     = (const float*)d_in[8];
    const float* v1     = (const float*)d_in[9];
    const float* w2     = (const float*)d_in[10];
    const float* a_src2 = (const float*)d_in[11];
    const float* a_dst2 = (const float*)d_in[12];
    const float* b2     = (const float*)d_in[13];
    const float* g2     = (const float*)d_in[14];
    const float* be2    = (const float*)d_in[15];
    const float* m2     = (const float*)d_in[16];
    const float* v2     = (const float*)d_in[17];
    const float* wc     = (const float*)d_in[18];
    const float* bc     = (const float*)d_in[19];
    float* out = (float*)d_out;

    float* ws = (float*)d_ws;
    _Float16* h1   = (_Float16*)ws;                       // NN*256 halves
    __half*  agg1h = (__half*)(ws + (size_t)NN * 128);    // NN*256 halves
    float* C = ws + (size_t)NN * 256;

    float* as1 = C;                        // NN*4
    float* ad1 = C + (size_t)NN * 4;       // NN*4
    float* ad2 = C + (size_t)NN * 8;       // NN*2
    float* packf = C + (size_t)NN * 10;    // NN*4 (uint4 per node, 16B-aligned)
    float* scs = C + (size_t)NN * 14;      // 256
    float* shs = scs + 256;                // 256
    float* wq  = shs + 256;                // 128
    float* cst = wq + 128;                 // 64 (2 + pad)
    _Float16* wt1 = (_Float16*)(cst + 64); // 32768 halves
    _Float16* wt2 = wt1 + 32768;           // 32768 halves
    int* counts = (int*)(cst + 64 + 16384 + 16384);   // NN (reused as cursor)
    int* rowptr = counts + NN;                        // NN+1
    int* bsum   = rowptr + NN + 63;                   // 512
    int* srcs   = bsum + 512;                         // ETOT

    // ---- prep (also zeroes counts) ----
    k_prep<<<258 + NBLK, 256, 0, stream>>>(b1, g1, be1, m1, v1, b2, g2, be2, m2, v2,
                                           wc, bc, w1, w2, scs, shs, wq, cst,
                                           wt1, wt2, counts);
    // ---- CSR build ----
    k_hist<<<(EE + 255) / 256, 256, 0, stream>>>(ei, counts);
    k_scan_bsum<<<NBLK, 256, 0, stream>>>(counts, bsum);
    k_scan_top<<<1, 512, 0, stream>>>(bsum, NBLK);
    k_scan_final<<<NBLK, 256, 0, stream>>>(counts, bsum, rowptr, srcs, counts);
    k_scatter<<<(EE + 255) / 256, 256, 0, stream>>>(ei, srcs, counts);

    // ---- layer 1 ----
    k_gemm1m<<<GXM, 256, 0, stream>>>(x, wt1, a_src1, a_dst1, h1, as1, ad1);
    k_agg1<<<(NN + 3) / 4, 256, 0, stream>>>(rowptr, srcs, (const __half*)h1,
                                             as1, ad1, agg1h);

    // ---- layer 2 ----
    k_gemm2m<<<GXM, 256, 0, stream>>>(agg1h, scs, shs, wt2, a_src2, a_dst2, wq,
                                      ad2, (uint2*)packf);
    k_agg2q<<<(NN + 15) / 16, 256, 0, stream>>>(rowptr, srcs, (const uint4*)packf,
                                                ad2, cst, out);
}

// Round 11
// 428.358 us; speedup vs baseline: 22.4861x; 1.0658x over previous
//
#include <hip/hip_runtime.h>
#include <hip/hip_fp16.h>
#include <math.h>

#define NN 100000
#define EE 1600000
#define ETOT (EE + NN)
#define BN_EPS 1e-5f
#define NEG_SLOPE 0.2f
#define NBLK ((NN + 255) / 256)   // 391
#define GXM ((NN + 127) / 128)    // 782

typedef _Float16 half8 __attribute__((ext_vector_type(8)));
typedef float f32x4 __attribute__((ext_vector_type(4)));

// ---------- helpers ----------
__device__ __forceinline__ float lrelu(float x) { return fmaxf(x, NEG_SLOPE * x); }
__device__ __forceinline__ float wsum(float v) {
#pragma unroll
    for (int m = 32; m; m >>= 1) v += __shfl_xor(v, m, 64);
    return v;
}
__device__ __forceinline__ float gsum16(float v) {
#pragma unroll
    for (int m = 1; m < 16; m <<= 1) v += __shfl_xor(v, m, 64);
    return v;
}
__device__ __forceinline__ unsigned packh2(float a, float b) {
    __half2 p = __float22half2_rn(make_float2(a, b));
    return *reinterpret_cast<unsigned*>(&p);
}

// ================= CSR build =================
__global__ __launch_bounds__(256) void k_hist(const int* __restrict__ ei,
                                              int* __restrict__ counts) {
    const int e = blockIdx.x * 256 + threadIdx.x;
    if (e < EE) atomicAdd(&counts[ei[EE + e]], 1);
}
__global__ __launch_bounds__(256) void k_scan_bsum(const int* __restrict__ counts,
                                                   int* __restrict__ bsum) {
    __shared__ int sd[256];
    const int i = blockIdx.x * 256 + threadIdx.x;
    sd[threadIdx.x] = (i < NN) ? counts[i] + 1 : 0;   // +1 = self-loop
    __syncthreads();
    for (int s2 = 128; s2; s2 >>= 1) {
        if (threadIdx.x < s2) sd[threadIdx.x] += sd[threadIdx.x + s2];
        __syncthreads();
    }
    if (threadIdx.x == 0) bsum[blockIdx.x] = sd[0];
}
__global__ __launch_bounds__(512) void k_scan_top(int* __restrict__ bsum, int nb) {
    __shared__ int sd[512];
    const int t = threadIdx.x;
    const int orig = (t < nb) ? bsum[t] : 0;
    sd[t] = orig;
    __syncthreads();
    for (int off = 1; off < 512; off <<= 1) {
        const int v = (t >= off) ? sd[t - off] : 0;
        __syncthreads();
        sd[t] += v;
        __syncthreads();
    }
    if (t < nb) bsum[t] = sd[t] - orig;              // exclusive
}
__global__ __launch_bounds__(256) void k_scan_final(const int* __restrict__ counts,
                                                    const int* __restrict__ bsum_ex,
                                                    int* __restrict__ rowptr,
                                                    int* __restrict__ srcs,
                                                    int* __restrict__ cursor) {
    __shared__ int sd[256];
    const int i = blockIdx.x * 256 + threadIdx.x;
    const int orig = (i < NN) ? counts[i] + 1 : 0;
    sd[threadIdx.x] = orig;
    __syncthreads();
    for (int off = 1; off < 256; off <<= 1) {
        const int v = (threadIdx.x >= off) ? sd[threadIdx.x - off] : 0;
        __syncthreads();
        sd[threadIdx.x] += v;
        __syncthreads();
    }
    if (i < NN) {
        const int rp = bsum_ex[blockIdx.x] + sd[threadIdx.x] - orig;
        rowptr[i] = rp;
        srcs[rp] = i;                                // self-loop first
        cursor[i] = rp + 1;
        if (i == NN - 1) rowptr[NN] = ETOT;
    }
}
__global__ __launch_bounds__(256) void k_scatter(const int* __restrict__ ei,
                                                 int* __restrict__ srcs,
                                                 int* __restrict__ cursor) {
    const int e = blockIdx.x * 256 + threadIdx.x;
    if (e < EE) {
        const int d = ei[EE + e];
        const int p = atomicAdd(&cursor[d], 1);
        srcs[p] = ei[e];
    }
}

// ===== prep: BN folds | w^T fp16 | va/vd = W1_h · a_{src,dst} | zero counts =====
__global__ __launch_bounds__(256) void k_prep(
    const float* __restrict__ b1, const float* __restrict__ g1,
    const float* __restrict__ be1, const float* __restrict__ m1,
    const float* __restrict__ v1,
    const float* __restrict__ b2, const float* __restrict__ g2,
    const float* __restrict__ be2, const float* __restrict__ m2,
    const float* __restrict__ v2, const float* __restrict__ wc,
    const float* __restrict__ bc,
    const float* __restrict__ w1, const float* __restrict__ w2,
    const float* __restrict__ as1w, const float* __restrict__ ad1w,
    float* __restrict__ scs, float* __restrict__ shs,
    float* __restrict__ wq, float* __restrict__ cst,
    float* __restrict__ va, float* __restrict__ vd,
    _Float16* __restrict__ wt1, _Float16* __restrict__ wt2,
    int* __restrict__ counts)
{
    const int b = blockIdx.x, t = threadIdx.x;
    if (b == 0) {
        const float sc = g1[t] * rsqrtf(v1[t] + BN_EPS);
        scs[t] = sc;
        shs[t] = (b1[t] - m1[t]) * sc + be1[t];
    } else if (b == 1) {
        if (t < 64) {
            const float s2 = g2[t] * rsqrtf(v2[t] + BN_EPS);
            wq[t * 2 + 0] = s2 * wc[t * 2 + 0];
            wq[t * 2 + 1] = s2 * wc[t * 2 + 1];
            const float tv = (b2[t] - m2[t]) * s2 + be2[t];
            const float c0 = wsum(tv * wc[t * 2 + 0]);
            const float c1 = wsum(tv * wc[t * 2 + 1]);
            if (t == 0) { cst[0] = c0 + bc[0]; cst[1] = c1 + bc[1]; }
        }
    } else if (b < 130) {
        const int idx = (b - 2) * 256 + t;           // wt1[n][k] = w1[k][n]
        const int n = idx >> 7, k = idx & 127;
        wt1[idx] = (_Float16)w1[k * 256 + n];
    } else if (b < 258) {
        const int idx = (b - 130) * 256 + t;         // wt2[n][k] = w2[k][n]
        const int n = idx >> 8, k = idx & 255;
        wt2[idx] = (_Float16)w2[k * 128 + n];
    } else if (b == 258) {
#pragma unroll
        for (int rep = 0; rep < 2; ++rep) {
            const int idx = rep * 256 + t;           // 0..511 = h*128+k
            const int h = idx >> 7, k = idx & 127;
            float sa = 0.f, sd = 0.f;
            for (int c = 0; c < 64; ++c) {
                const float wv = w1[k * 256 + h * 64 + c];
                sa = fmaf(wv, as1w[h * 64 + c], sa);
                sd = fmaf(wv, ad1w[h * 64 + c], sd);
            }
            va[idx] = sa;
            vd[idx] = sd;
        }
    } else {
        const int i = (b - 259) * 256 + t;
        if (i < NN) counts[i] = 0;
    }
}

// ====== x -> fp16, + as1/ad1 = x·va / x·vd (16 lanes per node) ======
__global__ __launch_bounds__(256) void k_xcvt(
    const float* __restrict__ x, const float* __restrict__ va,
    const float* __restrict__ vd, _Float16* __restrict__ xh,
    float* __restrict__ as_, float* __restrict__ ad_)
{
    const int gid = blockIdx.x * 256 + threadIdx.x;
    const int n = gid >> 4;
    if (n >= NN) return;
    const int j = gid & 15;
    const int k0 = j * 8;
    float xv[8];
    *(float4*)&xv[0] = *(const float4*)&x[(size_t)n * 128 + k0];
    *(float4*)&xv[4] = *(const float4*)&x[(size_t)n * 128 + k0 + 4];
    half8 hv;
#pragma unroll
    for (int i = 0; i < 8; ++i) hv[i] = (_Float16)xv[i];
    *(half8*)&xh[(size_t)n * 128 + k0] = hv;
    float sa[4], sd[4];
#pragma unroll
    for (int h = 0; h < 4; ++h) {
        float s = 0.f, d = 0.f;
#pragma unroll
        for (int i = 0; i < 8; ++i) {
            s = fmaf(xv[i], va[h * 128 + k0 + i], s);
            d = fmaf(xv[i], vd[h * 128 + k0 + i], d);
        }
        sa[h] = gsum16(s);
        sd[h] = gsum16(d);
    }
    if (j == 0) {
        *(float4*)&as_[n * 4] = make_float4(sa[0], sa[1], sa[2], sa[3]);
        *(float4*)&ad_[n * 4] = make_float4(sd[0], sd[1], sd[2], sd[3]);
    }
}

// ====== layer-1 aggregation over x: y[d][h][:] = sum_s alpha^h * xh[s] ======
// one wave per dst; head = lane>>4, cols = (lane&15)*8; 256B gather per edge.
__global__ __launch_bounds__(256) void k_agg1x(
    const int* __restrict__ rowptr, const int* __restrict__ srcs,
    const _Float16* __restrict__ xh, const float* __restrict__ as_,
    const float* __restrict__ ad_, _Float16* __restrict__ y)
{
    const int d = blockIdx.x * 4 + (threadIdx.x >> 6);
    if (d >= NN) return;
    const int lane = threadIdx.x & 63;
    const int r0 = rowptr[d], r1 = rowptr[d + 1];
    const int h = lane >> 4;
    const int cb = (lane & 15) * 8;
    const float myad = ad_[d * 4 + h];

    float den = 0.f;
    float acc[8] = {0.f, 0.f, 0.f, 0.f, 0.f, 0.f, 0.f, 0.f};
    int k = r0;
    for (; k + 3 < r1; k += 4) {
        const int s0 = srcs[k], s1 = srcs[k + 1], s2 = srcs[k + 2], s3 = srcs[k + 3];
        const float p0 = __expf(lrelu(as_[s0 * 4 + h] + myad));
        const float p1 = __expf(lrelu(as_[s1 * 4 + h] + myad));
        const float p2 = __expf(lrelu(as_[s2 * 4 + h] + myad));
        const float p3 = __expf(lrelu(as_[s3 * 4 + h] + myad));
        const half8 v0 = *(const half8*)&xh[(size_t)s0 * 128 + cb];
        const half8 v1 = *(const half8*)&xh[(size_t)s1 * 128 + cb];
        const half8 v2 = *(const half8*)&xh[(size_t)s2 * 128 + cb];
        const half8 v3 = *(const half8*)&xh[(size_t)s3 * 128 + cb];
        den += (p0 + p1) + (p2 + p3);
#pragma unroll
        for (int i = 0; i < 8; ++i) {
            acc[i] = fmaf(p0, (float)v0[i], acc[i]);
            acc[i] = fmaf(p1, (float)v1[i], acc[i]);
            acc[i] = fmaf(p2, (float)v2[i], acc[i]);
            acc[i] = fmaf(p3, (float)v3[i], acc[i]);
        }
    }
    for (; k < r1; ++k) {
        const int s = srcs[k];
        const float p = __expf(lrelu(as_[s * 4 + h] + myad));
        den += p;
        const half8 v = *(const half8*)&xh[(size_t)s * 128 + cb];
#pragma unroll
        for (int i = 0; i < 8; ++i) acc[i] = fmaf(p, (float)v[i], acc[i]);
    }
    // every lane saw every edge -> den is complete per lane (per head)
    const float inv = 1.f / (den + 1e-16f);
    half8 hv;
#pragma unroll
    for (int i = 0; i < 8; ++i) hv[i] = (_Float16)(acc[i] * inv);
    *(half8*)&y[(size_t)d * 512 + h * 128 + cb] = hv;
}

// ====== block-diagonal MFMA: agg1h = ELU(BN1( y_h @ W1_h )) per head ======
__global__ __launch_bounds__(256) void k_bd1(
    const _Float16* __restrict__ y, const _Float16* __restrict__ wt, // wt1[256][128]
    const float* __restrict__ scs, const float* __restrict__ shs,
    _Float16* __restrict__ agg)
{
    __shared__ _Float16 ys[128][136];
    const int n0 = blockIdx.x * 128;
    const int t = threadIdx.x;
    const int l = t & 63, w = t >> 6;
    const int m0w = (w & 1) * 64, n0w = (w >> 1) * 32;   // 2M x 2N(32)
    const int lc = l & 15, kq = (l >> 4) * 8, lr = (l >> 4) * 4;

    for (int h = 0; h < 4; ++h) {
        if (h) __syncthreads();
        // stage y[:,h,:] tile
#pragma unroll
        for (int i = 0; i < 8; ++i) {
            const int f = i * 2048 + t * 8;
            const int m = f >> 7, k8 = f & 127;
            half8 v = {};
            if (n0 + m < NN)
                v = *(const half8*)&y[(size_t)(n0 + m) * 512 + h * 128 + k8];
            *(half8*)&ys[m][k8] = v;
        }
        __syncthreads();

        const f32x4 fzero = {0.f, 0.f, 0.f, 0.f};
        f32x4 acc[4][2];
#pragma unroll
        for (int r = 0; r < 4; ++r) { acc[r][0] = fzero; acc[r][1] = fzero; }

#pragma unroll
        for (int ks = 0; ks < 4; ++ks) {
            const int k0 = ks * 32 + kq;
            const half8 a0 = *(const half8*)&ys[m0w + 0  + lc][k0];
            const half8 a1 = *(const half8*)&ys[m0w + 16 + lc][k0];
            const half8 a2 = *(const half8*)&ys[m0w + 32 + lc][k0];
            const half8 a3 = *(const half8*)&ys[m0w + 48 + lc][k0];
#pragma unroll
            for (int c = 0; c < 2; ++c) {
                const half8 b = *(const half8*)&wt[(size_t)(h * 64 + n0w + c * 16 + lc) * 128 + k0];
                acc[0][c] = __builtin_amdgcn_mfma_f32_16x16x32_f16(a0, b, acc[0][c], 0, 0, 0);
                acc[1][c] = __builtin_amdgcn_mfma_f32_16x16x32_f16(a1, b, acc[1][c], 0, 0, 0);
                acc[2][c] = __builtin_amdgcn_mfma_f32_16x16x32_f16(a2, b, acc[2][c], 0, 0, 0);
                acc[3][c] = __builtin_amdgcn_mfma_f32_16x16x32_f16(a3, b, acc[3][c], 0, 0, 0);
            }
        }

        const int j0 = h * 64 + n0w + lc;
        const float sc0 = scs[j0],      sh0 = shs[j0];
        const float sc1 = scs[j0 + 16], sh1 = shs[j0 + 16];
#pragma unroll
        for (int r = 0; r < 4; ++r) {
#pragma unroll
            for (int i = 0; i < 4; ++i) {
                const int rg = n0 + m0w + r * 16 + lr + i;
                if (rg < NN) {
                    float e0 = fmaf(acc[r][0][i], sc0, sh0);
                    float e1 = fmaf(acc[r][1][i], sc1, sh1);
                    e0 = e0 > 0.f ? e0 : __expf(e0) - 1.f;
                    e1 = e1 > 0.f ? e1 : __expf(e1) - 1.f;
                    _Float16* ap = agg + (size_t)rg * 256 + j0;
                    ap[0]  = (_Float16)e0;
                    ap[16] = (_Float16)e1;
                }
            }
        }
    }
}

// ====== MFMA GEMM2: agg1h(fp16, post BN/ELU) @ w2 -> {ad2, pack{as2,q}} ======
__global__ __launch_bounds__(256) void k_gemm2m(
    const _Float16* __restrict__ agg, const _Float16* __restrict__ wt, // wt2[128][256]
    const float* __restrict__ asrc, const float* __restrict__ adst,
    const float* __restrict__ wq,
    float* __restrict__ ad_, uint2* __restrict__ pack)
{
    __shared__ _Float16 xs[128][136];
    const int n0 = blockIdx.x * 128;
    const int t = threadIdx.x;
    const int l = t & 63, w = t >> 6;
    const int m0w = (w & 1) * 64, n0w = (w >> 1) * 64;
    const int lc = l & 15, kq = (l >> 4) * 8, lr = (l >> 4) * 4;

    const f32x4 fzero = {0.f, 0.f, 0.f, 0.f};
    f32x4 acc[4][4];
#pragma unroll
    for (int r = 0; r < 4; ++r)
#pragma unroll
        for (int c = 0; c < 4; ++c) acc[r][c] = fzero;

    const _Float16* abase = agg + (size_t)n0 * 256;
    for (int kc = 0; kc < 2; ++kc) {
        if (kc) __syncthreads();
#pragma unroll
        for (int i = 0; i < 8; ++i) {
            const int f = i * 2048 + t * 8;
            const int m = f >> 7, k8 = f & 127;
            half8 v = {};
            if (n0 + m < NN)
                v = *(const half8*)(abase + (size_t)m * 256 + kc * 128 + k8);
            *(half8*)&xs[m][k8] = v;
        }
        __syncthreads();

#pragma unroll
        for (int ks = 0; ks < 4; ++ks) {
            const int k0 = ks * 32 + kq;
            const int kgf = kc * 128 + k0;
            const half8 a0 = *(const half8*)&xs[m0w + 0  + lc][k0];
            const half8 a1 = *(const half8*)&xs[m0w + 16 + lc][k0];
            const half8 a2 = *(const half8*)&xs[m0w + 32 + lc][k0];
            const half8 a3 = *(const half8*)&xs[m0w + 48 + lc][k0];
#pragma unroll
            for (int c = 0; c < 4; ++c) {
                const half8 b = *(const half8*)&wt[(size_t)(n0w + c * 16 + lc) * 256 + kgf];
                acc[0][c] = __builtin_amdgcn_mfma_f32_16x16x32_f16(a0, b, acc[0][c], 0, 0, 0);
                acc[1][c] = __builtin_amdgcn_mfma_f32_16x16x32_f16(a1, b, acc[1][c], 0, 0, 0);
                acc[2][c] = __builtin_amdgcn_mfma_f32_16x16x32_f16(a2, b, acc[2][c], 0, 0, 0);
                acc[3][c] = __builtin_amdgcn_mfma_f32_16x16x32_f16(a3, b, acc[3][c], 0, 0, 0);
            }
        }
    }

    const int head = n0w >> 6;
    float awv[4], dwv[4], wq0[4], wq1[4];
#pragma unroll
    for (int c = 0; c < 4; ++c) {
        const int j = n0w + c * 16 + lc;
        const int cl = j & 63;
        awv[c] = asrc[j];
        dwv[c] = adst[j];
        wq0[c] = wq[cl * 2 + 0];
        wq1[c] = wq[cl * 2 + 1];
    }
#pragma unroll
    for (int r = 0; r < 4; ++r) {
#pragma unroll
        for (int i = 0; i < 4; ++i) {
            float s = 0.f, d = 0.f, q0 = 0.f, q1 = 0.f;
#pragma unroll
            for (int c = 0; c < 4; ++c) {
                s = fmaf(acc[r][c][i], awv[c], s);
                d = fmaf(acc[r][c][i], dwv[c], d);
                q0 = fmaf(acc[r][c][i], wq0[c], q0);
                q1 = fmaf(acc[r][c][i], wq1[c], q1);
            }
            s = gsum16(s); d = gsum16(d); q0 = gsum16(q0); q1 = gsum16(q1);
            const int rg = n0 + m0w + r * 16 + lr + i;
            if (lc == 0 && rg < NN) {
                ad_[rg * 2 + head] = d;
                uint2 u;
                u.x = __float_as_uint(s);
                u.y = packh2(q0, q1);
                pack[rg * 2 + head] = u;
            }
        }
    }
}

// ====== layer-2: single-pass softmax; one 16B record gather per edge ======
__global__ __launch_bounds__(256) void k_agg2q(
    const int* __restrict__ rowptr, const int* __restrict__ srcs,
    const uint4* __restrict__ pack, const float* __restrict__ ad_,
    const float* __restrict__ cst, float* __restrict__ out)
{
    const int d = blockIdx.x * 16 + (threadIdx.x >> 4);
    if (d >= NN) return;
    const int il = threadIdx.x & 15;
    const int r0 = rowptr[d], r1 = rowptr[d + 1];
    const float2 adv = *(const float2*)&ad_[d * 2];

    float den0 = 0.f, den1 = 0.f;
    float qa00 = 0.f, qa01 = 0.f, qa10 = 0.f, qa11 = 0.f;
    for (int k = r0 + il; k < r1; k += 16) {
        const int s = srcs[k];
        const uint4 rec = pack[s];
        const float a0 = __uint_as_float(rec.x);
        const float a1 = __uint_as_float(rec.z);
        const float2 q0 = __half22float2(*reinterpret_cast<const __half2*>(&rec.y));
        const float2 q1 = __half22float2(*reinterpret_cast<const __half2*>(&rec.w));
        const float p0 = __expf(lrelu(a0 + adv.x));
        const float p1 = __expf(lrelu(a1 + adv.y));
        den0 += p0; den1 += p1;
        qa00 = fmaf(p0, q0.x, qa00); qa01 = fmaf(p0, q0.y, qa01);
        qa10 = fmaf(p1, q1.x, qa10); qa11 = fmaf(p1, q1.y, qa11);
    }
    den0 = gsum16(den0); den1 = gsum16(den1);
    qa00 = gsum16(qa00); qa01 = gsum16(qa01);
    qa10 = gsum16(qa10); qa11 = gsum16(qa11);
    if (il == 0) {
        const float i0 = 1.f / (den0 + 1e-16f);
        const float i1 = 1.f / (den1 + 1e-16f);
        out[d * 2 + 0] = cst[0] + 0.5f * (qa00 * i0 + qa10 * i1);
        out[d * 2 + 1] = cst[1] + 0.5f * (qa01 * i0 + qa11 * i1);
    }
}

extern "C" void kernel_launch(void* const* d_in, const int* in_sizes, int n_in,
                              void* d_out, int out_size, void* d_ws, size_t ws_size,
                              hipStream_t stream) {
    const float* x      = (const float*)d_in[0];
    const int*   ei     = (const int*)d_in[1];
    const float* w1     = (const float*)d_in[2];
    const float* a_src1 = (const float*)d_in[3];
    const float* a_dst1 = (const float*)d_in[4];
    const float* b1     = (const float*)d_in[5];
    const float* g1     = (const float*)d_in[6];
    const float* be1    = (const float*)d_in[7];
    const float* m1     = (const float*)d_in[8];
    const float* v1     = (const float*)d_in[9];
    const float* w2     = (const float*)d_in[10];
    const float* a_src2 = (const float*)d_in[11];
    const float* a_dst2 = (const float*)d_in[12];
    const float* b2     = (const float*)d_in[13];
    const float* g2     = (const float*)d_in[14];
    const float* be2    = (const float*)d_in[15];
    const float* m2     = (const float*)d_in[16];
    const float* v2     = (const float*)d_in[17];
    const float* wc     = (const float*)d_in[18];
    const float* bc     = (const float*)d_in[19];
    float* out = (float*)d_out;

    float* ws = (float*)d_ws;
    _Float16* xh    = (_Float16*)ws;                      // NN*128 h  (NN*64 fl)
    _Float16* y     = (_Float16*)(ws + (size_t)NN * 64);  // NN*512 h  (NN*256 fl)
    _Float16* agg1h = (_Float16*)(ws + (size_t)NN * 320); // NN*256 h  (NN*128 fl)
    float* C = ws + (size_t)NN * 448;

    float* as1 = C;                        // NN*4
    float* ad1 = C + (size_t)NN * 4;       // NN*4
    float* ad2 = C + (size_t)NN * 8;       // NN*2
    float* packf = C + (size_t)NN * 10;    // NN*4 (uint2 x2 per node)
    float* scs = C + (size_t)NN * 14;      // 256
    float* shs = scs + 256;                // 256
    float* wq  = shs + 256;                // 128
    float* cst = wq + 128;                 // 64
    float* va  = cst + 64;                 // 512
    float* vd  = va + 512;                 // 512
    float* wbase = vd + 512;
    _Float16* wt1 = (_Float16*)wbase;      // 32768 h (16384 fl)
    _Float16* wt2 = wt1 + 32768;           // 32768 h
    int* counts = (int*)(wbase + 32768);   // NN (reused as cursor)
    int* rowptr = counts + NN;             // NN+1
    int* bsum   = rowptr + NN + 63;        // 512
    int* srcs   = bsum + 512;              // ETOT

    // ---- prep (BN folds, w^T, va/vd, zero counts) ----
    k_prep<<<259 + NBLK, 256, 0, stream>>>(b1, g1, be1, m1, v1, b2, g2, be2, m2, v2,
                                           wc, bc, w1, w2, a_src1, a_dst1,
                                           scs, shs, wq, cst, va, vd, wt1, wt2, counts);
    // ---- CSR build ----
    k_hist<<<(EE + 255) / 256, 256, 0, stream>>>(ei, counts);
    k_scan_bsum<<<NBLK, 256, 0, stream>>>(counts, bsum);
    k_scan_top<<<1, 512, 0, stream>>>(bsum, NBLK);
    k_scan_final<<<NBLK, 256, 0, stream>>>(counts, bsum, rowptr, srcs, counts);
    k_scatter<<<(EE + 255) / 256, 256, 0, stream>>>(ei, srcs, counts);

    // ---- layer 1 (h1 never materialized) ----
    k_xcvt<<<(NN * 16 + 255) / 256, 256, 0, stream>>>(x, va, vd, xh, as1, ad1);
    k_agg1x<<<(NN + 3) / 4, 256, 0, stream>>>(rowptr, srcs, xh, as1, ad1, y);
    k_bd1<<<GXM, 256, 0, stream>>>(y, wt1, scs, shs, agg1h);

    // ---- layer 2 ----
    k_gemm2m<<<GXM, 256, 0, stream>>>(agg1h, wt2, a_src2, a_dst2, wq,
                                      ad2, (uint2*)packf);
    k_agg2q<<<(NN + 15) / 16, 256, 0, stream>>>(rowptr, srcs, (const uint4*)packf,
                                                ad2, cst, out);
}

// Round 12
// 377.980 us; speedup vs baseline: 25.4832x; 1.1333x over previous
//
#include <hip/hip_runtime.h>
#include <hip/hip_fp16.h>
#include <math.h>

#define NN 100000
#define EE 1600000
#define ETOT (EE + NN)
#define BN_EPS 1e-5f
#define NEG_SLOPE 0.2f
#define NBLK ((NN + 255) / 256)   // 391
#define GXM ((NN + 127) / 128)    // 782
#define NGRP 8
#define GRPSZ ((NN + NGRP - 1) / NGRP)   // 12500

typedef _Float16 half8 __attribute__((ext_vector_type(8)));
typedef float f32x4 __attribute__((ext_vector_type(4)));

// ---------- helpers ----------
__device__ __forceinline__ float lrelu(float x) { return fmaxf(x, NEG_SLOPE * x); }
__device__ __forceinline__ float wsum(float v) {
#pragma unroll
    for (int m = 32; m; m >>= 1) v += __shfl_xor(v, m, 64);
    return v;
}
__device__ __forceinline__ float gsum16(float v) {
#pragma unroll
    for (int m = 1; m < 16; m <<= 1) v += __shfl_xor(v, m, 64);
    return v;
}
__device__ __forceinline__ unsigned packh2(float a, float b) {
    __half2 p = __float22half2_rn(make_float2(a, b));
    return *reinterpret_cast<unsigned*>(&p);
}

// ================= CSR build (XCD-partitioned by dst range) =================
// group g = blockIdx&7 handles dst in [g*GRPSZ, (g+1)*GRPSZ): atomics + writes
// stay in one XCD's L2 slice instead of thrashing all 8.
__global__ __launch_bounds__(256) void k_hist8(const int* __restrict__ ei,
                                               int* __restrict__ counts) {
    const int g = blockIdx.x & (NGRP - 1);
    const int lo = g * GRPSZ;
    const int hi = (lo + GRPSZ < NN) ? lo + GRPSZ : NN;
    const int nb = gridDim.x >> 3;
    const int stride = nb * 256;
    for (int e = (blockIdx.x >> 3) * 256 + threadIdx.x; e < EE; e += stride) {
        const int d = ei[EE + e];
        if (d >= lo && d < hi) atomicAdd(&counts[d], 1);
    }
}
__global__ __launch_bounds__(256) void k_scatter8(const int* __restrict__ ei,
                                                  int* __restrict__ srcs,
                                                  int* __restrict__ cursor) {
    const int g = blockIdx.x & (NGRP - 1);
    const int lo = g * GRPSZ;
    const int hi = (lo + GRPSZ < NN) ? lo + GRPSZ : NN;
    const int nb = gridDim.x >> 3;
    const int stride = nb * 256;
    for (int e = (blockIdx.x >> 3) * 256 + threadIdx.x; e < EE; e += stride) {
        const int d = ei[EE + e];
        if (d >= lo && d < hi) {
            const int p = atomicAdd(&cursor[d], 1);
            srcs[p] = ei[e];
        }
    }
}
__global__ __launch_bounds__(256) void k_scan_bsum(const int* __restrict__ counts,
                                                   int* __restrict__ bsum) {
    __shared__ int sd[256];
    const int i = blockIdx.x * 256 + threadIdx.x;
    sd[threadIdx.x] = (i < NN) ? counts[i] + 1 : 0;   // +1 = self-loop
    __syncthreads();
    for (int s2 = 128; s2; s2 >>= 1) {
        if (threadIdx.x < s2) sd[threadIdx.x] += sd[threadIdx.x + s2];
        __syncthreads();
    }
    if (threadIdx.x == 0) bsum[blockIdx.x] = sd[0];
}
__global__ __launch_bounds__(512) void k_scan_top(int* __restrict__ bsum, int nb) {
    __shared__ int sd[512];
    const int t = threadIdx.x;
    const int orig = (t < nb) ? bsum[t] : 0;
    sd[t] = orig;
    __syncthreads();
    for (int off = 1; off < 512; off <<= 1) {
        const int v = (t >= off) ? sd[t - off] : 0;
        __syncthreads();
        sd[t] += v;
        __syncthreads();
    }
    if (t < nb) bsum[t] = sd[t] - orig;              // exclusive
}
__global__ __launch_bounds__(256) void k_scan_final(const int* __restrict__ counts,
                                                    const int* __restrict__ bsum_ex,
                                                    int* __restrict__ rowptr,
                                                    int* __restrict__ srcs,
                                                    int* __restrict__ cursor) {
    __shared__ int sd[256];
    const int i = blockIdx.x * 256 + threadIdx.x;
    const int orig = (i < NN) ? counts[i] + 1 : 0;
    sd[threadIdx.x] = orig;
    __syncthreads();
    for (int off = 1; off < 256; off <<= 1) {
        const int v = (threadIdx.x >= off) ? sd[threadIdx.x - off] : 0;
        __syncthreads();
        sd[threadIdx.x] += v;
        __syncthreads();
    }
    if (i < NN) {
        const int rp = bsum_ex[blockIdx.x] + sd[threadIdx.x] - orig;
        rowptr[i] = rp;
        srcs[rp] = i;                                // self-loop first
        cursor[i] = rp + 1;
        if (i == NN - 1) rowptr[NN] = ETOT;
    }
}

// ===== prep: BN folds | w^T fp16 | va/vd = W1_h · a_{src,dst} | zero counts =====
__global__ __launch_bounds__(256) void k_prep(
    const float* __restrict__ b1, const float* __restrict__ g1,
    const float* __restrict__ be1, const float* __restrict__ m1,
    const float* __restrict__ v1,
    const float* __restrict__ b2, const float* __restrict__ g2,
    const float* __restrict__ be2, const float* __restrict__ m2,
    const float* __restrict__ v2, const float* __restrict__ wc,
    const float* __restrict__ bc,
    const float* __restrict__ w1, const float* __restrict__ w2,
    const float* __restrict__ as1w, const float* __restrict__ ad1w,
    float* __restrict__ scs, float* __restrict__ shs,
    float* __restrict__ wq, float* __restrict__ cst,
    float* __restrict__ va, float* __restrict__ vd,
    _Float16* __restrict__ wt1, _Float16* __restrict__ wt2,
    int* __restrict__ counts)
{
    const int b = blockIdx.x, t = threadIdx.x;
    if (b == 0) {
        const float sc = g1[t] * rsqrtf(v1[t] + BN_EPS);
        scs[t] = sc;
        shs[t] = (b1[t] - m1[t]) * sc + be1[t];
    } else if (b == 1) {
        if (t < 64) {
            const float s2 = g2[t] * rsqrtf(v2[t] + BN_EPS);
            wq[t * 2 + 0] = s2 * wc[t * 2 + 0];
            wq[t * 2 + 1] = s2 * wc[t * 2 + 1];
            const float tv = (b2[t] - m2[t]) * s2 + be2[t];
            const float c0 = wsum(tv * wc[t * 2 + 0]);
            const float c1 = wsum(tv * wc[t * 2 + 1]);
            if (t == 0) { cst[0] = c0 + bc[0]; cst[1] = c1 + bc[1]; }
        }
    } else if (b < 130) {
        const int idx = (b - 2) * 256 + t;           // wt1[n][k] = w1[k][n]
        const int n = idx >> 7, k = idx & 127;
        wt1[idx] = (_Float16)w1[k * 256 + n];
    } else if (b < 258) {
        const int idx = (b - 130) * 256 + t;         // wt2[n][k] = w2[k][n]
        const int n = idx >> 8, k = idx & 255;
        wt2[idx] = (_Float16)w2[k * 128 + n];
    } else if (b == 258) {
#pragma unroll
        for (int rep = 0; rep < 2; ++rep) {
            const int idx = rep * 256 + t;           // 0..511 = h*128+k
            const int h = idx >> 7, k = idx & 127;
            float sa = 0.f, sd = 0.f;
            for (int c = 0; c < 64; ++c) {
                const float wv = w1[k * 256 + h * 64 + c];
                sa = fmaf(wv, as1w[h * 64 + c], sa);
                sd = fmaf(wv, ad1w[h * 64 + c], sd);
            }
            va[idx] = sa;
            vd[idx] = sd;
        }
    } else {
        const int i = (b - 259) * 256 + t;
        if (i < NN) counts[i] = 0;
    }
}

// ====== x -> fp16, + as1/ad1 = x·va / x·vd (16 lanes per node) ======
__global__ __launch_bounds__(256) void k_xcvt(
    const float* __restrict__ x, const float* __restrict__ va,
    const float* __restrict__ vd, _Float16* __restrict__ xh,
    float* __restrict__ as_, float* __restrict__ ad_)
{
    const int gid = blockIdx.x * 256 + threadIdx.x;
    const int n = gid >> 4;
    if (n >= NN) return;
    const int j = gid & 15;
    const int k0 = j * 8;
    float xv[8];
    *(float4*)&xv[0] = *(const float4*)&x[(size_t)n * 128 + k0];
    *(float4*)&xv[4] = *(const float4*)&x[(size_t)n * 128 + k0 + 4];
    half8 hv;
#pragma unroll
    for (int i = 0; i < 8; ++i) hv[i] = (_Float16)xv[i];
    *(half8*)&xh[(size_t)n * 128 + k0] = hv;
    float sa[4], sd[4];
#pragma unroll
    for (int h = 0; h < 4; ++h) {
        float s = 0.f, d = 0.f;
#pragma unroll
        for (int i = 0; i < 8; ++i) {
            s = fmaf(xv[i], va[h * 128 + k0 + i], s);
            d = fmaf(xv[i], vd[h * 128 + k0 + i], d);
        }
        sa[h] = gsum16(s);
        sd[h] = gsum16(d);
    }
    if (j == 0) {
        *(float4*)&as_[n * 4] = make_float4(sa[0], sa[1], sa[2], sa[3]);
        *(float4*)&ad_[n * 4] = make_float4(sd[0], sd[1], sd[2], sd[3]);
    }
}

// ====== layer-1 aggregation over x: y[d][h][:] = sum_s alpha^h * xh[s] ======
__global__ __launch_bounds__(256) void k_agg1x(
    const int* __restrict__ rowptr, const int* __restrict__ srcs,
    const _Float16* __restrict__ xh, const float* __restrict__ as_,
    const float* __restrict__ ad_, _Float16* __restrict__ y)
{
    const int d = blockIdx.x * 4 + (threadIdx.x >> 6);
    if (d >= NN) return;
    const int lane = threadIdx.x & 63;
    const int r0 = rowptr[d], r1 = rowptr[d + 1];
    const int h = lane >> 4;
    const int cb = (lane & 15) * 8;
    const float myad = ad_[d * 4 + h];

    float den = 0.f;
    float acc[8] = {0.f, 0.f, 0.f, 0.f, 0.f, 0.f, 0.f, 0.f};
    int k = r0;
    for (; k + 3 < r1; k += 4) {
        const int s0 = srcs[k], s1 = srcs[k + 1], s2 = srcs[k + 2], s3 = srcs[k + 3];
        const float p0 = __expf(lrelu(as_[s0 * 4 + h] + myad));
        const float p1 = __expf(lrelu(as_[s1 * 4 + h] + myad));
        const float p2 = __expf(lrelu(as_[s2 * 4 + h] + myad));
        const float p3 = __expf(lrelu(as_[s3 * 4 + h] + myad));
        const half8 v0 = *(const half8*)&xh[(size_t)s0 * 128 + cb];
        const half8 v1 = *(const half8*)&xh[(size_t)s1 * 128 + cb];
        const half8 v2 = *(const half8*)&xh[(size_t)s2 * 128 + cb];
        const half8 v3 = *(const half8*)&xh[(size_t)s3 * 128 + cb];
        den += (p0 + p1) + (p2 + p3);
#pragma unroll
        for (int i = 0; i < 8; ++i) {
            acc[i] = fmaf(p0, (float)v0[i], acc[i]);
            acc[i] = fmaf(p1, (float)v1[i], acc[i]);
            acc[i] = fmaf(p2, (float)v2[i], acc[i]);
            acc[i] = fmaf(p3, (float)v3[i], acc[i]);
        }
    }
    for (; k < r1; ++k) {
        const int s = srcs[k];
        const float p = __expf(lrelu(as_[s * 4 + h] + myad));
        den += p;
        const half8 v = *(const half8*)&xh[(size_t)s * 128 + cb];
#pragma unroll
        for (int i = 0; i < 8; ++i) acc[i] = fmaf(p, (float)v[i], acc[i]);
    }
    const float inv = 1.f / (den + 1e-16f);
    half8 hv;
#pragma unroll
    for (int i = 0; i < 8; ++i) hv[i] = (_Float16)(acc[i] * inv);
    *(half8*)&y[(size_t)d * 512 + h * 128 + cb] = hv;
}

// ====== block-diagonal MFMA: agg1h = ELU(BN1( y_h @ W1_h )) per head ======
__global__ __launch_bounds__(256) void k_bd1(
    const _Float16* __restrict__ y, const _Float16* __restrict__ wt, // wt1[256][128]
    const float* __restrict__ scs, const float* __restrict__ shs,
    _Float16* __restrict__ agg)
{
    __shared__ _Float16 ys[128][136];
    const int n0 = blockIdx.x * 128;
    const int t = threadIdx.x;
    const int l = t & 63, w = t >> 6;
    const int m0w = (w & 1) * 64, n0w = (w >> 1) * 32;   // 2M x 2N(32)
    const int lc = l & 15, kq = (l >> 4) * 8, lr = (l >> 4) * 4;

    for (int h = 0; h < 4; ++h) {
        if (h) __syncthreads();
#pragma unroll
        for (int i = 0; i < 8; ++i) {
            const int f = i * 2048 + t * 8;
            const int m = f >> 7, k8 = f & 127;
            half8 v = {};
            if (n0 + m < NN)
                v = *(const half8*)&y[(size_t)(n0 + m) * 512 + h * 128 + k8];
            *(half8*)&ys[m][k8] = v;
        }
        __syncthreads();

        const f32x4 fzero = {0.f, 0.f, 0.f, 0.f};
        f32x4 acc[4][2];
#pragma unroll
        for (int r = 0; r < 4; ++r) { acc[r][0] = fzero; acc[r][1] = fzero; }

#pragma unroll
        for (int ks = 0; ks < 4; ++ks) {
            const int k0 = ks * 32 + kq;
            const half8 a0 = *(const half8*)&ys[m0w + 0  + lc][k0];
            const half8 a1 = *(const half8*)&ys[m0w + 16 + lc][k0];
            const half8 a2 = *(const half8*)&ys[m0w + 32 + lc][k0];
            const half8 a3 = *(const half8*)&ys[m0w + 48 + lc][k0];
#pragma unroll
            for (int c = 0; c < 2; ++c) {
                const half8 b = *(const half8*)&wt[(size_t)(h * 64 + n0w + c * 16 + lc) * 128 + k0];
                acc[0][c] = __builtin_amdgcn_mfma_f32_16x16x32_f16(a0, b, acc[0][c], 0, 0, 0);
                acc[1][c] = __builtin_amdgcn_mfma_f32_16x16x32_f16(a1, b, acc[1][c], 0, 0, 0);
                acc[2][c] = __builtin_amdgcn_mfma_f32_16x16x32_f16(a2, b, acc[2][c], 0, 0, 0);
                acc[3][c] = __builtin_amdgcn_mfma_f32_16x16x32_f16(a3, b, acc[3][c], 0, 0, 0);
            }
        }

        const int j0 = h * 64 + n0w + lc;
        const float sc0 = scs[j0],      sh0 = shs[j0];
        const float sc1 = scs[j0 + 16], sh1 = shs[j0 + 16];
#pragma unroll
        for (int r = 0; r < 4; ++r) {
#pragma unroll
            for (int i = 0; i < 4; ++i) {
                const int rg = n0 + m0w + r * 16 + lr + i;
                if (rg < NN) {
                    float e0 = fmaf(acc[r][0][i], sc0, sh0);
                    float e1 = fmaf(acc[r][1][i], sc1, sh1);
                    e0 = e0 > 0.f ? e0 : __expf(e0) - 1.f;
                    e1 = e1 > 0.f ? e1 : __expf(e1) - 1.f;
                    _Float16* ap = agg + (size_t)rg * 256 + j0;
                    ap[0]  = (_Float16)e0;
                    ap[16] = (_Float16)e1;
                }
            }
        }
    }
}

// ====== MFMA GEMM2: agg1h(fp16, post BN/ELU) @ w2 -> {ad2, pack{as2,q}} ======
__global__ __launch_bounds__(256) void k_gemm2m(
    const _Float16* __restrict__ agg, const _Float16* __restrict__ wt, // wt2[128][256]
    const float* __restrict__ asrc, const float* __restrict__ adst,
    const float* __restrict__ wq,
    float* __restrict__ ad_, uint2* __restrict__ pack)
{
    __shared__ _Float16 xs[128][136];
    const int n0 = blockIdx.x * 128;
    const int t = threadIdx.x;
    const int l = t & 63, w = t >> 6;
    const int m0w = (w & 1) * 64, n0w = (w >> 1) * 64;
    const int lc = l & 15, kq = (l >> 4) * 8, lr = (l >> 4) * 4;

    const f32x4 fzero = {0.f, 0.f, 0.f, 0.f};
    f32x4 acc[4][4];
#pragma unroll
    for (int r = 0; r < 4; ++r)
#pragma unroll
        for (int c = 0; c < 4; ++c) acc[r][c] = fzero;

    const _Float16* abase = agg + (size_t)n0 * 256;
    for (int kc = 0; kc < 2; ++kc) {
        if (kc) __syncthreads();
#pragma unroll
        for (int i = 0; i < 8; ++i) {
            const int f = i * 2048 + t * 8;
            const int m = f >> 7, k8 = f & 127;
            half8 v = {};
            if (n0 + m < NN)
                v = *(const half8*)(abase + (size_t)m * 256 + kc * 128 + k8);
            *(half8*)&xs[m][k8] = v;
        }
        __syncthreads();

#pragma unroll
        for (int ks = 0; ks < 4; ++ks) {
            const int k0 = ks * 32 + kq;
            const int kgf = kc * 128 + k0;
            const half8 a0 = *(const half8*)&xs[m0w + 0  + lc][k0];
            const half8 a1 = *(const half8*)&xs[m0w + 16 + lc][k0];
            const half8 a2 = *(const half8*)&xs[m0w + 32 + lc][k0];
            const half8 a3 = *(const half8*)&xs[m0w + 48 + lc][k0];
#pragma unroll
            for (int c = 0; c < 4; ++c) {
                const half8 b = *(const half8*)&wt[(size_t)(n0w + c * 16 + lc) * 256 + kgf];
                acc[0][c] = __builtin_amdgcn_mfma_f32_16x16x32_f16(a0, b, acc[0][c], 0, 0, 0);
                acc[1][c] = __builtin_amdgcn_mfma_f32_16x16x32_f16(a1, b, acc[1][c], 0, 0, 0);
                acc[2][c] = __builtin_amdgcn_mfma_f32_16x16x32_f16(a2, b, acc[2][c], 0, 0, 0);
                acc[3][c] = __builtin_amdgcn_mfma_f32_16x16x32_f16(a3, b, acc[3][c], 0, 0, 0);
            }
        }
    }

    const int head = n0w >> 6;
    float awv[4], dwv[4], wq0[4], wq1[4];
#pragma unroll
    for (int c = 0; c < 4; ++c) {
        const int j = n0w + c * 16 + lc;
        const int cl = j & 63;
        awv[c] = asrc[j];
        dwv[c] = adst[j];
        wq0[c] = wq[cl * 2 + 0];
        wq1[c] = wq[cl * 2 + 1];
    }
#pragma unroll
    for (int r = 0; r < 4; ++r) {
#pragma unroll
        for (int i = 0; i < 4; ++i) {
            float s = 0.f, d = 0.f, q0 = 0.f, q1 = 0.f;
#pragma unroll
            for (int c = 0; c < 4; ++c) {
                s = fmaf(acc[r][c][i], awv[c], s);
                d = fmaf(acc[r][c][i], dwv[c], d);
                q0 = fmaf(acc[r][c][i], wq0[c], q0);
                q1 = fmaf(acc[r][c][i], wq1[c], q1);
            }
            s = gsum16(s); d = gsum16(d); q0 = gsum16(q0); q1 = gsum16(q1);
            const int rg = n0 + m0w + r * 16 + lr + i;
            if (lc == 0 && rg < NN) {
                ad_[rg * 2 + head] = d;
                uint2 u;
                u.x = __float_as_uint(s);
                u.y = packh2(q0, q1);
                pack[rg * 2 + head] = u;
            }
        }
    }
}

// ====== layer-2: single-pass softmax; one 16B record gather per edge ======
__global__ __launch_bounds__(256) void k_agg2q(
    const int* __restrict__ rowptr, const int* __restrict__ srcs,
    const uint4* __restrict__ pack, const float* __restrict__ ad_,
    const float* __restrict__ cst, float* __restrict__ out)
{
    const int d = blockIdx.x * 16 + (threadIdx.x >> 4);
    if (d >= NN) return;
    const int il = threadIdx.x & 15;
    const int r0 = rowptr[d], r1 = rowptr[d + 1];
    const float2 adv = *(const float2*)&ad_[d * 2];

    float den0 = 0.f, den1 = 0.f;
    float qa00 = 0.f, qa01 = 0.f, qa10 = 0.f, qa11 = 0.f;
    for (int k = r0 + il; k < r1; k += 16) {
        const int s = srcs[k];
        const uint4 rec = pack[s];
        const float a0 = __uint_as_float(rec.x);
        const float a1 = __uint_as_float(rec.z);
        const float2 q0 = __half22float2(*reinterpret_cast<const __half2*>(&rec.y));
        const float2 q1 = __half22float2(*reinterpret_cast<const __half2*>(&rec.w));
        const float p0 = __expf(lrelu(a0 + adv.x));
        const float p1 = __expf(lrelu(a1 + adv.y));
        den0 += p0; den1 += p1;
        qa00 = fmaf(p0, q0.x, qa00); qa01 = fmaf(p0, q0.y, qa01);
        qa10 = fmaf(p1, q1.x, qa10); qa11 = fmaf(p1, q1.y, qa11);
    }
    den0 = gsum16(den0); den1 = gsum16(den1);
    qa00 = gsum16(qa00); qa01 = gsum16(qa01);
    qa10 = gsum16(qa10); qa11 = gsum16(qa11);
    if (il == 0) {
        const float i0 = 1.f / (den0 + 1e-16f);
        const float i1 = 1.f / (den1 + 1e-16f);
        out[d * 2 + 0] = cst[0] + 0.5f * (qa00 * i0 + qa10 * i1);
        out[d * 2 + 1] = cst[1] + 0.5f * (qa01 * i0 + qa11 * i1);
    }
}

extern "C" void kernel_launch(void* const* d_in, const int* in_sizes, int n_in,
                              void* d_out, int out_size, void* d_ws, size_t ws_size,
                              hipStream_t stream) {
    const float* x      = (const float*)d_in[0];
    const int*   ei     = (const int*)d_in[1];
    const float* w1     = (const float*)d_in[2];
    const float* a_src1 = (const float*)d_in[3];
    const float* a_dst1 = (const float*)d_in[4];
    const float* b1     = (const float*)d_in[5];
    const float* g1     = (const float*)d_in[6];
    const float* be1    = (const float*)d_in[7];
    const float* m1     = (const float*)d_in[8];
    const float* v1     = (const float*)d_in[9];
    const float* w2     = (const float*)d_in[10];
    const float* a_src2 = (const float*)d_in[11];
    const float* a_dst2 = (const float*)d_in[12];
    const float* b2     = (const float*)d_in[13];
    const float* g2     = (const float*)d_in[14];
    const float* be2    = (const float*)d_in[15];
    const float* m2     = (const float*)d_in[16];
    const float* v2     = (const float*)d_in[17];
    const float* wc     = (const float*)d_in[18];
    const float* bc     = (const float*)d_in[19];
    float* out = (float*)d_out;

    float* ws = (float*)d_ws;
    _Float16* xh    = (_Float16*)ws;                      // NN*128 h  (NN*64 fl)
    _Float16* y     = (_Float16*)(ws + (size_t)NN * 64);  // NN*512 h  (NN*256 fl)
    _Float16* agg1h = (_Float16*)(ws + (size_t)NN * 320); // NN*256 h  (NN*128 fl)
    float* C = ws + (size_t)NN * 448;

    float* as1 = C;                        // NN*4
    float* ad1 = C + (size_t)NN * 4;       // NN*4
    float* ad2 = C + (size_t)NN * 8;       // NN*2
    float* packf = C + (size_t)NN * 10;    // NN*4 (uint2 x2 per node)
    float* scs = C + (size_t)NN * 14;      // 256
    float* shs = scs + 256;                // 256
    float* wq  = shs + 256;                // 128
    float* cst = wq + 128;                 // 64
    float* va  = cst + 64;                 // 512
    float* vd  = va + 512;                 // 512
    float* wbase = vd + 512;
    _Float16* wt1 = (_Float16*)wbase;      // 32768 h (16384 fl)
    _Float16* wt2 = wt1 + 32768;           // 32768 h
    int* counts = (int*)(wbase + 32768);   // NN (reused as cursor)
    int* rowptr = counts + NN;             // NN+1
    int* bsum   = rowptr + NN + 63;        // 512
    int* srcs   = bsum + 512;              // ETOT

    // ---- prep (BN folds, w^T, va/vd, zero counts) ----
    k_prep<<<259 + NBLK, 256, 0, stream>>>(b1, g1, be1, m1, v1, b2, g2, be2, m2, v2,
                                           wc, bc, w1, w2, a_src1, a_dst1,
                                           scs, shs, wq, cst, va, vd, wt1, wt2, counts);
    // ---- CSR build (XCD-partitioned hist + scatter) ----
    k_hist8<<<2048, 256, 0, stream>>>(ei, counts);
    k_scan_bsum<<<NBLK, 256, 0, stream>>>(counts, bsum);
    k_scan_top<<<1, 512, 0, stream>>>(bsum, NBLK);
    k_scan_final<<<NBLK, 256, 0, stream>>>(counts, bsum, rowptr, srcs, counts);
    k_scatter8<<<2048, 256, 0, stream>>>(ei, srcs, counts);

    // ---- layer 1 (h1 never materialized) ----
    k_xcvt<<<(NN * 16 + 255) / 256, 256, 0, stream>>>(x, va, vd, xh, as1, ad1);
    k_agg1x<<<(NN + 3) / 4, 256, 0, stream>>>(rowptr, srcs, xh, as1, ad1, y);
    k_bd1<<<GXM, 256, 0, stream>>>(y, wt1, scs, shs, agg1h);

    // ---- layer 2 ----
    k_gemm2m<<<GXM, 256, 0, stream>>>(agg1h, wt2, a_src2, a_dst2, wq,
                                      ad2, (uint2*)packf);
    k_agg2q<<<(NN + 15) / 16, 256, 0, stream>>>(rowptr, srcs, (const uint4*)packf,
                                                ad2, cst, out);
}

// Round 13
// 360.182 us; speedup vs baseline: 26.7423x; 1.0494x over previous
//
#include <hip/hip_runtime.h>
#include <hip/hip_fp16.h>
#include <math.h>

#define NN 100000
#define EE 1600000
#define ETOT (EE + NN)
#define BN_EPS 1e-5f
#define NEG_SLOPE 0.2f
#define NBLK ((NN + 255) / 256)   // 391
#define NGRP 8
#define GRPSZ ((NN + NGRP - 1) / NGRP)   // 12500
#define HISTBLK 2048

typedef _Float16 half8 __attribute__((ext_vector_type(8)));
typedef float f32x4 __attribute__((ext_vector_type(4)));

// ---------- helpers ----------
__device__ __forceinline__ float lrelu(float x) { return fmaxf(x, NEG_SLOPE * x); }
__device__ __forceinline__ float wsum(float v) {
#pragma unroll
    for (int m = 32; m; m >>= 1) v += __shfl_xor(v, m, 64);
    return v;
}
__device__ __forceinline__ float gsum16(float v) {
#pragma unroll
    for (int m = 1; m < 16; m <<= 1) v += __shfl_xor(v, m, 64);
    return v;
}
__device__ __forceinline__ unsigned packh2(float a, float b) {
    __half2 p = __float22half2_rn(make_float2(a, b));
    return *reinterpret_cast<unsigned*>(&p);
}

// ========== prep (BN folds, w^T fp16, va/vd) + XCD-partitioned hist ==========
__global__ __launch_bounds__(256) void k_preph(
    const float* __restrict__ b1, const float* __restrict__ g1,
    const float* __restrict__ be1, const float* __restrict__ m1,
    const float* __restrict__ v1,
    const float* __restrict__ b2, const float* __restrict__ g2,
    const float* __restrict__ be2, const float* __restrict__ m2,
    const float* __restrict__ v2, const float* __restrict__ wc,
    const float* __restrict__ bc,
    const float* __restrict__ w1, const float* __restrict__ w2,
    const float* __restrict__ as1w, const float* __restrict__ ad1w,
    const int* __restrict__ ei,
    float* __restrict__ scs, float* __restrict__ shs,
    float* __restrict__ wq, float* __restrict__ cst,
    float* __restrict__ va, float* __restrict__ vd,
    _Float16* __restrict__ wt1, _Float16* __restrict__ wt2,
    int* __restrict__ counts)
{
    const int b = blockIdx.x, t = threadIdx.x;
    if (b == 0) {
        const float sc = g1[t] * rsqrtf(v1[t] + BN_EPS);
        scs[t] = sc;
        shs[t] = (b1[t] - m1[t]) * sc + be1[t];
    } else if (b == 1) {
        if (t < 64) {
            const float s2 = g2[t] * rsqrtf(v2[t] + BN_EPS);
            wq[t * 2 + 0] = s2 * wc[t * 2 + 0];
            wq[t * 2 + 1] = s2 * wc[t * 2 + 1];
            const float tv = (b2[t] - m2[t]) * s2 + be2[t];
            const float c0 = wsum(tv * wc[t * 2 + 0]);
            const float c1 = wsum(tv * wc[t * 2 + 1]);
            if (t == 0) { cst[0] = c0 + bc[0]; cst[1] = c1 + bc[1]; }
        }
    } else if (b < 130) {
        const int idx = (b - 2) * 256 + t;           // wt1[n][k] = w1[k][n]
        const int n = idx >> 7, k = idx & 127;
        wt1[idx] = (_Float16)w1[k * 256 + n];
    } else if (b < 258) {
        const int idx = (b - 130) * 256 + t;         // wt2[n][k] = w2[k][n]
        const int n = idx >> 8, k = idx & 255;
        wt2[idx] = (_Float16)w2[k * 128 + n];
    } else if (b == 258) {
#pragma unroll
        for (int rep = 0; rep < 2; ++rep) {
            const int idx = rep * 256 + t;           // 0..511 = h*128+k
            const int h = idx >> 7, k = idx & 127;
            float sa = 0.f, sd = 0.f;
            for (int c = 0; c < 64; ++c) {
                const float wv = w1[k * 256 + h * 64 + c];
                sa = fmaf(wv, as1w[h * 64 + c], sa);
                sd = fmaf(wv, ad1w[h * 64 + c], sd);
            }
            va[idx] = sa;
            vd[idx] = sd;
        }
    } else {
        // XCD-partitioned histogram (counts pre-zeroed by memsetAsync)
        const int bh = b - 259;
        const int g = bh & (NGRP - 1);
        const int lo = g * GRPSZ;
        const int hi = (lo + GRPSZ < NN) ? lo + GRPSZ : NN;
        const int stride = (HISTBLK >> 3) * 256;
        for (int e = (bh >> 3) * 256 + t; e < EE; e += stride) {
            const int d = ei[EE + e];
            if (d >= lo && d < hi) atomicAdd(&counts[d], 1);
        }
    }
}

// ================= CSR scans =================
__global__ __launch_bounds__(256) void k_scan_bsum(const int* __restrict__ counts,
                                                   int* __restrict__ bsum) {
    __shared__ int sd[256];
    const int i = blockIdx.x * 256 + threadIdx.x;
    sd[threadIdx.x] = (i < NN) ? counts[i] + 1 : 0;   // +1 = self-loop
    __syncthreads();
    for (int s2 = 128; s2; s2 >>= 1) {
        if (threadIdx.x < s2) sd[threadIdx.x] += sd[threadIdx.x + s2];
        __syncthreads();
    }
    if (threadIdx.x == 0) bsum[blockIdx.x] = sd[0];
}
// rowptr + self-loop + cursor, with inline top-scan (no separate k_scan_top)
__global__ __launch_bounds__(256) void k_scan_finaltop(
    const int* __restrict__ counts, const int* __restrict__ bsum,
    int* __restrict__ rowptr, int* __restrict__ srcs, int* __restrict__ cursor)
{
    __shared__ int sd[256];
    // inline exclusive top-scan: base = sum bsum[j], j < blockIdx.x
    int partial = 0;
    for (int j = threadIdx.x; j < NBLK; j += 256)
        if (j < blockIdx.x) partial += bsum[j];
    sd[threadIdx.x] = partial;
    __syncthreads();
    for (int s2 = 128; s2; s2 >>= 1) {
        if (threadIdx.x < s2) sd[threadIdx.x] += sd[threadIdx.x + s2];
        __syncthreads();
    }
    const int base = sd[0];
    __syncthreads();
    const int i = blockIdx.x * 256 + threadIdx.x;
    const int orig = (i < NN) ? counts[i] + 1 : 0;
    sd[threadIdx.x] = orig;
    __syncthreads();
    for (int off = 1; off < 256; off <<= 1) {
        const int v = (threadIdx.x >= off) ? sd[threadIdx.x - off] : 0;
        __syncthreads();
        sd[threadIdx.x] += v;
        __syncthreads();
    }
    if (i < NN) {
        const int rp = base + sd[threadIdx.x] - orig;
        rowptr[i] = rp;
        srcs[rp] = i;                                // self-loop first
        cursor[i] = rp + 1;
        if (i == NN - 1) rowptr[NN] = ETOT;
    }
}
__global__ __launch_bounds__(256) void k_scatter8(const int* __restrict__ ei,
                                                  int* __restrict__ srcs,
                                                  int* __restrict__ cursor) {
    const int g = blockIdx.x & (NGRP - 1);
    const int lo = g * GRPSZ;
    const int hi = (lo + GRPSZ < NN) ? lo + GRPSZ : NN;
    const int nb = gridDim.x >> 3;
    const int stride = nb * 256;
    for (int e = (blockIdx.x >> 3) * 256 + threadIdx.x; e < EE; e += stride) {
        const int d = ei[EE + e];
        if (d >= lo && d < hi) {
            const int p = atomicAdd(&cursor[d], 1);
            srcs[p] = ei[e];
        }
    }
}

// ====== x -> fp16, + as1/ad1 = x·va / x·vd (16 lanes per node) ======
__global__ __launch_bounds__(256) void k_xcvt(
    const float* __restrict__ x, const float* __restrict__ va,
    const float* __restrict__ vd, _Float16* __restrict__ xh,
    float* __restrict__ as_, float* __restrict__ ad_)
{
    const int gid = blockIdx.x * 256 + threadIdx.x;
    const int n = gid >> 4;
    if (n >= NN) return;
    const int j = gid & 15;
    const int k0 = j * 8;
    float xv[8];
    *(float4*)&xv[0] = *(const float4*)&x[(size_t)n * 128 + k0];
    *(float4*)&xv[4] = *(const float4*)&x[(size_t)n * 128 + k0 + 4];
    half8 hv;
#pragma unroll
    for (int i = 0; i < 8; ++i) hv[i] = (_Float16)xv[i];
    *(half8*)&xh[(size_t)n * 128 + k0] = hv;
    float sa[4], sd[4];
#pragma unroll
    for (int h = 0; h < 4; ++h) {
        float s = 0.f, d = 0.f;
#pragma unroll
        for (int i = 0; i < 8; ++i) {
            s = fmaf(xv[i], va[h * 128 + k0 + i], s);
            d = fmaf(xv[i], vd[h * 128 + k0 + i], d);
        }
        sa[h] = gsum16(s);
        sd[h] = gsum16(d);
    }
    if (j == 0) {
        *(float4*)&as_[n * 4] = make_float4(sa[0], sa[1], sa[2], sa[3]);
        *(float4*)&ad_[n * 4] = make_float4(sd[0], sd[1], sd[2], sd[3]);
    }
}

// ====== layer-1 aggregation over x; p computed once per (edge,head), shfl-shared ==
__global__ __launch_bounds__(256) void k_agg1x(
    const int* __restrict__ rowptr, const int* __restrict__ srcs,
    const _Float16* __restrict__ xh, const float* __restrict__ as_,
    const float* __restrict__ ad_, _Float16* __restrict__ y)
{
    const int d = blockIdx.x * 4 + (threadIdx.x >> 6);
    if (d >= NN) return;
    const int lane = threadIdx.x & 63;
    const int r0 = rowptr[d], r1 = rowptr[d + 1];
    const int h = lane >> 4;
    const int cb = (lane & 15) * 8;
    const float myad = ad_[d * 4 + h];

    float den = 0.f;
    float acc[8] = {0.f, 0.f, 0.f, 0.f, 0.f, 0.f, 0.f, 0.f};
    int k = r0;
    for (; k + 3 < r1; k += 4) {
        // one p per lane: edge k+(lane&3), head lane>>4; share via shfl
        const int sm = srcs[k + (lane & 3)];
        const float pm = __expf(lrelu(as_[sm * 4 + h] + myad));
        const int s0 = __shfl(sm, 0, 64);
        const int s1 = __shfl(sm, 1, 64);
        const int s2 = __shfl(sm, 2, 64);
        const int s3 = __shfl(sm, 3, 64);
        const int pb = lane & 48;
        const float p0 = __shfl(pm, pb | 0, 64);
        const float p1 = __shfl(pm, pb | 1, 64);
        const float p2 = __shfl(pm, pb | 2, 64);
        const float p3 = __shfl(pm, pb | 3, 64);
        den += (p0 + p1) + (p2 + p3);
        const half8 v0 = *(const half8*)&xh[(size_t)s0 * 128 + cb];
        const half8 v1 = *(const half8*)&xh[(size_t)s1 * 128 + cb];
        const half8 v2 = *(const half8*)&xh[(size_t)s2 * 128 + cb];
        const half8 v3 = *(const half8*)&xh[(size_t)s3 * 128 + cb];
#pragma unroll
        for (int i = 0; i < 8; ++i) {
            acc[i] = fmaf(p0, (float)v0[i], acc[i]);
            acc[i] = fmaf(p1, (float)v1[i], acc[i]);
            acc[i] = fmaf(p2, (float)v2[i], acc[i]);
            acc[i] = fmaf(p3, (float)v3[i], acc[i]);
        }
    }
    for (; k < r1; ++k) {
        const int s = srcs[k];
        const float p = __expf(lrelu(as_[s * 4 + h] + myad));
        den += p;
        const half8 v = *(const half8*)&xh[(size_t)s * 128 + cb];
#pragma unroll
        for (int i = 0; i < 8; ++i) acc[i] = fmaf(p, (float)v[i], acc[i]);
    }
    const float inv = 1.f / (den + 1e-16f);
    half8 hv;
#pragma unroll
    for (int i = 0; i < 8; ++i) hv[i] = (_Float16)(acc[i] * inv);
    *(half8*)&y[(size_t)d * 512 + h * 128 + cb] = hv;
}

// ====== fused: per-head BD-GEMM (y@W1_h, BN1+ELU) -> mid(LDS) -> GEMM2 -> pack ======
// 64-row tiles; grid ceil(NN/64); 4 waves.
__global__ __launch_bounds__(256) void k_l2fuse(
    const _Float16* __restrict__ y,    // [NN][4][128]
    const _Float16* __restrict__ wt1,  // [256][128]
    const _Float16* __restrict__ wt2,  // [128][256]
    const float* __restrict__ scs, const float* __restrict__ shs,
    const float* __restrict__ asrc, const float* __restrict__ adst,
    const float* __restrict__ wq,
    float* __restrict__ ad_, uint2* __restrict__ pack)
{
    __shared__ _Float16 ys[64][136];
    __shared__ _Float16 mid[64][264];
    const int n0 = blockIdx.x * 64;
    const int t = threadIdx.x;
    const int l = t & 63, w = t >> 6;
    const int lc = l & 15, kq = (l >> 4) * 8, lr = (l >> 4) * 4;
    const int m0w = (w & 1) * 32;          // 2 row-tiles per wave
    const f32x4 fzero = {0.f, 0.f, 0.f, 0.f};

    // ---- phase 1: per head, mid[:, h*64..] = ELU(BN1(y_h @ W1_h)) ----
    const int c0w = (w >> 1) * 32;         // 2 col-tiles per wave (within head)
    for (int h = 0; h < 4; ++h) {
        if (h) __syncthreads();
#pragma unroll
        for (int i = 0; i < 4; ++i) {
            const int f = i * 2048 + t * 8;
            const int m = f >> 7, k8 = f & 127;
            half8 v = {};
            if (n0 + m < NN)
                v = *(const half8*)&y[(size_t)(n0 + m) * 512 + h * 128 + k8];
            *(half8*)&ys[m][k8] = v;
        }
        __syncthreads();

        f32x4 acc[2][2];
        acc[0][0] = fzero; acc[0][1] = fzero; acc[1][0] = fzero; acc[1][1] = fzero;
#pragma unroll
        for (int ks = 0; ks < 4; ++ks) {
            const int k0 = ks * 32 + kq;
            const half8 a0 = *(const half8*)&ys[m0w + lc][k0];
            const half8 a1 = *(const half8*)&ys[m0w + 16 + lc][k0];
            const half8 b0 = *(const half8*)&wt1[(size_t)(h * 64 + c0w + lc) * 128 + k0];
            const half8 b1 = *(const half8*)&wt1[(size_t)(h * 64 + c0w + 16 + lc) * 128 + k0];
            acc[0][0] = __builtin_amdgcn_mfma_f32_16x16x32_f16(a0, b0, acc[0][0], 0, 0, 0);
            acc[0][1] = __builtin_amdgcn_mfma_f32_16x16x32_f16(a0, b1, acc[0][1], 0, 0, 0);
            acc[1][0] = __builtin_amdgcn_mfma_f32_16x16x32_f16(a1, b0, acc[1][0], 0, 0, 0);
            acc[1][1] = __builtin_amdgcn_mfma_f32_16x16x32_f16(a1, b1, acc[1][1], 0, 0, 0);
        }
        // BN1 + ELU -> mid
#pragma unroll
        for (int c = 0; c < 2; ++c) {
            const int col = h * 64 + c0w + c * 16 + lc;
            const float scv = scs[col], shv = shs[col];
#pragma unroll
            for (int r = 0; r < 2; ++r) {
#pragma unroll
                for (int i = 0; i < 4; ++i) {
                    float e = fmaf(acc[r][c][i], scv, shv);
                    e = e > 0.f ? e : __expf(e) - 1.f;
                    mid[m0w + r * 16 + lr + i][col] = (_Float16)e;
                }
            }
        }
    }
    __syncthreads();

    // ---- phase 2: gemm2 K=256 from mid; wave head = w>>1, cols c20..c20+63 ----
    const int c20 = (w >> 1) * 64;
    f32x4 acc2[2][4];
#pragma unroll
    for (int r = 0; r < 2; ++r)
#pragma unroll
        for (int c = 0; c < 4; ++c) acc2[r][c] = fzero;
#pragma unroll
    for (int ks = 0; ks < 8; ++ks) {
        const int k0 = ks * 32 + kq;
        const half8 a0 = *(const half8*)&mid[m0w + lc][k0];
        const half8 a1 = *(const half8*)&mid[m0w + 16 + lc][k0];
#pragma unroll
        for (int c = 0; c < 4; ++c) {
            const half8 b = *(const half8*)&wt2[(size_t)(c20 + c * 16 + lc) * 256 + k0];
            acc2[0][c] = __builtin_amdgcn_mfma_f32_16x16x32_f16(a0, b, acc2[0][c], 0, 0, 0);
            acc2[1][c] = __builtin_amdgcn_mfma_f32_16x16x32_f16(a1, b, acc2[1][c], 0, 0, 0);
        }
    }
    const int head = w >> 1;
    float awv[4], dwv[4], wq0[4], wq1[4];
#pragma unroll
    for (int c = 0; c < 4; ++c) {
        const int j = c20 + c * 16 + lc;
        const int cl = j & 63;
        awv[c] = asrc[j];
        dwv[c] = adst[j];
        wq0[c] = wq[cl * 2 + 0];
        wq1[c] = wq[cl * 2 + 1];
    }
#pragma unroll
    for (int r = 0; r < 2; ++r) {
#pragma unroll
        for (int i = 0; i < 4; ++i) {
            float s = 0.f, d = 0.f, q0 = 0.f, q1 = 0.f;
#pragma unroll
            for (int c = 0; c < 4; ++c) {
                s = fmaf(acc2[r][c][i], awv[c], s);
                d = fmaf(acc2[r][c][i], dwv[c], d);
                q0 = fmaf(acc2[r][c][i], wq0[c], q0);
                q1 = fmaf(acc2[r][c][i], wq1[c], q1);
            }
            s = gsum16(s); d = gsum16(d); q0 = gsum16(q0); q1 = gsum16(q1);
            const int rg = n0 + m0w + r * 16 + lr + i;
            if (lc == 0 && rg < NN) {
                ad_[rg * 2 + head] = d;
                uint2 u;
                u.x = __float_as_uint(s);
                u.y = packh2(q0, q1);
                pack[rg * 2 + head] = u;
            }
        }
    }
}

// ====== layer-2: single-pass softmax; one 16B record gather per edge ======
__global__ __launch_bounds__(256) void k_agg2q(
    const int* __restrict__ rowptr, const int* __restrict__ srcs,
    const uint4* __restrict__ pack, const float* __restrict__ ad_,
    const float* __restrict__ cst, float* __restrict__ out)
{
    const int d = blockIdx.x * 16 + (threadIdx.x >> 4);
    if (d >= NN) return;
    const int il = threadIdx.x & 15;
    const int r0 = rowptr[d], r1 = rowptr[d + 1];
    const float2 adv = *(const float2*)&ad_[d * 2];

    float den0 = 0.f, den1 = 0.f;
    float qa00 = 0.f, qa01 = 0.f, qa10 = 0.f, qa11 = 0.f;
    for (int k = r0 + il; k < r1; k += 16) {
        const int s = srcs[k];
        const uint4 rec = pack[s];
        const float a0 = __uint_as_float(rec.x);
        const float a1 = __uint_as_float(rec.z);
        const float2 q0 = __half22float2(*reinterpret_cast<const __half2*>(&rec.y));
        const float2 q1 = __half22float2(*reinterpret_cast<const __half2*>(&rec.w));
        const float p0 = __expf(lrelu(a0 + adv.x));
        const float p1 = __expf(lrelu(a1 + adv.y));
        den0 += p0; den1 += p1;
        qa00 = fmaf(p0, q0.x, qa00); qa01 = fmaf(p0, q0.y, qa01);
        qa10 = fmaf(p1, q1.x, qa10); qa11 = fmaf(p1, q1.y, qa11);
    }
    den0 = gsum16(den0); den1 = gsum16(den1);
    qa00 = gsum16(qa00); qa01 = gsum16(qa01);
    qa10 = gsum16(qa10); qa11 = gsum16(qa11);
    if (il == 0) {
        const float i0 = 1.f / (den0 + 1e-16f);
        const float i1 = 1.f / (den1 + 1e-16f);
        out[d * 2 + 0] = cst[0] + 0.5f * (qa00 * i0 + qa10 * i1);
        out[d * 2 + 1] = cst[1] + 0.5f * (qa01 * i0 + qa11 * i1);
    }
}

extern "C" void kernel_launch(void* const* d_in, const int* in_sizes, int n_in,
                              void* d_out, int out_size, void* d_ws, size_t ws_size,
                              hipStream_t stream) {
    const float* x      = (const float*)d_in[0];
    const int*   ei     = (const int*)d_in[1];
    const float* w1     = (const float*)d_in[2];
    const float* a_src1 = (const float*)d_in[3];
    const float* a_dst1 = (const float*)d_in[4];
    const float* b1     = (const float*)d_in[5];
    const float* g1     = (const float*)d_in[6];
    const float* be1    = (const float*)d_in[7];
    const float* m1     = (const float*)d_in[8];
    const float* v1     = (const float*)d_in[9];
    const float* w2     = (const float*)d_in[10];
    const float* a_src2 = (const float*)d_in[11];
    const float* a_dst2 = (const float*)d_in[12];
    const float* b2     = (const float*)d_in[13];
    const float* g2     = (const float*)d_in[14];
    const float* be2    = (const float*)d_in[15];
    const float* m2     = (const float*)d_in[16];
    const float* v2     = (const float*)d_in[17];
    const float* wc     = (const float*)d_in[18];
    const float* bc     = (const float*)d_in[19];
    float* out = (float*)d_out;

    float* ws = (float*)d_ws;
    _Float16* xh = (_Float16*)ws;                      // NN*128 h  (NN*64 fl)
    _Float16* y  = (_Float16*)(ws + (size_t)NN * 64);  // NN*512 h  (NN*256 fl)
    float* C = ws + (size_t)NN * 320;

    float* as1 = C;                        // NN*4
    float* ad1 = C + (size_t)NN * 4;       // NN*4
    float* ad2 = C + (size_t)NN * 8;       // NN*2
    float* packf = C + (size_t)NN * 10;    // NN*4 (uint2 x2 per node)
    float* scs = C + (size_t)NN * 14;      // 256
    float* shs = scs + 256;                // 256
    float* wq  = shs + 256;                // 128
    float* cst = wq + 128;                 // 64
    float* va  = cst + 64;                 // 512
    float* vd  = va + 512;                 // 512
    float* wbase = vd + 512;
    _Float16* wt1 = (_Float16*)wbase;      // 32768 h (16384 fl)
    _Float16* wt2 = wt1 + 32768;           // 32768 h
    int* counts = (int*)(wbase + 32768);   // NN (reused as cursor)
    int* rowptr = counts + NN;             // NN+1
    int* bsum   = rowptr + NN + 63;        // 512
    int* srcs   = bsum + 512;              // ETOT

    // ---- counts zero + combined prep/hist ----
    hipMemsetAsync(counts, 0, (size_t)NN * sizeof(int), stream);
    k_preph<<<259 + HISTBLK, 256, 0, stream>>>(
        b1, g1, be1, m1, v1, b2, g2, be2, m2, v2, wc, bc, w1, w2,
        a_src1, a_dst1, ei, scs, shs, wq, cst, va, vd, wt1, wt2, counts);

    // ---- CSR scans + scatter ----
    k_scan_bsum<<<NBLK, 256, 0, stream>>>(counts, bsum);
    k_scan_finaltop<<<NBLK, 256, 0, stream>>>(counts, bsum, rowptr, srcs, counts);
    k_scatter8<<<2048, 256, 0, stream>>>(ei, srcs, counts);

    // ---- layer 1 ----
    k_xcvt<<<(NN * 16 + 255) / 256, 256, 0, stream>>>(x, va, vd, xh, as1, ad1);
    k_agg1x<<<(NN + 3) / 4, 256, 0, stream>>>(rowptr, srcs, xh, as1, ad1, y);

    // ---- fused BD-GEMM + GEMM2 ----
    k_l2fuse<<<(NN + 63) / 64, 256, 0, stream>>>(y, wt1, wt2, scs, shs,
                                                 a_src2, a_dst2, wq,
                                                 ad2, (uint2*)packf);

    // ---- layer 2 edge pass ----
    k_agg2q<<<(NN + 15) / 16, 256, 0, stream>>>(rowptr, srcs, (const uint4*)packf,
                                                ad2, cst, out);
}